// Round 5
// baseline (2175.321 us; speedup 1.0000x reference)
//
#include <hip/hip_runtime.h>
#include <stdint.h>

typedef short short8 __attribute__((ext_vector_type(8)));
typedef float f32x4 __attribute__((ext_vector_type(4)));
typedef unsigned short u16;

#define HID 256
#define NLAYERS 5
#define BN_EPS 1e-5f

__device__ __forceinline__ float bf2f(u16 u) {
    union { unsigned int i; float f; } v;
    v.i = ((unsigned int)u) << 16;
    return v.f;
}
__device__ __forceinline__ u16 f2bf(float f) {
    union { float f; unsigned int i; } v;
    v.f = f;
    unsigned int r = v.i + 0x7FFFu + ((v.i >> 16) & 1u);   // RNE
    return (u16)(r >> 16);
}
// split fp32 -> (hi, lo) bf16 pair: hi+lo ~ 17-bit mantissa approximation
__device__ __forceinline__ void split_bf(float f, u16& hi, u16& lo) {
    hi = f2bf(f);
    lo = f2bf(f - bf2f(hi));
}

// 16-B direct global->LDS copy (vmcnt-tracked; drained by __syncthreads).
__device__ __forceinline__ void gl_lds16(const void* gsrc, void* ldst) {
    const __attribute__((address_space(1))) unsigned int* g =
        reinterpret_cast<const __attribute__((address_space(1))) unsigned int*>(
            reinterpret_cast<uintptr_t>(gsrc));
    __attribute__((address_space(3))) unsigned int* l =
        reinterpret_cast<__attribute__((address_space(3))) unsigned int*>(
            reinterpret_cast<uintptr_t>(ldst));
    __builtin_amdgcn_global_load_lds(g, l, 16, 0, 0);
}

// ---------------- utility ----------------

__global__ __launch_bounds__(256) void k_zero32(unsigned int* p, int n) {
    int i = blockIdx.x * 256 + threadIdx.x;
    if (i < n) p[i] = 0u;
}

// ---------------- graph preprocessing (staged in d_out) ----------------

__global__ __launch_bounds__(256) void k_detect(const int* ei, int* flag, int E) {
    __shared__ int nz;
    if (threadIdx.x == 0) nz = 0;
    __syncthreads();
    int lim = (2 * E < 4096) ? 2 * E : 4096;
    int c = 0;
    for (int i = threadIdx.x; 2 * i + 1 < lim; i += 256) c += (ei[2 * i + 1] != 0);
    atomicAdd(&nz, c);
    __syncthreads();
    if (threadIdx.x == 0) flag[0] = (nz == 0) ? 1 : 0;   // 1 => int64 layout
}

__global__ __launch_bounds__(256) void k_deg(const int* ei, const int* flag, int* deg, int E, int N) {
    int e = blockIdx.x * 256 + threadIdx.x;
    if (e >= E) return;
    int w = flag[0];
    int col = w ? ei[2 * (E + e)] : ei[E + e];
    if ((unsigned)col < (unsigned)N) atomicAdd(&deg[col], 1);
}

__global__ __launch_bounds__(256) void k_dinv(const int* deg, float* dinv, int N) {
    int n = blockIdx.x * 256 + threadIdx.x;
    if (n < N) { int d = deg[n]; dinv[n] = d > 0 ? rsqrtf((float)d) : 0.0f; }
}

__global__ __launch_bounds__(256) void k_scan1(const int* deg, int* offs, int* bsum, int N) {
    __shared__ int s[256];
    int tid = threadIdx.x;
    int i = blockIdx.x * 256 + tid;
    int v = (i < N) ? deg[i] : 0;
    s[tid] = v;
    __syncthreads();
    for (int off = 1; off < 256; off <<= 1) {
        int t = (tid >= off) ? s[tid - off] : 0;
        __syncthreads();
        s[tid] += t;
        __syncthreads();
    }
    if (i < N) offs[i] = s[tid] - v;
    if (tid == 255) bsum[blockIdx.x] = s[tid];
}

__global__ __launch_bounds__(256) void k_scan2(const int* bsum, int* bscan, int NB) {
    __shared__ int s[256];
    int tid = threadIdx.x;
    int v = (tid < NB) ? bsum[tid] : 0;
    s[tid] = v;
    __syncthreads();
    for (int off = 1; off < 256; off <<= 1) {
        int t = (tid >= off) ? s[tid - off] : 0;
        __syncthreads();
        s[tid] += t;
        __syncthreads();
    }
    bscan[tid] = s[tid] - v;
}

__global__ __launch_bounds__(256) void k_scan3(int* offs, const int* bscan, int* cursor, int N, int E) {
    int i = blockIdx.x * 256 + threadIdx.x;
    if (i < N) {
        int o = offs[i] + bscan[blockIdx.x];
        offs[i] = o;
        cursor[i] = o;
    }
    if (i == 0) offs[N] = E;
}

__global__ __launch_bounds__(256) void k_place(const int* ei, const int* flag, const float4* eattr,
                                               int* cursor, int* srow, float4* sea, int E, int N) {
    int e = blockIdx.x * 256 + threadIdx.x;
    if (e >= E) return;
    int w = flag[0];
    int r = w ? ei[2 * e] : ei[e];
    int c = w ? ei[2 * (E + e)] : ei[E + e];
    if ((unsigned)c >= (unsigned)N) return;
    int p = atomicAdd(&cursor[c], 1);
    srow[p] = r;
    sea[p] = eattr[e];
}

__global__ __launch_bounds__(256) void k_move(const int* srow, const float4* sea, const float* sdinv,
                                              const int* soffs, int* rowArr, float4* eaP,
                                              float* dinvF, int* offsF, int E, int N) {
    int i = blockIdx.x * 256 + threadIdx.x;
    if (i < E) { rowArr[i] = srow[i]; eaP[i] = sea[i]; }
    if (i < N) dinvF[i] = sdinv[i];
    if (i <= N) offsF[i] = soffs[i];
}

__global__ __launch_bounds__(256) void k_precheckN(const int* offsF, const int* cursor, const float* dinvF,
                                                   const int* gflag, int* diag, int N, int E) {
    int i = blockIdx.x * 256 + threadIdx.x;
    if (i < N) {
        if (offsF[i + 1] < offsF[i]) atomicOr(&diag[0], 1);
        if (cursor[i] != offsF[i + 1]) atomicOr(&diag[0], 2);
        float d = dinvF[i];
        if (!(d == d) || fabsf(d) > 1e10f) atomicOr(&diag[0], 4);
    }
    if (i == 0) {
        if (offsF[N] != E) atomicOr(&diag[0], 8);
        diag[7] = gflag[0];
    }
}
__global__ __launch_bounds__(256) void k_precheckE(const int* rowArr, int* diag, int E, int N) {
    int p = blockIdx.x * 256 + threadIdx.x;
    if (p < E && (unsigned)rowArr[p] >= (unsigned)N) atomicOr(&diag[0], 16);
}

// Per-layer: split W (fp32 512x256 row-major) into bf16 hi/lo planes in MFMA
// B-fragment order, kb-major: frag t = kb*1024 + nbg*64 + lane holds
// W[kb*32 + (lane>>4)*8 + j][nbg*16 + (lane&15)], j=0..7.
// Block 0 also zeroes the BN stats accumulators (512 floats at colsum).
__global__ __launch_bounds__(256) void k_wsplit(const float* W, u16* wpH, u16* wpL, float* colsum) {
    if (blockIdx.x == 0) {
        colsum[threadIdx.x] = 0.f;
        colsum[256 + threadIdx.x] = 0.f;
    }
    int t = blockIdx.x * 256 + threadIdx.x;   // 64 blocks -> 16384 frags
    int lane = t & 63;
    int nbg = (t >> 6) & 15;
    int kb = t >> 10;
    int quad = lane >> 4, nl = lane & 15;
    const float* src = W + (size_t)(kb * 32 + quad * 8) * HID + nbg * 16 + nl;
    short8 vh, vl;
#pragma unroll
    for (int j = 0; j < 8; ++j) {
        u16 h, l;
        split_bf(src[(size_t)j * HID], h, l);
        vh[j] = (short)h;
        vl[j] = (short)l;
    }
    *((short8*)wpH + t) = vh;
    *((short8*)wpL + t) = vl;
}

// ---------------- per-layer: aggregation (one wave per node), split output ----------------
#define FEA(ea, j) ((ea).w * w1v[j] + (ea).x * w20[j] + (ea).y * w21[j] + (ea).z * w22[j])

__global__ __launch_bounds__(256) void k_agg(const void* hin_, const u16* hin_lo, int hf32,
                                             const int* offs, const int* rowArr, const float4* eaP,
                                             const float* dinv, const float* ew1, const float* ew2,
                                             u16* agg_hi, u16* agg_lo, int* diag, int M) {
    int lane = threadIdx.x & 63, wave = threadIdx.x >> 6;
    int n = blockIdx.x * 4 + wave;

    float w1v[4] = {0.f, 0.f, 0.f, 0.f};
    float w20[4] = {0.f, 0.f, 0.f, 0.f};
    float w21[4] = {0.f, 0.f, 0.f, 0.f};
    float w22[4] = {0.f, 0.f, 0.f, 0.f};
    if (lane < 32) {
        int c = lane * 4;
#pragma unroll
        for (int j = 0; j < 4; ++j) w1v[j] = ew1[c + j];
    } else {
        int cc = (lane - 32) * 4;
#pragma unroll
        for (int j = 0; j < 4; ++j) {
            w20[j] = ew2[cc + j];
            w21[j] = ew2[128 + cc + j];
            w22[j] = ew2[256 + cc + j];
        }
    }

    if (n >= M) return;
    float dn = dinv[n];
    int s = offs[n], e = offs[n + 1];
    float a0 = 0.f, a1 = 0.f, a2 = 0.f, a3 = 0.f;
    int p = s;

    if (hf32) {
        for (; p + 4 <= e; p += 4) {
            int r0 = rowArr[p + 0], r1 = rowArr[p + 1], r2 = rowArr[p + 2], r3 = rowArr[p + 3];
            float4 ea0 = eaP[p + 0], ea1 = eaP[p + 1], ea2 = eaP[p + 2], ea3 = eaP[p + 3];
            float4 hv0 = *((const float4*)hin_ + (size_t)r0 * 64 + lane);
            float4 hv1 = *((const float4*)hin_ + (size_t)r1 * 64 + lane);
            float4 hv2 = *((const float4*)hin_ + (size_t)r2 * 64 + lane);
            float4 hv3 = *((const float4*)hin_ + (size_t)r3 * 64 + lane);
            float n0 = dn * dinv[r0], n1 = dn * dinv[r1], n2 = dn * dinv[r2], n3 = dn * dinv[r3];
            a0 += n0 * (hv0.x + FEA(ea0, 0)) + n1 * (hv1.x + FEA(ea1, 0))
                + n2 * (hv2.x + FEA(ea2, 0)) + n3 * (hv3.x + FEA(ea3, 0));
            a1 += n0 * (hv0.y + FEA(ea0, 1)) + n1 * (hv1.y + FEA(ea1, 1))
                + n2 * (hv2.y + FEA(ea2, 1)) + n3 * (hv3.y + FEA(ea3, 1));
            a2 += n0 * (hv0.z + FEA(ea0, 2)) + n1 * (hv1.z + FEA(ea1, 2))
                + n2 * (hv2.z + FEA(ea2, 2)) + n3 * (hv3.z + FEA(ea3, 2));
            a3 += n0 * (hv0.w + FEA(ea0, 3)) + n1 * (hv1.w + FEA(ea1, 3))
                + n2 * (hv2.w + FEA(ea2, 3)) + n3 * (hv3.w + FEA(ea3, 3));
        }
        for (; p < e; ++p) {
            int r = rowArr[p];
            float4 ea = eaP[p];
            float nrm = dn * dinv[r];
            float4 hv = *((const float4*)hin_ + (size_t)r * 64 + lane);
            a0 += nrm * (hv.x + FEA(ea, 0));
            a1 += nrm * (hv.y + FEA(ea, 1));
            a2 += nrm * (hv.z + FEA(ea, 2));
            a3 += nrm * (hv.w + FEA(ea, 3));
        }
    } else {
        for (; p + 4 <= e; p += 4) {
            int r0 = rowArr[p + 0], r1 = rowArr[p + 1], r2 = rowArr[p + 2], r3 = rowArr[p + 3];
            float4 ea0 = eaP[p + 0], ea1 = eaP[p + 1], ea2 = eaP[p + 2], ea3 = eaP[p + 3];
            ushort4 hh0 = *((const ushort4*)hin_ + (size_t)r0 * 64 + lane);
            ushort4 hl0 = *((const ushort4*)hin_lo + (size_t)r0 * 64 + lane);
            ushort4 hh1 = *((const ushort4*)hin_ + (size_t)r1 * 64 + lane);
            ushort4 hl1 = *((const ushort4*)hin_lo + (size_t)r1 * 64 + lane);
            ushort4 hh2 = *((const ushort4*)hin_ + (size_t)r2 * 64 + lane);
            ushort4 hl2 = *((const ushort4*)hin_lo + (size_t)r2 * 64 + lane);
            ushort4 hh3 = *((const ushort4*)hin_ + (size_t)r3 * 64 + lane);
            ushort4 hl3 = *((const ushort4*)hin_lo + (size_t)r3 * 64 + lane);
            float n0 = dn * dinv[r0], n1 = dn * dinv[r1], n2 = dn * dinv[r2], n3 = dn * dinv[r3];
            a0 += n0 * (bf2f(hh0.x) + bf2f(hl0.x) + FEA(ea0, 0))
                + n1 * (bf2f(hh1.x) + bf2f(hl1.x) + FEA(ea1, 0))
                + n2 * (bf2f(hh2.x) + bf2f(hl2.x) + FEA(ea2, 0))
                + n3 * (bf2f(hh3.x) + bf2f(hl3.x) + FEA(ea3, 0));
            a1 += n0 * (bf2f(hh0.y) + bf2f(hl0.y) + FEA(ea0, 1))
                + n1 * (bf2f(hh1.y) + bf2f(hl1.y) + FEA(ea1, 1))
                + n2 * (bf2f(hh2.y) + bf2f(hl2.y) + FEA(ea2, 1))
                + n3 * (bf2f(hh3.y) + bf2f(hl3.y) + FEA(ea3, 1));
            a2 += n0 * (bf2f(hh0.z) + bf2f(hl0.z) + FEA(ea0, 2))
                + n1 * (bf2f(hh1.z) + bf2f(hl1.z) + FEA(ea1, 2))
                + n2 * (bf2f(hh2.z) + bf2f(hl2.z) + FEA(ea2, 2))
                + n3 * (bf2f(hh3.z) + bf2f(hl3.z) + FEA(ea3, 2));
            a3 += n0 * (bf2f(hh0.w) + bf2f(hl0.w) + FEA(ea0, 3))
                + n1 * (bf2f(hh1.w) + bf2f(hl1.w) + FEA(ea1, 3))
                + n2 * (bf2f(hh2.w) + bf2f(hl2.w) + FEA(ea2, 3))
                + n3 * (bf2f(hh3.w) + bf2f(hl3.w) + FEA(ea3, 3));
        }
        for (; p < e; ++p) {
            int r = rowArr[p];
            float4 ea = eaP[p];
            float nrm = dn * dinv[r];
            ushort4 hh = *((const ushort4*)hin_ + (size_t)r * 64 + lane);
            ushort4 hl = *((const ushort4*)hin_lo + (size_t)r * 64 + lane);
            a0 += nrm * (bf2f(hh.x) + bf2f(hl.x) + FEA(ea, 0));
            a1 += nrm * (bf2f(hh.y) + bf2f(hl.y) + FEA(ea, 1));
            a2 += nrm * (bf2f(hh.z) + bf2f(hl.z) + FEA(ea, 2));
            a3 += nrm * (bf2f(hh.w) + bf2f(hl.w) + FEA(ea, 3));
        }
    }

    int bad = 0;
    if (!(a0 == a0)) { a0 = 777.f; bad++; }
    if (!(a1 == a1)) { a1 = 777.f; bad++; }
    if (!(a2 == a2)) { a2 = 777.f; bad++; }
    if (!(a3 == a3)) { a3 = 777.f; bad++; }
    if (bad) atomicAdd(&diag[1], bad);
    ushort4 oh, ol;
    split_bf(a0, oh.x, ol.x);
    split_bf(a1, oh.y, ol.y);
    split_bf(a2, oh.z, ol.z);
    split_bf(a3, oh.w, ol.w);
    *((ushort4*)agg_hi + (size_t)n * 64 + lane) = oh;
    *((ushort4*)agg_lo + (size_t)n * 64 + lane) = ol;
}

// ---------------- per-layer GEMM, primary (persistent-W, y -> workspace) ----------------
// y = relu(A·W + bias); A = [h | agg] hi/lo pairs; acc = Ahi·Whi + Alo·Whi + Ahi·Wlo.
// RACE NOTE (R4 fix): rows are column-split across 4 ns-blocks, so y MUST NOT alias the
// agg/h planes (v5 wrote y over agg -> cross-block read/write race, absmax 43-91).
// This kernel requires y_hi/y_lo in a buffer disjoint from hinA/agg (the d_ws workspace).
// Grid = 4 N-slices x 64 M-chunks = 256 blocks, 512 threads, 128 KB W-slice in LDS,
// staged once; then 8 waves stream row-tiles with ZERO barriers.
__global__ __launch_bounds__(512, 2) void MPNN_79044578115931_kernel(
        const void* hinA_, const u16* hinA_lo, int hf32,
        const u16* agg_hi, const u16* agg_lo,
        const u16* wpH, const u16* wpL, const float* bias,
        u16* y_hi, u16* y_lo,
        float* colsum, float* colsumsq, int* diag, int M) {
    __shared__ __align__(16) u16 wlds[65536];   // 128 KB: hi frags [0,32768), lo [32768,65536)

    int tid = threadIdx.x;
    int lane = tid & 63, wave = tid >> 6;
    int quad = lane >> 4, nl = lane & 15;
    int ns = blockIdx.x & 3;          // N-slice: global cols [ns*64, ns*64+64)
    int mc = blockIdx.x >> 2;         // M-chunk index (64 chunks)
    int MCH = (int)(gridDim.x >> 2);  // 64
    int RB = (M + MCH - 1) / MCH;     // rows per chunk (782)
    int rowBeg = mc * RB;
    int rowEnd = rowBeg + RB;
    if (rowEnd > M) rowEnd = M;
    int nt = (rowEnd > rowBeg) ? (rowEnd - rowBeg + 15) / 16 : 0;

    // stage W-slice: 4096 frags/plane x 16 B; LDS dest per wave = uniform + lane*16
#pragma unroll
    for (int i = 0; i < 8; ++i) {
        int fi = i * 512 + tid;
        int kb = fi >> 8, nbg = (fi >> 6) & 3, l = fi & 63;
        size_t gsrc = ((size_t)kb * 1024 + (size_t)(ns * 4 + nbg) * 64 + l) * 8;
        gl_lds16(wpH + gsrc, &wlds[(size_t)fi * 8]);
        gl_lds16(wpL + gsrc, &wlds[32768 + (size_t)fi * 8]);
    }
    __syncthreads();   // drains vmcnt(0): W-slice resident; only pre-epilogue barrier

    float bv[4];
#pragma unroll
    for (int nbg = 0; nbg < 4; ++nbg) bv[nbg] = bias[ns * 64 + nbg * 16 + nl];

    float sstat[4] = {0.f, 0.f, 0.f, 0.f};
    float qstat[4] = {0.f, 0.f, 0.f, 0.f};
    int badY = 0;

    const short8* bw = (const short8*)wlds + lane;   // hi frag f at bw[f*64]; lo at bw[4096 + f*64]

    for (int rt = wave; rt < nt; rt += 8) {
        int mBase = rowBeg + rt * 16;
        int rowA = mBase + nl;
        if (rowA >= M) rowA = M - 1;

        f32x4 acc[4];
#pragma unroll
        for (int i = 0; i < 4; ++i) acc[i] = {0.f, 0.f, 0.f, 0.f};

#pragma unroll
        for (int kb = 0; kb < 16; ++kb) {
            short8 ah, al;
            if (kb < 8) {
                int k0 = kb * 32 + quad * 8;
                if (hf32) {
                    const float* hp = (const float*)hinA_ + (size_t)rowA * HID + k0;
#pragma unroll
                    for (int j = 0; j < 8; ++j) {
                        u16 h, l;
                        split_bf(hp[j], h, l);
                        ah[j] = (short)h;
                        al[j] = (short)l;
                    }
                } else {
                    ah = *(const short8*)((const u16*)hinA_ + (size_t)rowA * HID + k0);
                    al = *(const short8*)(hinA_lo + (size_t)rowA * HID + k0);
                }
            } else {
                int k0 = (kb - 8) * 32 + quad * 8;
                ah = *(const short8*)(agg_hi + (size_t)rowA * HID + k0);
                al = *(const short8*)(agg_lo + (size_t)rowA * HID + k0);
            }
#pragma unroll
            for (int nbg = 0; nbg < 4; ++nbg) {
                short8 bh = bw[(kb * 4 + nbg) * 64];
                short8 bl = bw[4096 + (kb * 4 + nbg) * 64];
                acc[nbg] = __builtin_amdgcn_mfma_f32_16x16x32_bf16(ah, bh, acc[nbg], 0, 0, 0);
                acc[nbg] = __builtin_amdgcn_mfma_f32_16x16x32_bf16(al, bh, acc[nbg], 0, 0, 0);
                acc[nbg] = __builtin_amdgcn_mfma_f32_16x16x32_bf16(ah, bl, acc[nbg], 0, 0, 0);
            }
        }

#pragma unroll
        for (int nbg = 0; nbg < 4; ++nbg) {
            int c = ns * 64 + nbg * 16 + nl;
#pragma unroll
            for (int r = 0; r < 4; ++r) {
                int m = mBase + quad * 4 + r;
                if (m < rowEnd) {
                    float v = acc[nbg][r] + bv[nbg];
                    if (!(v == v)) { v = 777.f; badY++; }
                    v = v > 0.f ? v : 0.f;
                    u16 h, l;
                    split_bf(v, h, l);
                    y_hi[(size_t)m * HID + c] = h;
                    y_lo[(size_t)m * HID + c] = l;
                    sstat[nbg] += v;
                    qstat[nbg] += v * v;
                }
            }
        }
    }
    if (badY) atomicAdd(&diag[2], badY);

    // BN stats fold: overlay on dead W LDS
    __syncthreads();
    float* ls = (float*)wlds;      // ls[0..63] = sum, ls[64..127] = sumsq (local cols)
    if (tid < 128) ls[tid] = 0.f;
    __syncthreads();
#pragma unroll
    for (int nbg = 0; nbg < 4; ++nbg) {
        int cl = nbg * 16 + nl;
        atomicAdd(&ls[cl], sstat[nbg]);
        atomicAdd(&ls[64 + cl], qstat[nbg]);
    }
    __syncthreads();
    if (tid < 64) {
        atomicAdd(&colsum[ns * 64 + tid], ls[tid]);
        atomicAdd(&colsumsq[ns * 64 + tid], ls[64 + tid]);
    }
}

// ---------------- per-layer GEMM, fallback (row-exclusive, in-place-safe; R1-proven) ----
// Used when ws_size is too small for y planes. 128 rows x 256 cols per block, 4 waves x
// 2 row-groups; per K-step the 32 KB B kb-slice is staged into LDS; 2-barrier loop.
// Safe to write y over agg because each block owns its rows exclusively and all reads
// of a row precede its epilogue write within the same block.
__global__ __launch_bounds__(256, 2) void k_gemm_fb(
        const void* hinA_, const u16* hinA_lo, int hf32,
        const u16* agg_hi, const u16* agg_lo,
        const u16* wpH, const u16* wpL, const float* bias,
        u16* y_hi, u16* y_lo,
        float* colsum, float* colsumsq, int* diag, int M) {
    __shared__ __align__(16) u16 bstage[16384];   // 32 KB: hi [0,8192), lo [8192,16384)
    __shared__ float lsum[256];
    __shared__ float lsq[256];

    int tid = threadIdx.x;
    int lane = tid & 63, wave = tid >> 6;
    int quad = lane >> 4, nl = lane & 15;
    int mBase = blockIdx.x * 128 + wave * 32;
    int rowA0 = mBase + nl;
    int rowA1 = mBase + 16 + nl;
    if (rowA0 >= M) rowA0 = M - 1;
    if (rowA1 >= M) rowA1 = M - 1;

    lsum[tid] = 0.f;
    lsq[tid] = 0.f;

    f32x4 acc0[16], acc1[16];
#pragma unroll
    for (int i = 0; i < 16; ++i) {
        acc0[i] = {0.f, 0.f, 0.f, 0.f};
        acc1[i] = {0.f, 0.f, 0.f, 0.f};
    }

    for (int kb = 0; kb < 16; ++kb) {
        __syncthreads();
        const u16* srcH = wpH + (size_t)kb * 8192;
        const u16* srcL = wpL + (size_t)kb * 8192;
#pragma unroll
        for (int i = 0; i < 4; ++i) {
            int ci = i * 256 + tid;
            gl_lds16(srcH + ci * 8, &bstage[ci * 8]);
            gl_lds16(srcL + ci * 8, &bstage[8192 + ci * 8]);
        }

        short8 a0h, a0l, a1h, a1l;
        if (kb < 8) {
            int k0 = kb * 32 + quad * 8;
            if (hf32) {
                const float* hp0 = (const float*)hinA_ + (size_t)rowA0 * HID + k0;
                const float* hp1 = (const float*)hinA_ + (size_t)rowA1 * HID + k0;
#pragma unroll
                for (int j = 0; j < 8; ++j) {
                    u16 h, l;
                    split_bf(hp0[j], h, l);
                    a0h[j] = (short)h; a0l[j] = (short)l;
                    split_bf(hp1[j], h, l);
                    a1h[j] = (short)h; a1l[j] = (short)l;
                }
            } else {
                a0h = *(const short8*)((const u16*)hinA_ + (size_t)rowA0 * HID + k0);
                a0l = *(const short8*)(hinA_lo + (size_t)rowA0 * HID + k0);
                a1h = *(const short8*)((const u16*)hinA_ + (size_t)rowA1 * HID + k0);
                a1l = *(const short8*)(hinA_lo + (size_t)rowA1 * HID + k0);
            }
        } else {
            int k0 = (kb - 8) * 32 + quad * 8;
            a0h = *(const short8*)(agg_hi + (size_t)rowA0 * HID + k0);
            a0l = *(const short8*)(agg_lo + (size_t)rowA0 * HID + k0);
            a1h = *(const short8*)(agg_hi + (size_t)rowA1 * HID + k0);
            a1l = *(const short8*)(agg_lo + (size_t)rowA1 * HID + k0);
        }

        __syncthreads();

        const short8* bbase = (const short8*)bstage;
#pragma unroll
        for (int nbg = 0; nbg < 16; ++nbg) {
            short8 bh = bbase[nbg * 64 + lane];
            short8 bl = bbase[1024 + nbg * 64 + lane];
            acc0[nbg] = __builtin_amdgcn_mfma_f32_16x16x32_bf16(a0h, bh, acc0[nbg], 0, 0, 0);
            acc1[nbg] = __builtin_amdgcn_mfma_f32_16x16x32_bf16(a1h, bh, acc1[nbg], 0, 0, 0);
            acc0[nbg] = __builtin_amdgcn_mfma_f32_16x16x32_bf16(a0l, bh, acc0[nbg], 0, 0, 0);
            acc1[nbg] = __builtin_amdgcn_mfma_f32_16x16x32_bf16(a1l, bh, acc1[nbg], 0, 0, 0);
            acc0[nbg] = __builtin_amdgcn_mfma_f32_16x16x32_bf16(a0h, bl, acc0[nbg], 0, 0, 0);
            acc1[nbg] = __builtin_amdgcn_mfma_f32_16x16x32_bf16(a1h, bl, acc1[nbg], 0, 0, 0);
        }
    }

    __syncthreads();

    int badY = 0;
#pragma unroll
    for (int nbg = 0; nbg < 16; ++nbg) {
        int c = nbg * 16 + nl;
        float bvv = bias[c];
        float s = 0.f, q = 0.f;
#pragma unroll
        for (int r = 0; r < 4; ++r) {
            int m = mBase + quad * 4 + r;
            if (m < M) {
                float v = acc0[nbg][r] + bvv;
                if (!(v == v)) { v = 777.f; badY++; }
                v = v > 0.f ? v : 0.f;
                u16 h, l;
                split_bf(v, h, l);
                y_hi[(size_t)m * HID + c] = h;
                y_lo[(size_t)m * HID + c] = l;
                s += v;
                q += v * v;
            }
        }
        atomicAdd(&lsum[c], s);
        atomicAdd(&lsq[c], q);
    }
#pragma unroll
    for (int nbg = 0; nbg < 16; ++nbg) {
        int c = nbg * 16 + nl;
        float bvv = bias[c];
        float s = 0.f, q = 0.f;
#pragma unroll
        for (int r = 0; r < 4; ++r) {
            int m = mBase + 16 + quad * 4 + r;
            if (m < M) {
                float v = acc1[nbg][r] + bvv;
                if (!(v == v)) { v = 777.f; badY++; }
                v = v > 0.f ? v : 0.f;
                u16 h, l;
                split_bf(v, h, l);
                y_hi[(size_t)m * HID + c] = h;
                y_lo[(size_t)m * HID + c] = l;
                s += v;
                q += v * v;
            }
        }
        atomicAdd(&lsum[c], s);
        atomicAdd(&lsq[c], q);
    }
    if (badY) atomicAdd(&diag[2], badY);
    __syncthreads();
    atomicAdd(&colsum[tid], lsum[tid]);
    atomicAdd(&colsumsq[tid], lsq[tid]);
}

__global__ __launch_bounds__(256) void k_bnscale(const float* colsum, const float* colsumsq,
                                                 const float* g, const float* b,
                                                 float* scale, float* shift, int* diag, int M) {
    int c = threadIdx.x;
    float mu = colsum[c] / (float)M;
    float var = colsumsq[c] / (float)M - mu * mu;
    if (!(mu == mu) || !(var == var) || var > 1e30f) atomicAdd(&diag[3], 1);
    if (var < 0.f) var = 0.f;
    float sc = rsqrtf(var + BN_EPS) * g[c];
    scale[c] = sc;
    shift[c] = b[c] - mu * sc;
}

// BN apply: reads y from src planes; non-final writes dst planes (+ReLU);
// final writes fp32 to outf. src may equal dst (in-place, fallback mode).
__global__ __launch_bounds__(256) void k_bnapply(const u16* src_hi, const u16* src_lo,
                                                 u16* dst_hi, u16* dst_lo,
                                                 const float* scale, const float* shift,
                                                 float* outf, int finalL, int relu, int total) {
    int q4 = blockIdx.x * 256 + threadIdx.x;
    int idx = q4 * 4;
    if (idx >= total) return;
    int c = idx & (HID - 1);
    ushort4 vh = *((const ushort4*)src_hi + q4);
    ushort4 vl = *((const ushort4*)src_lo + q4);
    float o0 = scale[c + 0] * (bf2f(vh.x) + bf2f(vl.x)) + shift[c + 0];
    float o1 = scale[c + 1] * (bf2f(vh.y) + bf2f(vl.y)) + shift[c + 1];
    float o2 = scale[c + 2] * (bf2f(vh.z) + bf2f(vl.z)) + shift[c + 2];
    float o3 = scale[c + 3] * (bf2f(vh.w) + bf2f(vl.w)) + shift[c + 3];
    if (relu) {
        o0 = o0 > 0.f ? o0 : 0.f;
        o1 = o1 > 0.f ? o1 : 0.f;
        o2 = o2 > 0.f ? o2 : 0.f;
        o3 = o3 > 0.f ? o3 : 0.f;
    }
    if (finalL) {
        float4 ov; ov.x = o0; ov.y = o1; ov.z = o2; ov.w = o3;
        *((float4*)outf + q4) = ov;
    } else {
        ushort4 oh, ol;
        split_bf(o0, oh.x, ol.x);
        split_bf(o1, oh.y, ol.y);
        split_bf(o2, oh.z, ol.z);
        split_bf(o3, oh.w, ol.w);
        *((ushort4*)dst_hi + q4) = oh;
        *((ushort4*)dst_lo + q4) = ol;
    }
}

// d_out[0] = (1+k+8*int64)*2^20 only if a check failed.
__global__ void k_encode(const int* diag, float* out) {
    if (threadIdx.x != 0 || blockIdx.x != 0) return;
    int k = -1;
    for (int i = 0; i < 4; ++i) if (diag[i] != 0) { k = i; break; }
    if (k < 0) return;
    out[0] = (float)(1 + k + (diag[7] != 0 ? 8 : 0)) * 1048576.0f;
}

// ---------------- launcher ----------------

extern "C" void kernel_launch(void* const* d_in, const int* in_sizes, int n_in,
                              void* d_out, int out_size, void* d_ws, size_t ws_size,
                              hipStream_t stream) {
    const float*  x     = (const float*)d_in[0];
    const int*    ei    = (const int*)d_in[1];
    const float4* eattr = (const float4*)d_in[2];
    const float*  mlp_w = (const float*)d_in[3];
    const float*  mlp_b = (const float*)d_in[4];
    const float*  ew1   = (const float*)d_in[5];
    const float*  ew2   = (const float*)d_in[6];
    const float*  bn_g  = (const float*)d_in[7];
    const float*  bn_b  = (const float*)d_in[8];
    (void)n_in; (void)out_size;

    const int N = in_sizes[0] / HID;   // 50000
    const int E = in_sizes[1] / 2;     // 320000
    const size_t P = (size_t)N * HID;  // plane elements

    // ---- CSR staging inside d_out (dead before layer 0 writes d_out) ----
    char* st = (char*)d_out;
    int*    S_deg    = (int*)   (st + 0);
    float*  S_dinv   = (float*) (st + 204800);
    int*    S_offs   = (int*)   (st + 409600);
    int*    S_cursor = (int*)   (st + 614400);
    int*    S_bsum   = (int*)   (st + 819200);
    int*    S_bscan  = (int*)   (st + 820224);
    int*    S_gflag  = (int*)   (st + 821248);
    int*    S_row    = (int*)   (st + 1048576);
    float4* S_ea     = (float4*)(st + 2621440);   // ends 7,741,440 < 51.2 MB

    // ---- small homes in edge_index buffer (>=2.56 MB); eattr buffer holds eaP ----
    char* eb = (char*)d_in[1];
    int*   rowArr = (int*)  (eb + 0);          // 1,280,000
    float* dinvF  = (float*)(eb + 1280000);    // 200,000
    int*   offsF  = (int*)  (eb + 1480000);    // 200,004
    float* colsum = (float*)(eb + 1680128);
    float* colsq  = (float*)(eb + 1681152);
    float* scaleF = (float*)(eb + 1682176);
    float* shiftF = (float*)(eb + 1683200);
    int*   diag   = (int*)  (eb + 1684224);    // 1 KB
    u16*   wpH    = (u16*)  (eb + 1685504);    // 256 KB -> ends 1,947,648
    u16*   wpL    = (u16*)  (eb + 1947648);    // 256 KB -> ends 2,209,792 <= 2,560,000
    float4* eaP   = (float4*)d_in[2];          // 5,120,000 exact

    // ---- h slots as bf16 hi/lo planes (each slot = 2 planes = 51.2 MB) ----
    u16* sX_hi = (u16*)d_in[0];          // x buffer (x consumed during layer 0)
    u16* sX_lo = sX_hi + P;
    u16* sD_hi = (u16*)d_out;
    u16* sD_lo = sD_hi + P;

    // ---- y planes: workspace if big enough (race-free persistent-W GEMM);
    //      else y aliases dst (row-exclusive fallback GEMM) ----
    const size_t yBytes = 2 * P * sizeof(u16);   // 51.2 MB
    int useWs = (d_ws != 0 && ws_size >= yBytes) ? 1 : 0;
    u16* wsY_hi = (u16*)d_ws;
    u16* wsY_lo = wsY_hi + P;

    int NB  = (N + 255) / 256;
    int NBE = (E + 255) / 256;
    int NBGF = (N + 127) / 128;   // 391 fallback GEMM blocks
    int NBA = (N + 3) / 4;        // 12500 agg blocks
    int NBQ = (int)((P / 4 + 255) / 256);

    // ---- preprocessing ----
    k_detect<<<1, 256, 0, stream>>>(ei, S_gflag, E);
    k_zero32<<<NB, 256, 0, stream>>>((unsigned int*)S_deg, N);
    k_deg<<<NBE, 256, 0, stream>>>(ei, S_gflag, S_deg, E, N);
    k_dinv<<<NB, 256, 0, stream>>>(S_deg, S_dinv, N);
    k_scan1<<<NB, 256, 0, stream>>>(S_deg, S_offs, S_bsum, N);
    k_scan2<<<1, 256, 0, stream>>>(S_bsum, S_bscan, NB);
    k_scan3<<<NB, 256, 0, stream>>>(S_offs, S_bscan, S_cursor, N, E);
    k_place<<<NBE, 256, 0, stream>>>(ei, S_gflag, eattr, S_cursor, S_row, S_ea, E, N);
    k_move<<<NBE, 256, 0, stream>>>(S_row, S_ea, S_dinv, S_offs, rowArr, eaP, dinvF, offsF, E, N);
    k_zero32<<<1, 256, 0, stream>>>((unsigned int*)diag, 256);
    k_precheckN<<<NB, 256, 0, stream>>>(offsF, S_cursor, dinvF, S_gflag, diag, N, E);
    k_precheckE<<<NBE, 256, 0, stream>>>(rowArr, diag, E, N);

    // ---- layers: even l -> dst = D(d_out), odd l -> dst = X; agg planes live in dst ----
    for (int l = 0; l < NLAYERS; ++l) {
        int even = (l % 2 == 0);
        u16* dst_hi = even ? sD_hi : sX_hi;
        u16* dst_lo = even ? sD_lo : sX_lo;
        const void* hinA; const u16* hin_lo; int hf32;
        if (l == 0) { hinA = (const void*)x; hin_lo = 0; hf32 = 1; }
        else if (even) { hinA = (const void*)sX_hi; hin_lo = sX_lo; hf32 = 0; }
        else { hinA = (const void*)sD_hi; hin_lo = sD_lo; hf32 = 0; }

        u16* y_hi = useWs ? wsY_hi : dst_hi;
        u16* y_lo = useWs ? wsY_lo : dst_lo;

        k_wsplit<<<64, 256, 0, stream>>>(mlp_w + (size_t)l * 512 * HID, wpH, wpL, colsum);
        k_agg<<<NBA, 256, 0, stream>>>(hinA, hin_lo, hf32, offsF, rowArr, eaP, dinvF,
                                       ew1 + (size_t)l * 128, ew2 + (size_t)l * 384,
                                       dst_hi, dst_lo, diag, N);
        if (useWs) {
            MPNN_79044578115931_kernel<<<256, 512, 0, stream>>>(
                hinA, hin_lo, hf32, dst_hi, dst_lo, wpH, wpL,
                mlp_b + (size_t)l * HID, y_hi, y_lo, colsum, colsq, diag, N);
        } else {
            k_gemm_fb<<<NBGF, 256, 0, stream>>>(
                hinA, hin_lo, hf32, dst_hi, dst_lo, wpH, wpL,
                mlp_b + (size_t)l * HID, y_hi, y_lo, colsum, colsq, diag, N);
        }
        k_bnscale<<<1, 256, 0, stream>>>(colsum, colsq,
                                         bn_g + (size_t)l * HID, bn_b + (size_t)l * HID,
                                         scaleF, shiftF, diag, N);
        int finalL = (l == NLAYERS - 1) ? 1 : 0;
        int relu = finalL ? 0 : 1;
        // final: fp32 into X buffer, then copy back to d_out
        k_bnapply<<<NBQ, 256, 0, stream>>>(y_hi, y_lo, dst_hi, dst_lo, scaleF, shiftF,
                                           (float*)d_in[0], finalL, relu, (int)P);
    }

    hipMemcpyAsync(d_out, d_in[0], P * 4, hipMemcpyDeviceToDevice, stream);
    k_encode<<<1, 64, 0, stream>>>(diag, (float*)d_out);
}

// Round 7
// 1163.004 us; speedup vs baseline: 1.8704x; 1.8704x over previous
//
#include <hip/hip_runtime.h>
#include <stdint.h>

typedef short short8 __attribute__((ext_vector_type(8)));
typedef float f32x4 __attribute__((ext_vector_type(4)));
typedef unsigned short u16;

#define HID 256
#define NLAYERS 5
#define BN_EPS 1e-5f

__device__ __forceinline__ float bf2f(u16 u) {
    union { unsigned int i; float f; } v;
    v.i = ((unsigned int)u) << 16;
    return v.f;
}
__device__ __forceinline__ u16 f2bf(float f) {
    union { float f; unsigned int i; } v;
    v.f = f;
    unsigned int r = v.i + 0x7FFFu + ((v.i >> 16) & 1u);   // RNE
    return (u16)(r >> 16);
}
// split fp32 -> (hi, lo) bf16 pair: hi+lo ~ 17-bit mantissa approximation
__device__ __forceinline__ void split_bf(float f, u16& hi, u16& lo) {
    hi = f2bf(f);
    lo = f2bf(f - bf2f(hi));
}

// 16-B direct global->LDS copy (vmcnt-tracked; drained by __syncthreads).
__device__ __forceinline__ void gl_lds16(const void* gsrc, void* ldst) {
    const __attribute__((address_space(1))) unsigned int* g =
        reinterpret_cast<const __attribute__((address_space(1))) unsigned int*>(
            reinterpret_cast<uintptr_t>(gsrc));
    __attribute__((address_space(3))) unsigned int* l =
        reinterpret_cast<__attribute__((address_space(3))) unsigned int*>(
            reinterpret_cast<uintptr_t>(ldst));
    __builtin_amdgcn_global_load_lds(g, l, 16, 0, 0);
}

// ---------------- utility ----------------

__global__ __launch_bounds__(256) void k_zero32(unsigned int* p, int n) {
    int i = blockIdx.x * 256 + threadIdx.x;
    if (i < n) p[i] = 0u;
}

// ---------------- graph preprocessing (staged in d_out) ----------------

__global__ __launch_bounds__(256) void k_detect(const int* ei, int* flag, int E) {
    __shared__ int nz;
    if (threadIdx.x == 0) nz = 0;
    __syncthreads();
    int lim = (2 * E < 4096) ? 2 * E : 4096;
    int c = 0;
    for (int i = threadIdx.x; 2 * i + 1 < lim; i += 256) c += (ei[2 * i + 1] != 0);
    atomicAdd(&nz, c);
    __syncthreads();
    if (threadIdx.x == 0) flag[0] = (nz == 0) ? 1 : 0;   // 1 => int64 layout
}

__global__ __launch_bounds__(256) void k_deg(const int* ei, const int* flag, int* deg, int E, int N) {
    int e = blockIdx.x * 256 + threadIdx.x;
    if (e >= E) return;
    int w = flag[0];
    int col = w ? ei[2 * (E + e)] : ei[E + e];
    if ((unsigned)col < (unsigned)N) atomicAdd(&deg[col], 1);
}

__global__ __launch_bounds__(256) void k_dinv(const int* deg, float* dinv, int N) {
    int n = blockIdx.x * 256 + threadIdx.x;
    if (n < N) { int d = deg[n]; dinv[n] = d > 0 ? rsqrtf((float)d) : 0.0f; }
}

__global__ __launch_bounds__(256) void k_scan1(const int* deg, int* offs, int* bsum, int N) {
    __shared__ int s[256];
    int tid = threadIdx.x;
    int i = blockIdx.x * 256 + tid;
    int v = (i < N) ? deg[i] : 0;
    s[tid] = v;
    __syncthreads();
    for (int off = 1; off < 256; off <<= 1) {
        int t = (tid >= off) ? s[tid - off] : 0;
        __syncthreads();
        s[tid] += t;
        __syncthreads();
    }
    if (i < N) offs[i] = s[tid] - v;
    if (tid == 255) bsum[blockIdx.x] = s[tid];
}

__global__ __launch_bounds__(256) void k_scan2(const int* bsum, int* bscan, int NB) {
    __shared__ int s[256];
    int tid = threadIdx.x;
    int v = (tid < NB) ? bsum[tid] : 0;
    s[tid] = v;
    __syncthreads();
    for (int off = 1; off < 256; off <<= 1) {
        int t = (tid >= off) ? s[tid - off] : 0;
        __syncthreads();
        s[tid] += t;
        __syncthreads();
    }
    bscan[tid] = s[tid] - v;
}

__global__ __launch_bounds__(256) void k_scan3(int* offs, const int* bscan, int* cursor, int N, int E) {
    int i = blockIdx.x * 256 + threadIdx.x;
    if (i < N) {
        int o = offs[i] + bscan[blockIdx.x];
        offs[i] = o;
        cursor[i] = o;
    }
    if (i == 0) offs[N] = E;
}

__global__ __launch_bounds__(256) void k_place(const int* ei, const int* flag, const float4* eattr,
                                               int* cursor, int* srow, float4* sea, int E, int N) {
    int e = blockIdx.x * 256 + threadIdx.x;
    if (e >= E) return;
    int w = flag[0];
    int r = w ? ei[2 * e] : ei[e];
    int c = w ? ei[2 * (E + e)] : ei[E + e];
    if ((unsigned)c >= (unsigned)N) return;
    int p = atomicAdd(&cursor[c], 1);
    srow[p] = r;
    sea[p] = eattr[e];
}

__global__ __launch_bounds__(256) void k_move(const int* srow, const float4* sea, const float* sdinv,
                                              const int* soffs, int* rowArr, float4* eaP,
                                              float* dinvF, int* offsF, int E, int N) {
    int i = blockIdx.x * 256 + threadIdx.x;
    if (i < E) { rowArr[i] = srow[i]; eaP[i] = sea[i]; }
    if (i < N) dinvF[i] = sdinv[i];
    if (i <= N) offsF[i] = soffs[i];
}

__global__ __launch_bounds__(256) void k_precheckN(const int* offsF, const int* cursor, const float* dinvF,
                                                   const int* gflag, int* diag, int N, int E) {
    int i = blockIdx.x * 256 + threadIdx.x;
    if (i < N) {
        if (offsF[i + 1] < offsF[i]) atomicOr(&diag[0], 1);
        if (cursor[i] != offsF[i + 1]) atomicOr(&diag[0], 2);
        float d = dinvF[i];
        if (!(d == d) || fabsf(d) > 1e10f) atomicOr(&diag[0], 4);
    }
    if (i == 0) {
        if (offsF[N] != E) atomicOr(&diag[0], 8);
        diag[7] = gflag[0];
    }
}
__global__ __launch_bounds__(256) void k_precheckE(const int* rowArr, int* diag, int E, int N) {
    int p = blockIdx.x * 256 + threadIdx.x;
    if (p < E && (unsigned)rowArr[p] >= (unsigned)N) atomicOr(&diag[0], 16);
}

// Per-layer: split W (fp32 512x256 row-major) into bf16 hi/lo planes in MFMA
// B-fragment order, kb-major: frag t = kb*1024 + nbg*64 + lane holds
// W[kb*32 + (lane>>4)*8 + j][nbg*16 + (lane&15)], j=0..7.
// Block 0 also zeroes the BN stats accumulators (512 floats at colsum).
__global__ __launch_bounds__(256) void k_wsplit(const float* W, u16* wpH, u16* wpL, float* colsum) {
    if (blockIdx.x == 0) {
        colsum[threadIdx.x] = 0.f;
        colsum[256 + threadIdx.x] = 0.f;
    }
    int t = blockIdx.x * 256 + threadIdx.x;   // 64 blocks -> 16384 frags
    int lane = t & 63;
    int nbg = (t >> 6) & 15;
    int kb = t >> 10;
    int quad = lane >> 4, nl = lane & 15;
    const float* src = W + (size_t)(kb * 32 + quad * 8) * HID + nbg * 16 + nl;
    short8 vh, vl;
#pragma unroll
    for (int j = 0; j < 8; ++j) {
        u16 h, l;
        split_bf(src[(size_t)j * HID], h, l);
        vh[j] = (short)h;
        vl[j] = (short)l;
    }
    *((short8*)wpH + t) = vh;
    *((short8*)wpL + t) = vl;
}

// ---------------- per-layer: aggregation (one wave per node), split output ----------------
#define FEA(ea, j) ((ea).w * w1v[j] + (ea).x * w20[j] + (ea).y * w21[j] + (ea).z * w22[j])

__global__ __launch_bounds__(256) void k_agg(const void* hin_, const u16* hin_lo, int hf32,
                                             const int* offs, const int* rowArr, const float4* eaP,
                                             const float* dinv, const float* ew1, const float* ew2,
                                             u16* agg_hi, u16* agg_lo, int* diag, int M) {
    int lane = threadIdx.x & 63, wave = threadIdx.x >> 6;
    int n = blockIdx.x * 4 + wave;

    float w1v[4] = {0.f, 0.f, 0.f, 0.f};
    float w20[4] = {0.f, 0.f, 0.f, 0.f};
    float w21[4] = {0.f, 0.f, 0.f, 0.f};
    float w22[4] = {0.f, 0.f, 0.f, 0.f};
    if (lane < 32) {
        int c = lane * 4;
#pragma unroll
        for (int j = 0; j < 4; ++j) w1v[j] = ew1[c + j];
    } else {
        int cc = (lane - 32) * 4;
#pragma unroll
        for (int j = 0; j < 4; ++j) {
            w20[j] = ew2[cc + j];
            w21[j] = ew2[128 + cc + j];
            w22[j] = ew2[256 + cc + j];
        }
    }

    if (n >= M) return;
    float dn = dinv[n];
    int s = offs[n], e = offs[n + 1];
    float a0 = 0.f, a1 = 0.f, a2 = 0.f, a3 = 0.f;
    int p = s;

    if (hf32) {
        for (; p + 4 <= e; p += 4) {
            int r0 = rowArr[p + 0], r1 = rowArr[p + 1], r2 = rowArr[p + 2], r3 = rowArr[p + 3];
            float4 ea0 = eaP[p + 0], ea1 = eaP[p + 1], ea2 = eaP[p + 2], ea3 = eaP[p + 3];
            float4 hv0 = *((const float4*)hin_ + (size_t)r0 * 64 + lane);
            float4 hv1 = *((const float4*)hin_ + (size_t)r1 * 64 + lane);
            float4 hv2 = *((const float4*)hin_ + (size_t)r2 * 64 + lane);
            float4 hv3 = *((const float4*)hin_ + (size_t)r3 * 64 + lane);
            float n0 = dn * dinv[r0], n1 = dn * dinv[r1], n2 = dn * dinv[r2], n3 = dn * dinv[r3];
            a0 += n0 * (hv0.x + FEA(ea0, 0)) + n1 * (hv1.x + FEA(ea1, 0))
                + n2 * (hv2.x + FEA(ea2, 0)) + n3 * (hv3.x + FEA(ea3, 0));
            a1 += n0 * (hv0.y + FEA(ea0, 1)) + n1 * (hv1.y + FEA(ea1, 1))
                + n2 * (hv2.y + FEA(ea2, 1)) + n3 * (hv3.y + FEA(ea3, 1));
            a2 += n0 * (hv0.z + FEA(ea0, 2)) + n1 * (hv1.z + FEA(ea1, 2))
                + n2 * (hv2.z + FEA(ea2, 2)) + n3 * (hv3.z + FEA(ea3, 2));
            a3 += n0 * (hv0.w + FEA(ea0, 3)) + n1 * (hv1.w + FEA(ea1, 3))
                + n2 * (hv2.w + FEA(ea2, 3)) + n3 * (hv3.w + FEA(ea3, 3));
        }
        for (; p < e; ++p) {
            int r = rowArr[p];
            float4 ea = eaP[p];
            float nrm = dn * dinv[r];
            float4 hv = *((const float4*)hin_ + (size_t)r * 64 + lane);
            a0 += nrm * (hv.x + FEA(ea, 0));
            a1 += nrm * (hv.y + FEA(ea, 1));
            a2 += nrm * (hv.z + FEA(ea, 2));
            a3 += nrm * (hv.w + FEA(ea, 3));
        }
    } else {
        for (; p + 4 <= e; p += 4) {
            int r0 = rowArr[p + 0], r1 = rowArr[p + 1], r2 = rowArr[p + 2], r3 = rowArr[p + 3];
            float4 ea0 = eaP[p + 0], ea1 = eaP[p + 1], ea2 = eaP[p + 2], ea3 = eaP[p + 3];
            ushort4 hh0 = *((const ushort4*)hin_ + (size_t)r0 * 64 + lane);
            ushort4 hl0 = *((const ushort4*)hin_lo + (size_t)r0 * 64 + lane);
            ushort4 hh1 = *((const ushort4*)hin_ + (size_t)r1 * 64 + lane);
            ushort4 hl1 = *((const ushort4*)hin_lo + (size_t)r1 * 64 + lane);
            ushort4 hh2 = *((const ushort4*)hin_ + (size_t)r2 * 64 + lane);
            ushort4 hl2 = *((const ushort4*)hin_lo + (size_t)r2 * 64 + lane);
            ushort4 hh3 = *((const ushort4*)hin_ + (size_t)r3 * 64 + lane);
            ushort4 hl3 = *((const ushort4*)hin_lo + (size_t)r3 * 64 + lane);
            float n0 = dn * dinv[r0], n1 = dn * dinv[r1], n2 = dn * dinv[r2], n3 = dn * dinv[r3];
            a0 += n0 * (bf2f(hh0.x) + bf2f(hl0.x) + FEA(ea0, 0))
                + n1 * (bf2f(hh1.x) + bf2f(hl1.x) + FEA(ea1, 0))
                + n2 * (bf2f(hh2.x) + bf2f(hl2.x) + FEA(ea2, 0))
                + n3 * (bf2f(hh3.x) + bf2f(hl3.x) + FEA(ea3, 0));
            a1 += n0 * (bf2f(hh0.y) + bf2f(hl0.y) + FEA(ea0, 1))
                + n1 * (bf2f(hh1.y) + bf2f(hl1.y) + FEA(ea1, 1))
                + n2 * (bf2f(hh2.y) + bf2f(hl2.y) + FEA(ea2, 1))
                + n3 * (bf2f(hh3.y) + bf2f(hl3.y) + FEA(ea3, 1));
            a2 += n0 * (bf2f(hh0.z) + bf2f(hl0.z) + FEA(ea0, 2))
                + n1 * (bf2f(hh1.z) + bf2f(hl1.z) + FEA(ea1, 2))
                + n2 * (bf2f(hh2.z) + bf2f(hl2.z) + FEA(ea2, 2))
                + n3 * (bf2f(hh3.z) + bf2f(hl3.z) + FEA(ea3, 2));
            a3 += n0 * (bf2f(hh0.w) + bf2f(hl0.w) + FEA(ea0, 3))
                + n1 * (bf2f(hh1.w) + bf2f(hl1.w) + FEA(ea1, 3))
                + n2 * (bf2f(hh2.w) + bf2f(hl2.w) + FEA(ea2, 3))
                + n3 * (bf2f(hh3.w) + bf2f(hl3.w) + FEA(ea3, 3));
        }
        for (; p < e; ++p) {
            int r = rowArr[p];
            float4 ea = eaP[p];
            float nrm = dn * dinv[r];
            ushort4 hh = *((const ushort4*)hin_ + (size_t)r * 64 + lane);
            ushort4 hl = *((const ushort4*)hin_lo + (size_t)r * 64 + lane);
            a0 += nrm * (bf2f(hh.x) + bf2f(hl.x) + FEA(ea, 0));
            a1 += nrm * (bf2f(hh.y) + bf2f(hl.y) + FEA(ea, 1));
            a2 += nrm * (bf2f(hh.z) + bf2f(hl.z) + FEA(ea, 2));
            a3 += nrm * (bf2f(hh.w) + bf2f(hl.w) + FEA(ea, 3));
        }
    }

    int bad = 0;
    if (!(a0 == a0)) { a0 = 777.f; bad++; }
    if (!(a1 == a1)) { a1 = 777.f; bad++; }
    if (!(a2 == a2)) { a2 = 777.f; bad++; }
    if (!(a3 == a3)) { a3 = 777.f; bad++; }
    if (bad) atomicAdd(&diag[1], bad);
    ushort4 oh, ol;
    split_bf(a0, oh.x, ol.x);
    split_bf(a1, oh.y, ol.y);
    split_bf(a2, oh.z, ol.z);
    split_bf(a3, oh.w, ol.w);
    *((ushort4*)agg_hi + (size_t)n * 64 + lane) = oh;
    *((ushort4*)agg_lo + (size_t)n * 64 + lane) = ol;
}

// ---------------- per-layer: split-precision MFMA GEMM + bias/ReLU + BN stats ----------------
// y = relu(A·W + bias); A = [h | agg] hi/lo pairs; acc = Ahi·Whi + Alo·Whi + Ahi·Wlo.
// v7: ROW-EXCLUSIVE (in-place safe: block owns its 32 rows; all global agg reads happen
// before the last drain barrier, epilogue writes after) + high residency:
// 32 rows x 256 cols per block, 1563 blocks, 256 threads (4 waves).
// Wave w computes nbg in [4w,4w+4) for both 16-row groups (8 f32x4 acc = 32 VGPR).
// LDS 32KB B-stage + 2KB stats = 34.8KB -> 4 blocks/CU (~16 waves/CU): while one block
// sits in its vmcnt(0)+barrier drain, 3 other blocks' waves keep SIMDs + L2 busy —
// the amortization v2 (1.5 blocks/CU, 90us) and v6-persistent (1 block/CU, 2 waves/SIMD,
// 323us + 9x traffic) both lacked. B-stage is L2-resident (512KB W per XCD).
__global__ __launch_bounds__(256, 4) void MPNN_79044578115931_kernel(
        const void* hinA_, const u16* hinA_lo, int hf32,
        const u16* agg_hi, const u16* agg_lo,
        const u16* wpH, const u16* wpL, const float* bias,
        u16* y_hi, u16* y_lo,
        float* colsum, float* colsumsq, int* diag, int M) {
    __shared__ __align__(16) u16 bstage[16384];   // 32 KB: hi frags [0,8192), lo [8192,16384)
    __shared__ float lsum[256];
    __shared__ float lsq[256];

    int tid = threadIdx.x;
    int lane = tid & 63, wave = tid >> 6;
    int quad = lane >> 4, nl = lane & 15;
    int mBase = blockIdx.x * 32;
    int nbg0 = wave * 4;              // this wave's 4 column groups
    int rowA0 = mBase + nl;           // row-group 0
    int rowA1 = mBase + 16 + nl;      // row-group 1
    if (rowA0 >= M) rowA0 = M - 1;
    if (rowA1 >= M) rowA1 = M - 1;

    lsum[tid] = 0.f;
    lsq[tid] = 0.f;

    f32x4 acc0[4], acc1[4];
#pragma unroll
    for (int i = 0; i < 4; ++i) {
        acc0[i] = {0.f, 0.f, 0.f, 0.f};
        acc1[i] = {0.f, 0.f, 0.f, 0.f};
    }

    for (int kb = 0; kb < 16; ++kb) {
        __syncthreads();   // previous step's LDS reads done before overwrite (covers lsum init too)

        // stage B kb-slice: 1024 hi + 1024 lo frags x 16 B; thread t stages frags {i*256+t}
        const u16* srcH = wpH + (size_t)kb * 8192;
        const u16* srcL = wpL + (size_t)kb * 8192;
#pragma unroll
        for (int i = 0; i < 4; ++i) {
            int ci = i * 256 + tid;
            gl_lds16(srcH + ci * 8, &bstage[ci * 8]);
            gl_lds16(srcL + ci * 8, &bstage[8192 + ci * 8]);
        }

        // A fragments for this K-step (both row-groups)
        short8 a0h, a0l, a1h, a1l;
        if (kb < 8) {
            int k0 = kb * 32 + quad * 8;
            if (hf32) {
                const float* hp0 = (const float*)hinA_ + (size_t)rowA0 * HID + k0;
                const float* hp1 = (const float*)hinA_ + (size_t)rowA1 * HID + k0;
#pragma unroll
                for (int j = 0; j < 8; ++j) {
                    u16 h, l;
                    split_bf(hp0[j], h, l);
                    a0h[j] = (short)h; a0l[j] = (short)l;
                    split_bf(hp1[j], h, l);
                    a1h[j] = (short)h; a1l[j] = (short)l;
                }
            } else {
                a0h = *(const short8*)((const u16*)hinA_ + (size_t)rowA0 * HID + k0);
                a0l = *(const short8*)(hinA_lo + (size_t)rowA0 * HID + k0);
                a1h = *(const short8*)((const u16*)hinA_ + (size_t)rowA1 * HID + k0);
                a1l = *(const short8*)(hinA_lo + (size_t)rowA1 * HID + k0);
            }
        } else {
            int k0 = (kb - 8) * 32 + quad * 8;
            a0h = *(const short8*)(agg_hi + (size_t)rowA0 * HID + k0);
            a0l = *(const short8*)(agg_lo + (size_t)rowA0 * HID + k0);
            a1h = *(const short8*)(agg_hi + (size_t)rowA1 * HID + k0);
            a1l = *(const short8*)(agg_lo + (size_t)rowA1 * HID + k0);
        }

        __syncthreads();   // drains vmcnt(0): staged B + A frags ready

        const short8* bbase = (const short8*)bstage;
#pragma unroll
        for (int j = 0; j < 4; ++j) {
            short8 bh = bbase[(nbg0 + j) * 64 + lane];
            short8 bl = bbase[1024 + (nbg0 + j) * 64 + lane];
            acc0[j] = __builtin_amdgcn_mfma_f32_16x16x32_bf16(a0h, bh, acc0[j], 0, 0, 0);
            acc1[j] = __builtin_amdgcn_mfma_f32_16x16x32_bf16(a1h, bh, acc1[j], 0, 0, 0);
            acc0[j] = __builtin_amdgcn_mfma_f32_16x16x32_bf16(a0l, bh, acc0[j], 0, 0, 0);
            acc1[j] = __builtin_amdgcn_mfma_f32_16x16x32_bf16(a1l, bh, acc1[j], 0, 0, 0);
            acc0[j] = __builtin_amdgcn_mfma_f32_16x16x32_bf16(a0h, bl, acc0[j], 0, 0, 0);
            acc1[j] = __builtin_amdgcn_mfma_f32_16x16x32_bf16(a1h, bl, acc1[j], 0, 0, 0);
        }
    }

    // After the last drain barrier all global agg reads are complete -> in-place y write safe.
    __syncthreads();

    int badY = 0;
#pragma unroll
    for (int j = 0; j < 4; ++j) {
        int c = (nbg0 + j) * 16 + nl;
        float bvv = bias[c];
        float s = 0.f, q = 0.f;
#pragma unroll
        for (int r = 0; r < 4; ++r) {
            int m = mBase + quad * 4 + r;
            if (m < M) {
                float v = acc0[j][r] + bvv;
                if (!(v == v)) { v = 777.f; badY++; }
                v = v > 0.f ? v : 0.f;
                u16 h, l;
                split_bf(v, h, l);
                y_hi[(size_t)m * HID + c] = h;
                y_lo[(size_t)m * HID + c] = l;
                s += v;
                q += v * v;
            }
        }
#pragma unroll
        for (int r = 0; r < 4; ++r) {
            int m = mBase + 16 + quad * 4 + r;
            if (m < M) {
                float v = acc1[j][r] + bvv;
                if (!(v == v)) { v = 777.f; badY++; }
                v = v > 0.f ? v : 0.f;
                u16 h, l;
                split_bf(v, h, l);
                y_hi[(size_t)m * HID + c] = h;
                y_lo[(size_t)m * HID + c] = l;
                s += v;
                q += v * v;
            }
        }
        atomicAdd(&lsum[c], s);
        atomicAdd(&lsq[c], q);
    }
    if (badY) atomicAdd(&diag[2], badY);
    __syncthreads();
    atomicAdd(&colsum[tid], lsum[tid]);
    atomicAdd(&colsumsq[tid], lsq[tid]);
}

__global__ __launch_bounds__(256) void k_bnscale(const float* colsum, const float* colsumsq,
                                                 const float* g, const float* b,
                                                 float* scale, float* shift, int* diag, int M) {
    int c = threadIdx.x;
    float mu = colsum[c] / (float)M;
    float var = colsumsq[c] / (float)M - mu * mu;
    if (!(mu == mu) || !(var == var) || var > 1e30f) atomicAdd(&diag[3], 1);
    if (var < 0.f) var = 0.f;
    float sc = rsqrtf(var + BN_EPS) * g[c];
    scale[c] = sc;
    shift[c] = b[c] - mu * sc;
}

// BN apply: reads y from src planes; non-final writes dst planes (+ReLU);
// final writes fp32 to outf. src may equal dst (in-place).
__global__ __launch_bounds__(256) void k_bnapply(const u16* src_hi, const u16* src_lo,
                                                 u16* dst_hi, u16* dst_lo,
                                                 const float* scale, const float* shift,
                                                 float* outf, int finalL, int relu, int total) {
    int q4 = blockIdx.x * 256 + threadIdx.x;
    int idx = q4 * 4;
    if (idx >= total) return;
    int c = idx & (HID - 1);
    ushort4 vh = *((const ushort4*)src_hi + q4);
    ushort4 vl = *((const ushort4*)src_lo + q4);
    float o0 = scale[c + 0] * (bf2f(vh.x) + bf2f(vl.x)) + shift[c + 0];
    float o1 = scale[c + 1] * (bf2f(vh.y) + bf2f(vl.y)) + shift[c + 1];
    float o2 = scale[c + 2] * (bf2f(vh.z) + bf2f(vl.z)) + shift[c + 2];
    float o3 = scale[c + 3] * (bf2f(vh.w) + bf2f(vl.w)) + shift[c + 3];
    if (relu) {
        o0 = o0 > 0.f ? o0 : 0.f;
        o1 = o1 > 0.f ? o1 : 0.f;
        o2 = o2 > 0.f ? o2 : 0.f;
        o3 = o3 > 0.f ? o3 : 0.f;
    }
    if (finalL) {
        float4 ov; ov.x = o0; ov.y = o1; ov.z = o2; ov.w = o3;
        *((float4*)outf + q4) = ov;
    } else {
        ushort4 oh, ol;
        split_bf(o0, oh.x, ol.x);
        split_bf(o1, oh.y, ol.y);
        split_bf(o2, oh.z, ol.z);
        split_bf(o3, oh.w, ol.w);
        *((ushort4*)dst_hi + q4) = oh;
        *((ushort4*)dst_lo + q4) = ol;
    }
}

// d_out[0] = (1+k+8*int64)*2^20 only if a check failed.
__global__ void k_encode(const int* diag, float* out) {
    if (threadIdx.x != 0 || blockIdx.x != 0) return;
    int k = -1;
    for (int i = 0; i < 4; ++i) if (diag[i] != 0) { k = i; break; }
    if (k < 0) return;
    out[0] = (float)(1 + k + (diag[7] != 0 ? 8 : 0)) * 1048576.0f;
}

// ---------------- launcher (zero workspace dependency) ----------------

extern "C" void kernel_launch(void* const* d_in, const int* in_sizes, int n_in,
                              void* d_out, int out_size, void* d_ws, size_t ws_size,
                              hipStream_t stream) {
    const float*  x     = (const float*)d_in[0];
    const int*    ei    = (const int*)d_in[1];
    const float4* eattr = (const float4*)d_in[2];
    const float*  mlp_w = (const float*)d_in[3];
    const float*  mlp_b = (const float*)d_in[4];
    const float*  ew1   = (const float*)d_in[5];
    const float*  ew2   = (const float*)d_in[6];
    const float*  bn_g  = (const float*)d_in[7];
    const float*  bn_b  = (const float*)d_in[8];
    (void)n_in; (void)out_size; (void)d_ws; (void)ws_size;

    const int N = in_sizes[0] / HID;   // 50000
    const int E = in_sizes[1] / 2;     // 320000
    const size_t P = (size_t)N * HID;  // plane elements

    // ---- CSR staging inside d_out (dead before layer 0 writes d_out) ----
    char* st = (char*)d_out;
    int*    S_deg    = (int*)   (st + 0);
    float*  S_dinv   = (float*) (st + 204800);
    int*    S_offs   = (int*)   (st + 409600);
    int*    S_cursor = (int*)   (st + 614400);
    int*    S_bsum   = (int*)   (st + 819200);
    int*    S_bscan  = (int*)   (st + 820224);
    int*    S_gflag  = (int*)   (st + 821248);
    int*    S_row    = (int*)   (st + 1048576);
    float4* S_ea     = (float4*)(st + 2621440);   // ends 7,741,440 < 51.2 MB

    // ---- small homes in edge_index buffer (>=2.56 MB); eattr buffer holds eaP ----
    char* eb = (char*)d_in[1];
    int*   rowArr = (int*)  (eb + 0);          // 1,280,000
    float* dinvF  = (float*)(eb + 1280000);    // 200,000
    int*   offsF  = (int*)  (eb + 1480000);    // 200,004
    float* colsum = (float*)(eb + 1680128);
    float* colsq  = (float*)(eb + 1681152);
    float* scaleF = (float*)(eb + 1682176);
    float* shiftF = (float*)(eb + 1683200);
    int*   diag   = (int*)  (eb + 1684224);    // 1 KB
    u16*   wpH    = (u16*)  (eb + 1685504);    // 256 KB -> ends 1,947,648
    u16*   wpL    = (u16*)  (eb + 1947648);    // 256 KB -> ends 2,209,792 <= 2,560,000
    float4* eaP   = (float4*)d_in[2];          // 5,120,000 exact

    // ---- h slots as bf16 hi/lo planes (each slot = 2 planes = 51.2 MB) ----
    u16* sX_hi = (u16*)d_in[0];          // x buffer (x consumed during layer 0)
    u16* sX_lo = sX_hi + P;
    u16* sD_hi = (u16*)d_out;
    u16* sD_lo = sD_hi + P;

    int NB  = (N + 255) / 256;
    int NBE = (E + 255) / 256;
    int NBG = (N + 31) / 32;      // 1563 GEMM blocks (32 rows each)
    int NBA = (N + 3) / 4;        // 12500 agg blocks (one wave per node)
    int NBQ = (int)((P / 4 + 255) / 256);

    // ---- preprocessing ----
    k_detect<<<1, 256, 0, stream>>>(ei, S_gflag, E);
    k_zero32<<<NB, 256, 0, stream>>>((unsigned int*)S_deg, N);
    k_deg<<<NBE, 256, 0, stream>>>(ei, S_gflag, S_deg, E, N);
    k_dinv<<<NB, 256, 0, stream>>>(S_deg, S_dinv, N);
    k_scan1<<<NB, 256, 0, stream>>>(S_deg, S_offs, S_bsum, N);
    k_scan2<<<1, 256, 0, stream>>>(S_bsum, S_bscan, NB);
    k_scan3<<<NB, 256, 0, stream>>>(S_offs, S_bscan, S_cursor, N, E);
    k_place<<<NBE, 256, 0, stream>>>(ei, S_gflag, eattr, S_cursor, S_row, S_ea, E, N);
    k_move<<<NBE, 256, 0, stream>>>(S_row, S_ea, S_dinv, S_offs, rowArr, eaP, dinvF, offsF, E, N);
    k_zero32<<<1, 256, 0, stream>>>((unsigned int*)diag, 256);
    k_precheckN<<<NB, 256, 0, stream>>>(offsF, S_cursor, dinvF, S_gflag, diag, N, E);
    k_precheckE<<<NBE, 256, 0, stream>>>(rowArr, diag, E, N);

    // ---- layers: even l -> dst = D(d_out), odd l -> dst = X; agg planes live in dst ----
    for (int l = 0; l < NLAYERS; ++l) {
        int even = (l % 2 == 0);
        u16* dst_hi = even ? sD_hi : sX_hi;
        u16* dst_lo = even ? sD_lo : sX_lo;
        const void* hinA; const u16* hin_lo; int hf32;
        if (l == 0) { hinA = (const void*)x; hin_lo = 0; hf32 = 1; }
        else if (even) { hinA = (const void*)sX_hi; hin_lo = sX_lo; hf32 = 0; }
        else { hinA = (const void*)sD_hi; hin_lo = sD_lo; hf32 = 0; }

        k_wsplit<<<64, 256, 0, stream>>>(mlp_w + (size_t)l * 512 * HID, wpH, wpL, colsum);
        k_agg<<<NBA, 256, 0, stream>>>(hinA, hin_lo, hf32, offsF, rowArr, eaP, dinvF,
                                       ew1 + (size_t)l * 128, ew2 + (size_t)l * 384,
                                       dst_hi, dst_lo, diag, N);
        MPNN_79044578115931_kernel<<<NBG, 256, 0, stream>>>(
            hinA, hin_lo, hf32, dst_hi, dst_lo, wpH, wpL,
            mlp_b + (size_t)l * HID, dst_hi, dst_lo, colsum, colsq, diag, N);
        k_bnscale<<<1, 256, 0, stream>>>(colsum, colsq,
                                         bn_g + (size_t)l * HID, bn_b + (size_t)l * HID,
                                         scaleF, shiftF, diag, N);
        int finalL = (l == NLAYERS - 1) ? 1 : 0;
        int relu = finalL ? 0 : 1;
        // final: expand planes -> fp32 into X buffer, then copy back to d_out
        k_bnapply<<<NBQ, 256, 0, stream>>>(dst_hi, dst_lo, dst_hi, dst_lo, scaleF, shiftF,
                                           (float*)d_in[0], finalL, relu, (int)P);
    }

    hipMemcpyAsync(d_out, d_in[0], P * 4, hipMemcpyDeviceToDevice, stream);
    k_encode<<<1, 64, 0, stream>>>(diag, (float*)d_out);
}

// Round 8
// 926.590 us; speedup vs baseline: 2.3477x; 1.2551x over previous
//
#include <hip/hip_runtime.h>
#include <stdint.h>

typedef short short8 __attribute__((ext_vector_type(8)));
typedef float f32x4 __attribute__((ext_vector_type(4)));
typedef unsigned short u16;

#define HID 256
#define NLAYERS 5
#define BN_EPS 1e-5f

__device__ __forceinline__ float bf2f(u16 u) {
    union { unsigned int i; float f; } v;
    v.i = ((unsigned int)u) << 16;
    return v.f;
}
__device__ __forceinline__ u16 f2bf(float f) {
    union { float f; unsigned int i; } v;
    v.f = f;
    unsigned int r = v.i + 0x7FFFu + ((v.i >> 16) & 1u);   // RNE
    return (u16)(r >> 16);
}
// split fp32 -> (hi, lo) bf16 pair: hi+lo ~ 17-bit mantissa approximation
__device__ __forceinline__ void split_bf(float f, u16& hi, u16& lo) {
    hi = f2bf(f);
    lo = f2bf(f - bf2f(hi));
}

// 16-B direct global->LDS copy (vmcnt-tracked; drained by __syncthreads).
__device__ __forceinline__ void gl_lds16(const void* gsrc, void* ldst) {
    const __attribute__((address_space(1))) unsigned int* g =
        reinterpret_cast<const __attribute__((address_space(1))) unsigned int*>(
            reinterpret_cast<uintptr_t>(gsrc));
    __attribute__((address_space(3))) unsigned int* l =
        reinterpret_cast<__attribute__((address_space(3))) unsigned int*>(
            reinterpret_cast<uintptr_t>(ldst));
    __builtin_amdgcn_global_load_lds(g, l, 16, 0, 0);
}

// ---------------- utility ----------------

__global__ __launch_bounds__(256) void k_zero32(unsigned int* p, int n) {
    int i = blockIdx.x * 256 + threadIdx.x;
    if (i < n) p[i] = 0u;
}

// ---------------- graph preprocessing (staged in d_out) ----------------

__global__ __launch_bounds__(256) void k_detect(const int* ei, int* flag, int E) {
    __shared__ int nz;
    if (threadIdx.x == 0) nz = 0;
    __syncthreads();
    int lim = (2 * E < 4096) ? 2 * E : 4096;
    int c = 0;
    for (int i = threadIdx.x; 2 * i + 1 < lim; i += 256) c += (ei[2 * i + 1] != 0);
    atomicAdd(&nz, c);
    __syncthreads();
    if (threadIdx.x == 0) flag[0] = (nz == 0) ? 1 : 0;   // 1 => int64 layout
}

__global__ __launch_bounds__(256) void k_deg(const int* ei, const int* flag, int* deg, int E, int N) {
    int e = blockIdx.x * 256 + threadIdx.x;
    if (e >= E) return;
    int w = flag[0];
    int col = w ? ei[2 * (E + e)] : ei[E + e];
    if ((unsigned)col < (unsigned)N) atomicAdd(&deg[col], 1);
}

__global__ __launch_bounds__(256) void k_dinv(const int* deg, float* dinv, int N) {
    int n = blockIdx.x * 256 + threadIdx.x;
    if (n < N) { int d = deg[n]; dinv[n] = d > 0 ? rsqrtf((float)d) : 0.0f; }
}

__global__ __launch_bounds__(256) void k_scan1(const int* deg, int* offs, int* bsum, int N) {
    __shared__ int s[256];
    int tid = threadIdx.x;
    int i = blockIdx.x * 256 + tid;
    int v = (i < N) ? deg[i] : 0;
    s[tid] = v;
    __syncthreads();
    for (int off = 1; off < 256; off <<= 1) {
        int t = (tid >= off) ? s[tid - off] : 0;
        __syncthreads();
        s[tid] += t;
        __syncthreads();
    }
    if (i < N) offs[i] = s[tid] - v;
    if (tid == 255) bsum[blockIdx.x] = s[tid];
}

__global__ __launch_bounds__(256) void k_scan2(const int* bsum, int* bscan, int NB) {
    __shared__ int s[256];
    int tid = threadIdx.x;
    int v = (tid < NB) ? bsum[tid] : 0;
    s[tid] = v;
    __syncthreads();
    for (int off = 1; off < 256; off <<= 1) {
        int t = (tid >= off) ? s[tid - off] : 0;
        __syncthreads();
        s[tid] += t;
        __syncthreads();
    }
    bscan[tid] = s[tid] - v;
}

__global__ __launch_bounds__(256) void k_scan3(int* offs, const int* bscan, int* cursor, int N, int E) {
    int i = blockIdx.x * 256 + threadIdx.x;
    if (i < N) {
        int o = offs[i] + bscan[blockIdx.x];
        offs[i] = o;
        cursor[i] = o;
    }
    if (i == 0) offs[N] = E;
}

__global__ __launch_bounds__(256) void k_place(const int* ei, const int* flag, const float4* eattr,
                                               int* cursor, int* srow, float4* sea, int E, int N) {
    int e = blockIdx.x * 256 + threadIdx.x;
    if (e >= E) return;
    int w = flag[0];
    int r = w ? ei[2 * e] : ei[e];
    int c = w ? ei[2 * (E + e)] : ei[E + e];
    if ((unsigned)c >= (unsigned)N) return;
    int p = atomicAdd(&cursor[c], 1);
    srow[p] = r;
    sea[p] = eattr[e];
}

__global__ __launch_bounds__(256) void k_move(const int* srow, const float4* sea, const float* sdinv,
                                              const int* soffs, int* rowArr, float4* eaP,
                                              float* dinvF, int* offsF, int E, int N) {
    int i = blockIdx.x * 256 + threadIdx.x;
    if (i < E) { rowArr[i] = srow[i]; eaP[i] = sea[i]; }
    if (i < N) dinvF[i] = sdinv[i];
    if (i <= N) offsF[i] = soffs[i];
}

__global__ __launch_bounds__(256) void k_precheckN(const int* offsF, const int* cursor, const float* dinvF,
                                                   const int* gflag, int* diag, int N, int E) {
    int i = blockIdx.x * 256 + threadIdx.x;
    if (i < N) {
        if (offsF[i + 1] < offsF[i]) atomicOr(&diag[0], 1);
        if (cursor[i] != offsF[i + 1]) atomicOr(&diag[0], 2);
        float d = dinvF[i];
        if (!(d == d) || fabsf(d) > 1e10f) atomicOr(&diag[0], 4);
    }
    if (i == 0) {
        if (offsF[N] != E) atomicOr(&diag[0], 8);
        diag[7] = gflag[0];
    }
}
__global__ __launch_bounds__(256) void k_precheckE(const int* rowArr, int* diag, int E, int N) {
    int p = blockIdx.x * 256 + threadIdx.x;
    if (p < E && (unsigned)rowArr[p] >= (unsigned)N) atomicOr(&diag[0], 16);
}

// Per-layer: split W (fp32 512x256 row-major) into bf16 hi/lo planes in MFMA
// B-fragment order, kb-major: frag t = kb*1024 + nbg*64 + lane holds
// W[kb*32 + (lane>>4)*8 + j][nbg*16 + (lane&15)], j=0..7.
// Block 0 also zeroes the BN stats accumulators (512 floats at colsum).
__global__ __launch_bounds__(256) void k_wsplit(const float* W, u16* wpH, u16* wpL, float* colsum) {
    if (blockIdx.x == 0) {
        colsum[threadIdx.x] = 0.f;
        colsum[256 + threadIdx.x] = 0.f;
    }
    int t = blockIdx.x * 256 + threadIdx.x;   // 64 blocks -> 16384 frags
    int lane = t & 63;
    int nbg = (t >> 6) & 15;
    int kb = t >> 10;
    int quad = lane >> 4, nl = lane & 15;
    const float* src = W + (size_t)(kb * 32 + quad * 8) * HID + nbg * 16 + nl;
    short8 vh, vl;
#pragma unroll
    for (int j = 0; j < 8; ++j) {
        u16 h, l;
        split_bf(src[(size_t)j * HID], h, l);
        vh[j] = (short)h;
        vl[j] = (short)l;
    }
    *((short8*)wpH + t) = vh;
    *((short8*)wpL + t) = vl;
}

// ---------------- per-layer: aggregation (one wave per node), split output ----------------
// v8: bf16 path gathers ONLY the hi plane (h_lo <= 2^-9|h| -> agg perturbation ~0.002,
// negligible vs absmax 0.125 / threshold 0.925). Halves the L3-bound gather volume
// (328 -> 164 MB/dispatch; k_agg is L3-BW-bound at ~5.5 TB/s effective).
#define FEA(ea, j) ((ea).w * w1v[j] + (ea).x * w20[j] + (ea).y * w21[j] + (ea).z * w22[j])

__global__ __launch_bounds__(256) void k_agg(const void* hin_, const u16* hin_lo, int hf32,
                                             const int* offs, const int* rowArr, const float4* eaP,
                                             const float* dinv, const float* ew1, const float* ew2,
                                             u16* agg_hi, u16* agg_lo, int* diag, int M) {
    (void)hin_lo;
    int lane = threadIdx.x & 63, wave = threadIdx.x >> 6;
    int n = blockIdx.x * 4 + wave;

    float w1v[4] = {0.f, 0.f, 0.f, 0.f};
    float w20[4] = {0.f, 0.f, 0.f, 0.f};
    float w21[4] = {0.f, 0.f, 0.f, 0.f};
    float w22[4] = {0.f, 0.f, 0.f, 0.f};
    if (lane < 32) {
        int c = lane * 4;
#pragma unroll
        for (int j = 0; j < 4; ++j) w1v[j] = ew1[c + j];
    } else {
        int cc = (lane - 32) * 4;
#pragma unroll
        for (int j = 0; j < 4; ++j) {
            w20[j] = ew2[cc + j];
            w21[j] = ew2[128 + cc + j];
            w22[j] = ew2[256 + cc + j];
        }
    }

    if (n >= M) return;
    float dn = dinv[n];
    int s = offs[n], e = offs[n + 1];
    float a0 = 0.f, a1 = 0.f, a2 = 0.f, a3 = 0.f;
    int p = s;

    if (hf32) {
        for (; p + 4 <= e; p += 4) {
            int r0 = rowArr[p + 0], r1 = rowArr[p + 1], r2 = rowArr[p + 2], r3 = rowArr[p + 3];
            float4 ea0 = eaP[p + 0], ea1 = eaP[p + 1], ea2 = eaP[p + 2], ea3 = eaP[p + 3];
            float4 hv0 = *((const float4*)hin_ + (size_t)r0 * 64 + lane);
            float4 hv1 = *((const float4*)hin_ + (size_t)r1 * 64 + lane);
            float4 hv2 = *((const float4*)hin_ + (size_t)r2 * 64 + lane);
            float4 hv3 = *((const float4*)hin_ + (size_t)r3 * 64 + lane);
            float n0 = dn * dinv[r0], n1 = dn * dinv[r1], n2 = dn * dinv[r2], n3 = dn * dinv[r3];
            a0 += n0 * (hv0.x + FEA(ea0, 0)) + n1 * (hv1.x + FEA(ea1, 0))
                + n2 * (hv2.x + FEA(ea2, 0)) + n3 * (hv3.x + FEA(ea3, 0));
            a1 += n0 * (hv0.y + FEA(ea0, 1)) + n1 * (hv1.y + FEA(ea1, 1))
                + n2 * (hv2.y + FEA(ea2, 1)) + n3 * (hv3.y + FEA(ea3, 1));
            a2 += n0 * (hv0.z + FEA(ea0, 2)) + n1 * (hv1.z + FEA(ea1, 2))
                + n2 * (hv2.z + FEA(ea2, 2)) + n3 * (hv3.z + FEA(ea3, 2));
            a3 += n0 * (hv0.w + FEA(ea0, 3)) + n1 * (hv1.w + FEA(ea1, 3))
                + n2 * (hv2.w + FEA(ea2, 3)) + n3 * (hv3.w + FEA(ea3, 3));
        }
        for (; p < e; ++p) {
            int r = rowArr[p];
            float4 ea = eaP[p];
            float nrm = dn * dinv[r];
            float4 hv = *((const float4*)hin_ + (size_t)r * 64 + lane);
            a0 += nrm * (hv.x + FEA(ea, 0));
            a1 += nrm * (hv.y + FEA(ea, 1));
            a2 += nrm * (hv.z + FEA(ea, 2));
            a3 += nrm * (hv.w + FEA(ea, 3));
        }
    } else {
        for (; p + 4 <= e; p += 4) {
            int r0 = rowArr[p + 0], r1 = rowArr[p + 1], r2 = rowArr[p + 2], r3 = rowArr[p + 3];
            float4 ea0 = eaP[p + 0], ea1 = eaP[p + 1], ea2 = eaP[p + 2], ea3 = eaP[p + 3];
            ushort4 hh0 = *((const ushort4*)hin_ + (size_t)r0 * 64 + lane);
            ushort4 hh1 = *((const ushort4*)hin_ + (size_t)r1 * 64 + lane);
            ushort4 hh2 = *((const ushort4*)hin_ + (size_t)r2 * 64 + lane);
            ushort4 hh3 = *((const ushort4*)hin_ + (size_t)r3 * 64 + lane);
            float n0 = dn * dinv[r0], n1 = dn * dinv[r1], n2 = dn * dinv[r2], n3 = dn * dinv[r3];
            a0 += n0 * (bf2f(hh0.x) + FEA(ea0, 0)) + n1 * (bf2f(hh1.x) + FEA(ea1, 0))
                + n2 * (bf2f(hh2.x) + FEA(ea2, 0)) + n3 * (bf2f(hh3.x) + FEA(ea3, 0));
            a1 += n0 * (bf2f(hh0.y) + FEA(ea0, 1)) + n1 * (bf2f(hh1.y) + FEA(ea1, 1))
                + n2 * (bf2f(hh2.y) + FEA(ea2, 1)) + n3 * (bf2f(hh3.y) + FEA(ea3, 1));
            a2 += n0 * (bf2f(hh0.z) + FEA(ea0, 2)) + n1 * (bf2f(hh1.z) + FEA(ea1, 2))
                + n2 * (bf2f(hh2.z) + FEA(ea2, 2)) + n3 * (bf2f(hh3.z) + FEA(ea3, 2));
            a3 += n0 * (bf2f(hh0.w) + FEA(ea0, 3)) + n1 * (bf2f(hh1.w) + FEA(ea1, 3))
                + n2 * (bf2f(hh2.w) + FEA(ea2, 3)) + n3 * (bf2f(hh3.w) + FEA(ea3, 3));
        }
        for (; p < e; ++p) {
            int r = rowArr[p];
            float4 ea = eaP[p];
            float nrm = dn * dinv[r];
            ushort4 hh = *((const ushort4*)hin_ + (size_t)r * 64 + lane);
            a0 += nrm * (bf2f(hh.x) + FEA(ea, 0));
            a1 += nrm * (bf2f(hh.y) + FEA(ea, 1));
            a2 += nrm * (bf2f(hh.z) + FEA(ea, 2));
            a3 += nrm * (bf2f(hh.w) + FEA(ea, 3));
        }
    }

    int bad = 0;
    if (!(a0 == a0)) { a0 = 777.f; bad++; }
    if (!(a1 == a1)) { a1 = 777.f; bad++; }
    if (!(a2 == a2)) { a2 = 777.f; bad++; }
    if (!(a3 == a3)) { a3 = 777.f; bad++; }
    if (bad) atomicAdd(&diag[1], bad);
    ushort4 oh, ol;
    split_bf(a0, oh.x, ol.x);
    split_bf(a1, oh.y, ol.y);
    split_bf(a2, oh.z, ol.z);
    split_bf(a3, oh.w, ol.w);
    *((ushort4*)agg_hi + (size_t)n * 64 + lane) = oh;
    *((ushort4*)agg_lo + (size_t)n * 64 + lane) = ol;
}

// ---------------- per-layer: split-precision MFMA GEMM + bias/ReLU + BN stats ----------------
// y = relu(A·W + bias); A = [h | agg] as bf16 hi/lo pairs (fp32 x split on the fly at l0).
// acc = Ahi·Whi + Alo·Whi + Ahi·Wlo.
// v8 = EXACT R1-measured structure (89.9us, MfmaUtil 17): 128 rows x 256 cols per block,
// 391 blocks, 4 waves x 2 row-groups (acc 128 VGPR). Per K-step the 32 KB B kb-slice is
// staged into LDS once per block (global_load_lds w16); 2-barrier loop. Row-exclusive ->
// in-place y-over-agg write is safe. Tile-size evidence: 128-row=90us, 64-row=113,
// 32-row=126 — per-K-step drain cost amortizes over MFMAs/wave, residency doesn't pay.
__global__ __launch_bounds__(256, 2) void MPNN_79044578115931_kernel(
        const void* hinA_, const u16* hinA_lo, int hf32,
        const u16* agg_hi, const u16* agg_lo,
        const u16* wpH, const u16* wpL, const float* bias,
        u16* y_hi, u16* y_lo,
        float* colsum, float* colsumsq, int* diag, int M) {
    __shared__ __align__(16) u16 bstage[16384];   // 32 KB: hi frags [0,8192), lo [8192,16384)
    __shared__ float lsum[256];
    __shared__ float lsq[256];

    int tid = threadIdx.x;
    int lane = tid & 63, wave = tid >> 6;
    int quad = lane >> 4, nl = lane & 15;
    int mBase = blockIdx.x * 128 + wave * 32;
    int rowA0 = mBase + nl;          // row-group 0
    int rowA1 = mBase + 16 + nl;     // row-group 1
    if (rowA0 >= M) rowA0 = M - 1;
    if (rowA1 >= M) rowA1 = M - 1;

    lsum[tid] = 0.f;
    lsq[tid] = 0.f;

    f32x4 acc0[16], acc1[16];
#pragma unroll
    for (int i = 0; i < 16; ++i) {
        acc0[i] = {0.f, 0.f, 0.f, 0.f};
        acc1[i] = {0.f, 0.f, 0.f, 0.f};
    }

    for (int kb = 0; kb < 16; ++kb) {
        __syncthreads();   // previous K-step's LDS reads done before overwrite

        // stage B kb-slice: 2048 frags x 16 B, thread t handles frags {i*256+t}
        const u16* srcH = wpH + (size_t)kb * 8192;
        const u16* srcL = wpL + (size_t)kb * 8192;
#pragma unroll
        for (int i = 0; i < 4; ++i) {
            int ci = i * 256 + tid;
            gl_lds16(srcH + ci * 8, &bstage[ci * 8]);
            gl_lds16(srcL + ci * 8, &bstage[8192 + ci * 8]);
        }

        // A fragments for this K-step (latency covered by the drain barrier below)
        short8 a0h, a0l, a1h, a1l;
        if (kb < 8) {
            int k0 = kb * 32 + quad * 8;
            if (hf32) {
                const float* hp0 = (const float*)hinA_ + (size_t)rowA0 * HID + k0;
                const float* hp1 = (const float*)hinA_ + (size_t)rowA1 * HID + k0;
#pragma unroll
                for (int j = 0; j < 8; ++j) {
                    u16 h, l;
                    split_bf(hp0[j], h, l);
                    a0h[j] = (short)h; a0l[j] = (short)l;
                    split_bf(hp1[j], h, l);
                    a1h[j] = (short)h; a1l[j] = (short)l;
                }
            } else {
                a0h = *(const short8*)((const u16*)hinA_ + (size_t)rowA0 * HID + k0);
                a0l = *(const short8*)(hinA_lo + (size_t)rowA0 * HID + k0);
                a1h = *(const short8*)((const u16*)hinA_ + (size_t)rowA1 * HID + k0);
                a1l = *(const short8*)(hinA_lo + (size_t)rowA1 * HID + k0);
            }
        } else {
            int k0 = (kb - 8) * 32 + quad * 8;
            a0h = *(const short8*)(agg_hi + (size_t)rowA0 * HID + k0);
            a0l = *(const short8*)(agg_lo + (size_t)rowA0 * HID + k0);
            a1h = *(const short8*)(agg_hi + (size_t)rowA1 * HID + k0);
            a1l = *(const short8*)(agg_lo + (size_t)rowA1 * HID + k0);
        }

        __syncthreads();   // drains vmcnt(0): staged B + A frags ready

        const short8* bbase = (const short8*)bstage;
#pragma unroll
        for (int nbg = 0; nbg < 16; ++nbg) {
            short8 bh = bbase[nbg * 64 + lane];
            short8 bl = bbase[1024 + nbg * 64 + lane];
            acc0[nbg] = __builtin_amdgcn_mfma_f32_16x16x32_bf16(a0h, bh, acc0[nbg], 0, 0, 0);
            acc1[nbg] = __builtin_amdgcn_mfma_f32_16x16x32_bf16(a1h, bh, acc1[nbg], 0, 0, 0);
            acc0[nbg] = __builtin_amdgcn_mfma_f32_16x16x32_bf16(a0l, bh, acc0[nbg], 0, 0, 0);
            acc1[nbg] = __builtin_amdgcn_mfma_f32_16x16x32_bf16(a1l, bh, acc1[nbg], 0, 0, 0);
            acc0[nbg] = __builtin_amdgcn_mfma_f32_16x16x32_bf16(a0h, bl, acc0[nbg], 0, 0, 0);
            acc1[nbg] = __builtin_amdgcn_mfma_f32_16x16x32_bf16(a1h, bl, acc1[nbg], 0, 0, 0);
        }
    }

    __syncthreads();   // all global agg reads complete -> in-place y write safe

    // epilogue: bias + ReLU + split-store + BN partial stats (pre-split fp32)
    int badY = 0;
#pragma unroll
    for (int nbg = 0; nbg < 16; ++nbg) {
        int c = nbg * 16 + nl;
        float bv = bias[c];
        float s = 0.f, q = 0.f;
#pragma unroll
        for (int r = 0; r < 4; ++r) {
            int m = mBase + quad * 4 + r;
            if (m < M) {
                float v = acc0[nbg][r] + bv;
                if (!(v == v)) { v = 777.f; badY++; }
                v = v > 0.f ? v : 0.f;
                u16 h, l;
                split_bf(v, h, l);
                y_hi[(size_t)m * HID + c] = h;
                y_lo[(size_t)m * HID + c] = l;
                s += v;
                q += v * v;
            }
        }
        atomicAdd(&lsum[c], s);
        atomicAdd(&lsq[c], q);
    }
#pragma unroll
    for (int nbg = 0; nbg < 16; ++nbg) {
        int c = nbg * 16 + nl;
        float bv = bias[c];
        float s = 0.f, q = 0.f;
#pragma unroll
        for (int r = 0; r < 4; ++r) {
            int m = mBase + 16 + quad * 4 + r;
            if (m < M) {
                float v = acc1[nbg][r] + bv;
                if (!(v == v)) { v = 777.f; badY++; }
                v = v > 0.f ? v : 0.f;
                u16 h, l;
                split_bf(v, h, l);
                y_hi[(size_t)m * HID + c] = h;
                y_lo[(size_t)m * HID + c] = l;
                s += v;
                q += v * v;
            }
        }
        atomicAdd(&lsum[c], s);
        atomicAdd(&lsq[c], q);
    }
    if (badY) atomicAdd(&diag[2], badY);
    __syncthreads();
    atomicAdd(&colsum[tid], lsum[tid]);
    atomicAdd(&colsumsq[tid], lsq[tid]);
}

__global__ __launch_bounds__(256) void k_bnscale(const float* colsum, const float* colsumsq,
                                                 const float* g, const float* b,
                                                 float* scale, float* shift, int* diag, int M) {
    int c = threadIdx.x;
    float mu = colsum[c] / (float)M;
    float var = colsumsq[c] / (float)M - mu * mu;
    if (!(mu == mu) || !(var == var) || var > 1e30f) atomicAdd(&diag[3], 1);
    if (var < 0.f) var = 0.f;
    float sc = rsqrtf(var + BN_EPS) * g[c];
    scale[c] = sc;
    shift[c] = b[c] - mu * sc;
}

// BN apply: reads y from src planes; non-final writes dst planes (+ReLU);
// final writes fp32 to outf. src may equal dst (in-place).
__global__ __launch_bounds__(256) void k_bnapply(const u16* src_hi, const u16* src_lo,
                                                 u16* dst_hi, u16* dst_lo,
                                                 const float* scale, const float* shift,
                                                 float* outf, int finalL, int relu, int total) {
    int q4 = blockIdx.x * 256 + threadIdx.x;
    int idx = q4 * 4;
    if (idx >= total) return;
    int c = idx & (HID - 1);
    ushort4 vh = *((const ushort4*)src_hi + q4);
    ushort4 vl = *((const ushort4*)src_lo + q4);
    float o0 = scale[c + 0] * (bf2f(vh.x) + bf2f(vl.x)) + shift[c + 0];
    float o1 = scale[c + 1] * (bf2f(vh.y) + bf2f(vl.y)) + shift[c + 1];
    float o2 = scale[c + 2] * (bf2f(vh.z) + bf2f(vl.z)) + shift[c + 2];
    float o3 = scale[c + 3] * (bf2f(vh.w) + bf2f(vl.w)) + shift[c + 3];
    if (relu) {
        o0 = o0 > 0.f ? o0 : 0.f;
        o1 = o1 > 0.f ? o1 : 0.f;
        o2 = o2 > 0.f ? o2 : 0.f;
        o3 = o3 > 0.f ? o3 : 0.f;
    }
    if (finalL) {
        float4 ov; ov.x = o0; ov.y = o1; ov.z = o2; ov.w = o3;
        *((float4*)outf + q4) = ov;
    } else {
        ushort4 oh, ol;
        split_bf(o0, oh.x, ol.x);
        split_bf(o1, oh.y, ol.y);
        split_bf(o2, oh.z, ol.z);
        split_bf(o3, oh.w, ol.w);
        *((ushort4*)dst_hi + q4) = oh;
        *((ushort4*)dst_lo + q4) = ol;
    }
}

// d_out[0] = (1+k+8*int64)*2^20 only if a check failed.
__global__ void k_encode(const int* diag, float* out) {
    if (threadIdx.x != 0 || blockIdx.x != 0) return;
    int k = -1;
    for (int i = 0; i < 4; ++i) if (diag[i] != 0) { k = i; break; }
    if (k < 0) return;
    out[0] = (float)(1 + k + (diag[7] != 0 ? 8 : 0)) * 1048576.0f;
}

// ---------------- launcher (zero workspace dependency) ----------------

extern "C" void kernel_launch(void* const* d_in, const int* in_sizes, int n_in,
                              void* d_out, int out_size, void* d_ws, size_t ws_size,
                              hipStream_t stream) {
    const float*  x     = (const float*)d_in[0];
    const int*    ei    = (const int*)d_in[1];
    const float4* eattr = (const float4*)d_in[2];
    const float*  mlp_w = (const float*)d_in[3];
    const float*  mlp_b = (const float*)d_in[4];
    const float*  ew1   = (const float*)d_in[5];
    const float*  ew2   = (const float*)d_in[6];
    const float*  bn_g  = (const float*)d_in[7];
    const float*  bn_b  = (const float*)d_in[8];
    (void)n_in; (void)out_size; (void)d_ws; (void)ws_size;

    const int N = in_sizes[0] / HID;   // 50000
    const int E = in_sizes[1] / 2;     // 320000
    const size_t P = (size_t)N * HID;  // plane elements

    // ---- CSR staging inside d_out (dead before layer 0 writes d_out) ----
    char* st = (char*)d_out;
    int*    S_deg    = (int*)   (st + 0);
    float*  S_dinv   = (float*) (st + 204800);
    int*    S_offs   = (int*)   (st + 409600);
    int*    S_cursor = (int*)   (st + 614400);
    int*    S_bsum   = (int*)   (st + 819200);
    int*    S_bscan  = (int*)   (st + 820224);
    int*    S_gflag  = (int*)   (st + 821248);
    int*    S_row    = (int*)   (st + 1048576);
    float4* S_ea     = (float4*)(st + 2621440);   // ends 7,741,440 < 51.2 MB

    // ---- small homes in edge_index buffer (>=2.56 MB); eattr buffer holds eaP ----
    char* eb = (char*)d_in[1];
    int*   rowArr = (int*)  (eb + 0);          // 1,280,000
    float* dinvF  = (float*)(eb + 1280000);    // 200,000
    int*   offsF  = (int*)  (eb + 1480000);    // 200,004
    float* colsum = (float*)(eb + 1680128);
    float* colsq  = (float*)(eb + 1681152);
    float* scaleF = (float*)(eb + 1682176);
    float* shiftF = (float*)(eb + 1683200);
    int*   diag   = (int*)  (eb + 1684224);    // 1 KB
    u16*   wpH    = (u16*)  (eb + 1685504);    // 256 KB -> ends 1,947,648
    u16*   wpL    = (u16*)  (eb + 1947648);    // 256 KB -> ends 2,209,792 <= 2,560,000
    float4* eaP   = (float4*)d_in[2];          // 5,120,000 exact

    // ---- h slots as bf16 hi/lo planes (each slot = 2 planes = 51.2 MB) ----
    u16* sX_hi = (u16*)d_in[0];          // x buffer (x consumed during layer 0)
    u16* sX_lo = sX_hi + P;
    u16* sD_hi = (u16*)d_out;
    u16* sD_lo = sD_hi + P;

    int NB  = (N + 255) / 256;
    int NBE = (E + 255) / 256;
    int NBG = (N + 127) / 128;    // 391 GEMM blocks (128 rows each)
    int NBA = (N + 3) / 4;        // 12500 agg blocks (one wave per node)
    int NBQ = (int)((P / 4 + 255) / 256);

    // ---- preprocessing ----
    k_detect<<<1, 256, 0, stream>>>(ei, S_gflag, E);
    k_zero32<<<NB, 256, 0, stream>>>((unsigned int*)S_deg, N);
    k_deg<<<NBE, 256, 0, stream>>>(ei, S_gflag, S_deg, E, N);
    k_dinv<<<NB, 256, 0, stream>>>(S_deg, S_dinv, N);
    k_scan1<<<NB, 256, 0, stream>>>(S_deg, S_offs, S_bsum, N);
    k_scan2<<<1, 256, 0, stream>>>(S_bsum, S_bscan, NB);
    k_scan3<<<NB, 256, 0, stream>>>(S_offs, S_bscan, S_cursor, N, E);
    k_place<<<NBE, 256, 0, stream>>>(ei, S_gflag, eattr, S_cursor, S_row, S_ea, E, N);
    k_move<<<NBE, 256, 0, stream>>>(S_row, S_ea, S_dinv, S_offs, rowArr, eaP, dinvF, offsF, E, N);
    k_zero32<<<1, 256, 0, stream>>>((unsigned int*)diag, 256);
    k_precheckN<<<NB, 256, 0, stream>>>(offsF, S_cursor, dinvF, S_gflag, diag, N, E);
    k_precheckE<<<NBE, 256, 0, stream>>>(rowArr, diag, E, N);

    // ---- layers: even l -> dst = D(d_out), odd l -> dst = X; agg planes live in dst ----
    for (int l = 0; l < NLAYERS; ++l) {
        int even = (l % 2 == 0);
        u16* dst_hi = even ? sD_hi : sX_hi;
        u16* dst_lo = even ? sD_lo : sX_lo;
        const void* hinA; const u16* hin_lo; int hf32;
        if (l == 0) { hinA = (const void*)x; hin_lo = 0; hf32 = 1; }
        else if (even) { hinA = (const void*)sX_hi; hin_lo = sX_lo; hf32 = 0; }
        else { hinA = (const void*)sD_hi; hin_lo = sD_lo; hf32 = 0; }

        k_wsplit<<<64, 256, 0, stream>>>(mlp_w + (size_t)l * 512 * HID, wpH, wpL, colsum);
        k_agg<<<NBA, 256, 0, stream>>>(hinA, hin_lo, hf32, offsF, rowArr, eaP, dinvF,
                                       ew1 + (size_t)l * 128, ew2 + (size_t)l * 384,
                                       dst_hi, dst_lo, diag, N);
        MPNN_79044578115931_kernel<<<NBG, 256, 0, stream>>>(
            hinA, hin_lo, hf32, dst_hi, dst_lo, wpH, wpL,
            mlp_b + (size_t)l * HID, dst_hi, dst_lo, colsum, colsq, diag, N);
        k_bnscale<<<1, 256, 0, stream>>>(colsum, colsq,
                                         bn_g + (size_t)l * HID, bn_b + (size_t)l * HID,
                                         scaleF, shiftF, diag, N);
        int finalL = (l == NLAYERS - 1) ? 1 : 0;
        int relu = finalL ? 0 : 1;
        // final: expand planes -> fp32 into X buffer, then copy back to d_out
        k_bnapply<<<NBQ, 256, 0, stream>>>(dst_hi, dst_lo, dst_hi, dst_lo, scaleF, shiftF,
                                           (float*)d_in[0], finalL, relu, (int)P);
    }

    hipMemcpyAsync(d_out, d_in[0], P * 4, hipMemcpyDeviceToDevice, stream);
    k_encode<<<1, 64, 0, stream>>>(diag, (float*)d_out);
}

// Round 9
// 908.552 us; speedup vs baseline: 2.3943x; 1.0199x over previous
//
#include <hip/hip_runtime.h>
#include <stdint.h>

typedef short short8 __attribute__((ext_vector_type(8)));
typedef float f32x4 __attribute__((ext_vector_type(4)));
typedef unsigned short u16;

#define HID 256
#define NLAYERS 5
#define BN_EPS 1e-5f

__device__ __forceinline__ float bf2f(u16 u) {
    union { unsigned int i; float f; } v;
    v.i = ((unsigned int)u) << 16;
    return v.f;
}
__device__ __forceinline__ u16 f2bf(float f) {
    union { float f; unsigned int i; } v;
    v.f = f;
    unsigned int r = v.i + 0x7FFFu + ((v.i >> 16) & 1u);   // RNE
    return (u16)(r >> 16);
}
// split fp32 -> (hi, lo) bf16 pair: hi+lo ~ 17-bit mantissa approximation
__device__ __forceinline__ void split_bf(float f, u16& hi, u16& lo) {
    hi = f2bf(f);
    lo = f2bf(f - bf2f(hi));
}

// 16-B direct global->LDS copy (vmcnt-tracked; drained by __syncthreads).
__device__ __forceinline__ void gl_lds16(const void* gsrc, void* ldst) {
    const __attribute__((address_space(1))) unsigned int* g =
        reinterpret_cast<const __attribute__((address_space(1))) unsigned int*>(
            reinterpret_cast<uintptr_t>(gsrc));
    __attribute__((address_space(3))) unsigned int* l =
        reinterpret_cast<__attribute__((address_space(3))) unsigned int*>(
            reinterpret_cast<uintptr_t>(ldst));
    __builtin_amdgcn_global_load_lds(g, l, 16, 0, 0);
}

// ---------------- utility ----------------

__global__ __launch_bounds__(256) void k_zero32(unsigned int* p, int n) {
    int i = blockIdx.x * 256 + threadIdx.x;
    if (i < n) p[i] = 0u;
}

// ---------------- graph preprocessing (staged in d_out) ----------------

__global__ __launch_bounds__(256) void k_detect(const int* ei, int* flag, int E) {
    __shared__ int nz;
    if (threadIdx.x == 0) nz = 0;
    __syncthreads();
    int lim = (2 * E < 4096) ? 2 * E : 4096;
    int c = 0;
    for (int i = threadIdx.x; 2 * i + 1 < lim; i += 256) c += (ei[2 * i + 1] != 0);
    atomicAdd(&nz, c);
    __syncthreads();
    if (threadIdx.x == 0) flag[0] = (nz == 0) ? 1 : 0;   // 1 => int64 layout
}

__global__ __launch_bounds__(256) void k_deg(const int* ei, const int* flag, int* deg, int E, int N) {
    int e = blockIdx.x * 256 + threadIdx.x;
    if (e >= E) return;
    int w = flag[0];
    int col = w ? ei[2 * (E + e)] : ei[E + e];
    if ((unsigned)col < (unsigned)N) atomicAdd(&deg[col], 1);
}

__global__ __launch_bounds__(256) void k_dinv(const int* deg, float* dinv, int N) {
    int n = blockIdx.x * 256 + threadIdx.x;
    if (n < N) { int d = deg[n]; dinv[n] = d > 0 ? rsqrtf((float)d) : 0.0f; }
}

__global__ __launch_bounds__(256) void k_scan1(const int* deg, int* offs, int* bsum, int N) {
    __shared__ int s[256];
    int tid = threadIdx.x;
    int i = blockIdx.x * 256 + tid;
    int v = (i < N) ? deg[i] : 0;
    s[tid] = v;
    __syncthreads();
    for (int off = 1; off < 256; off <<= 1) {
        int t = (tid >= off) ? s[tid - off] : 0;
        __syncthreads();
        s[tid] += t;
        __syncthreads();
    }
    if (i < N) offs[i] = s[tid] - v;
    if (tid == 255) bsum[blockIdx.x] = s[tid];
}

__global__ __launch_bounds__(256) void k_scan2(const int* bsum, int* bscan, int NB) {
    __shared__ int s[256];
    int tid = threadIdx.x;
    int v = (tid < NB) ? bsum[tid] : 0;
    s[tid] = v;
    __syncthreads();
    for (int off = 1; off < 256; off <<= 1) {
        int t = (tid >= off) ? s[tid - off] : 0;
        __syncthreads();
        s[tid] += t;
        __syncthreads();
    }
    bscan[tid] = s[tid] - v;
}

__global__ __launch_bounds__(256) void k_scan3(int* offs, const int* bscan, int* cursor, int N, int E) {
    int i = blockIdx.x * 256 + threadIdx.x;
    if (i < N) {
        int o = offs[i] + bscan[blockIdx.x];
        offs[i] = o;
        cursor[i] = o;
    }
    if (i == 0) offs[N] = E;
}

__global__ __launch_bounds__(256) void k_place(const int* ei, const int* flag, const float4* eattr,
                                               int* cursor, int* srow, float4* sea, int E, int N) {
    int e = blockIdx.x * 256 + threadIdx.x;
    if (e >= E) return;
    int w = flag[0];
    int r = w ? ei[2 * e] : ei[e];
    int c = w ? ei[2 * (E + e)] : ei[E + e];
    if ((unsigned)c >= (unsigned)N) return;
    int p = atomicAdd(&cursor[c], 1);
    srow[p] = r;
    sea[p] = eattr[e];
}

__global__ __launch_bounds__(256) void k_move(const int* srow, const float4* sea, const float* sdinv,
                                              const int* soffs, int* rowArr, float4* eaP,
                                              float* dinvF, int* offsF, int E, int N) {
    int i = blockIdx.x * 256 + threadIdx.x;
    if (i < E) { rowArr[i] = srow[i]; eaP[i] = sea[i]; }
    if (i < N) dinvF[i] = sdinv[i];
    if (i <= N) offsF[i] = soffs[i];
}

__global__ __launch_bounds__(256) void k_precheckN(const int* offsF, const int* cursor, const float* dinvF,
                                                   const int* gflag, int* diag, int N, int E) {
    int i = blockIdx.x * 256 + threadIdx.x;
    if (i < N) {
        if (offsF[i + 1] < offsF[i]) atomicOr(&diag[0], 1);
        if (cursor[i] != offsF[i + 1]) atomicOr(&diag[0], 2);
        float d = dinvF[i];
        if (!(d == d) || fabsf(d) > 1e10f) atomicOr(&diag[0], 4);
    }
    if (i == 0) {
        if (offsF[N] != E) atomicOr(&diag[0], 8);
        diag[7] = gflag[0];
    }
}
__global__ __launch_bounds__(256) void k_precheckE(const int* rowArr, int* diag, int E, int N) {
    int p = blockIdx.x * 256 + threadIdx.x;
    if (p < E && (unsigned)rowArr[p] >= (unsigned)N) atomicOr(&diag[0], 16);
}

// Per-layer: split W (fp32 512x256 row-major) into bf16 hi/lo planes in MFMA
// B-fragment order, kb-major: frag t = kb*1024 + nbg*64 + lane holds
// W[kb*32 + (lane>>4)*8 + j][nbg*16 + (lane&15)], j=0..7.
// Block 0 also zeroes the BN stats accumulators (512 floats at colsum).
__global__ __launch_bounds__(256) void k_wsplit(const float* W, u16* wpH, u16* wpL, float* colsum) {
    if (blockIdx.x == 0) {
        colsum[threadIdx.x] = 0.f;
        colsum[256 + threadIdx.x] = 0.f;
    }
    int t = blockIdx.x * 256 + threadIdx.x;   // 64 blocks -> 16384 frags
    int lane = t & 63;
    int nbg = (t >> 6) & 15;
    int kb = t >> 10;
    int quad = lane >> 4, nl = lane & 15;
    const float* src = W + (size_t)(kb * 32 + quad * 8) * HID + nbg * 16 + nl;
    short8 vh, vl;
#pragma unroll
    for (int j = 0; j < 8; ++j) {
        u16 h, l;
        split_bf(src[(size_t)j * HID], h, l);
        vh[j] = (short)h;
        vl[j] = (short)l;
    }
    *((short8*)wpH + t) = vh;
    *((short8*)wpL + t) = vl;
}

// ---------------- per-layer: aggregation (one wave per node), split output ----------------
// v9 (BN deferral): for l>=1 the hin plane holds y = relu(A·W+b) PRE-BN; this kernel
// applies h = relu(scale*y + shift) on the fly per gathered element (+2 VALU, BW-bound
// kernel -> free). Per-lane scale/shift = 2 float4 register loads (lane owns channels
// 4*lane..+3). Still gathers ONLY the hi plane (R8 bandwidth win; error = sc*y_lo,
// sc ~ O(1) for non-degenerate batch stats).
#define FEA(ea, j) ((ea).w * w1v[j] + (ea).x * w20[j] + (ea).y * w21[j] + (ea).z * w22[j])
#define BNX(u, comp) (fmaxf(sc4.comp * bf2f(u) + sh4.comp, 0.f))

__global__ __launch_bounds__(256) void k_agg(const void* hin_, const u16* hin_lo, int hf32,
                                             const int* offs, const int* rowArr, const float4* eaP,
                                             const float* dinv, const float* ew1, const float* ew2,
                                             const float* bnsc, const float* bnsh,
                                             u16* agg_hi, u16* agg_lo, int* diag, int M) {
    (void)hin_lo;
    int lane = threadIdx.x & 63, wave = threadIdx.x >> 6;
    int n = blockIdx.x * 4 + wave;

    float w1v[4] = {0.f, 0.f, 0.f, 0.f};
    float w20[4] = {0.f, 0.f, 0.f, 0.f};
    float w21[4] = {0.f, 0.f, 0.f, 0.f};
    float w22[4] = {0.f, 0.f, 0.f, 0.f};
    if (lane < 32) {
        int c = lane * 4;
#pragma unroll
        for (int j = 0; j < 4; ++j) w1v[j] = ew1[c + j];
    } else {
        int cc = (lane - 32) * 4;
#pragma unroll
        for (int j = 0; j < 4; ++j) {
            w20[j] = ew2[cc + j];
            w21[j] = ew2[128 + cc + j];
            w22[j] = ew2[256 + cc + j];
        }
    }

    float4 sc4 = {0.f, 0.f, 0.f, 0.f}, sh4 = {0.f, 0.f, 0.f, 0.f};
    if (!hf32) {
        sc4 = ((const float4*)bnsc)[lane];
        sh4 = ((const float4*)bnsh)[lane];
    }

    if (n >= M) return;
    float dn = dinv[n];
    int s = offs[n], e = offs[n + 1];
    float a0 = 0.f, a1 = 0.f, a2 = 0.f, a3 = 0.f;
    int p = s;

    if (hf32) {
        for (; p + 4 <= e; p += 4) {
            int r0 = rowArr[p + 0], r1 = rowArr[p + 1], r2 = rowArr[p + 2], r3 = rowArr[p + 3];
            float4 ea0 = eaP[p + 0], ea1 = eaP[p + 1], ea2 = eaP[p + 2], ea3 = eaP[p + 3];
            float4 hv0 = *((const float4*)hin_ + (size_t)r0 * 64 + lane);
            float4 hv1 = *((const float4*)hin_ + (size_t)r1 * 64 + lane);
            float4 hv2 = *((const float4*)hin_ + (size_t)r2 * 64 + lane);
            float4 hv3 = *((const float4*)hin_ + (size_t)r3 * 64 + lane);
            float n0 = dn * dinv[r0], n1 = dn * dinv[r1], n2 = dn * dinv[r2], n3 = dn * dinv[r3];
            a0 += n0 * (hv0.x + FEA(ea0, 0)) + n1 * (hv1.x + FEA(ea1, 0))
                + n2 * (hv2.x + FEA(ea2, 0)) + n3 * (hv3.x + FEA(ea3, 0));
            a1 += n0 * (hv0.y + FEA(ea0, 1)) + n1 * (hv1.y + FEA(ea1, 1))
                + n2 * (hv2.y + FEA(ea2, 1)) + n3 * (hv3.y + FEA(ea3, 1));
            a2 += n0 * (hv0.z + FEA(ea0, 2)) + n1 * (hv1.z + FEA(ea1, 2))
                + n2 * (hv2.z + FEA(ea2, 2)) + n3 * (hv3.z + FEA(ea3, 2));
            a3 += n0 * (hv0.w + FEA(ea0, 3)) + n1 * (hv1.w + FEA(ea1, 3))
                + n2 * (hv2.w + FEA(ea2, 3)) + n3 * (hv3.w + FEA(ea3, 3));
        }
        for (; p < e; ++p) {
            int r = rowArr[p];
            float4 ea = eaP[p];
            float nrm = dn * dinv[r];
            float4 hv = *((const float4*)hin_ + (size_t)r * 64 + lane);
            a0 += nrm * (hv.x + FEA(ea, 0));
            a1 += nrm * (hv.y + FEA(ea, 1));
            a2 += nrm * (hv.z + FEA(ea, 2));
            a3 += nrm * (hv.w + FEA(ea, 3));
        }
    } else {
        for (; p + 4 <= e; p += 4) {
            int r0 = rowArr[p + 0], r1 = rowArr[p + 1], r2 = rowArr[p + 2], r3 = rowArr[p + 3];
            float4 ea0 = eaP[p + 0], ea1 = eaP[p + 1], ea2 = eaP[p + 2], ea3 = eaP[p + 3];
            ushort4 hh0 = *((const ushort4*)hin_ + (size_t)r0 * 64 + lane);
            ushort4 hh1 = *((const ushort4*)hin_ + (size_t)r1 * 64 + lane);
            ushort4 hh2 = *((const ushort4*)hin_ + (size_t)r2 * 64 + lane);
            ushort4 hh3 = *((const ushort4*)hin_ + (size_t)r3 * 64 + lane);
            float n0 = dn * dinv[r0], n1 = dn * dinv[r1], n2 = dn * dinv[r2], n3 = dn * dinv[r3];
            a0 += n0 * (BNX(hh0.x, x) + FEA(ea0, 0)) + n1 * (BNX(hh1.x, x) + FEA(ea1, 0))
                + n2 * (BNX(hh2.x, x) + FEA(ea2, 0)) + n3 * (BNX(hh3.x, x) + FEA(ea3, 0));
            a1 += n0 * (BNX(hh0.y, y) + FEA(ea0, 1)) + n1 * (BNX(hh1.y, y) + FEA(ea1, 1))
                + n2 * (BNX(hh2.y, y) + FEA(ea2, 1)) + n3 * (BNX(hh3.y, y) + FEA(ea3, 1));
            a2 += n0 * (BNX(hh0.z, z) + FEA(ea0, 2)) + n1 * (BNX(hh1.z, z) + FEA(ea1, 2))
                + n2 * (BNX(hh2.z, z) + FEA(ea2, 2)) + n3 * (BNX(hh3.z, z) + FEA(ea3, 2));
            a3 += n0 * (BNX(hh0.w, w) + FEA(ea0, 3)) + n1 * (BNX(hh1.w, w) + FEA(ea1, 3))
                + n2 * (BNX(hh2.w, w) + FEA(ea2, 3)) + n3 * (BNX(hh3.w, w) + FEA(ea3, 3));
        }
        for (; p < e; ++p) {
            int r = rowArr[p];
            float4 ea = eaP[p];
            float nrm = dn * dinv[r];
            ushort4 hh = *((const ushort4*)hin_ + (size_t)r * 64 + lane);
            a0 += nrm * (BNX(hh.x, x) + FEA(ea, 0));
            a1 += nrm * (BNX(hh.y, y) + FEA(ea, 1));
            a2 += nrm * (BNX(hh.z, z) + FEA(ea, 2));
            a3 += nrm * (BNX(hh.w, w) + FEA(ea, 3));
        }
    }

    int bad = 0;
    if (!(a0 == a0)) { a0 = 777.f; bad++; }
    if (!(a1 == a1)) { a1 = 777.f; bad++; }
    if (!(a2 == a2)) { a2 = 777.f; bad++; }
    if (!(a3 == a3)) { a3 = 777.f; bad++; }
    if (bad) atomicAdd(&diag[1], bad);
    ushort4 oh, ol;
    split_bf(a0, oh.x, ol.x);
    split_bf(a1, oh.y, ol.y);
    split_bf(a2, oh.z, ol.z);
    split_bf(a3, oh.w, ol.w);
    *((ushort4*)agg_hi + (size_t)n * 64 + lane) = oh;
    *((ushort4*)agg_lo + (size_t)n * 64 + lane) = ol;
}

// ---------------- per-layer: split-precision MFMA GEMM + bias/ReLU + BN stats ----------------
// y = relu(A·W + bias); A = [h | agg]; acc = Ahi·Whi + Alo·Whi + Ahi·Wlo.
// v9 = R8's proven 128-row structure (90us measured) + BN deferral on the A h-path:
// for l>=1 (bf16), kb<8 loads y hi/lo planes and computes h = relu(sc*(hi+lo)+sh)
// on the fly (same value bnapply would have materialized; split identically).
// sc/sh float4 loads issue with the A-loads (covered by the drain barrier);
// ~208 VALU ops/wave for 8 of 16 K-steps, hidden under the drain-dominated K-step.
// Row-exclusive -> in-place y-over-agg write safe. Tile-size evidence: 128=90/64=113/32=126.
__global__ __launch_bounds__(256, 2) void MPNN_79044578115931_kernel(
        const void* hinA_, const u16* hinA_lo, int hf32,
        const u16* agg_hi, const u16* agg_lo,
        const u16* wpH, const u16* wpL, const float* bias,
        const float* bnsc, const float* bnsh,
        u16* y_hi, u16* y_lo,
        float* colsum, float* colsumsq, int* diag, int M) {
    __shared__ __align__(16) u16 bstage[16384];   // 32 KB: hi frags [0,8192), lo [8192,16384)
    __shared__ float lsum[256];
    __shared__ float lsq[256];

    int tid = threadIdx.x;
    int lane = tid & 63, wave = tid >> 6;
    int quad = lane >> 4, nl = lane & 15;
    int mBase = blockIdx.x * 128 + wave * 32;
    int rowA0 = mBase + nl;          // row-group 0
    int rowA1 = mBase + 16 + nl;     // row-group 1
    if (rowA0 >= M) rowA0 = M - 1;
    if (rowA1 >= M) rowA1 = M - 1;

    lsum[tid] = 0.f;
    lsq[tid] = 0.f;

    f32x4 acc0[16], acc1[16];
#pragma unroll
    for (int i = 0; i < 16; ++i) {
        acc0[i] = {0.f, 0.f, 0.f, 0.f};
        acc1[i] = {0.f, 0.f, 0.f, 0.f};
    }

    for (int kb = 0; kb < 16; ++kb) {
        __syncthreads();   // previous K-step's LDS reads done before overwrite

        // stage B kb-slice: 2048 frags x 16 B, thread t handles frags {i*256+t}
        const u16* srcH = wpH + (size_t)kb * 8192;
        const u16* srcL = wpL + (size_t)kb * 8192;
#pragma unroll
        for (int i = 0; i < 4; ++i) {
            int ci = i * 256 + tid;
            gl_lds16(srcH + ci * 8, &bstage[ci * 8]);
            gl_lds16(srcL + ci * 8, &bstage[8192 + ci * 8]);
        }

        // A fragments for this K-step (latency covered by the drain barrier below)
        short8 a0h, a0l, a1h, a1l;
        float4 scv0, scv1, shv0, shv1;
        if (kb < 8) {
            int k0 = kb * 32 + quad * 8;
            if (hf32) {
                const float* hp0 = (const float*)hinA_ + (size_t)rowA0 * HID + k0;
                const float* hp1 = (const float*)hinA_ + (size_t)rowA1 * HID + k0;
#pragma unroll
                for (int j = 0; j < 8; ++j) {
                    u16 h, l;
                    split_bf(hp0[j], h, l);
                    a0h[j] = (short)h; a0l[j] = (short)l;
                    split_bf(hp1[j], h, l);
                    a1h[j] = (short)h; a1l[j] = (short)l;
                }
            } else {
                a0h = *(const short8*)((const u16*)hinA_ + (size_t)rowA0 * HID + k0);
                a0l = *(const short8*)(hinA_lo + (size_t)rowA0 * HID + k0);
                a1h = *(const short8*)((const u16*)hinA_ + (size_t)rowA1 * HID + k0);
                a1l = *(const short8*)(hinA_lo + (size_t)rowA1 * HID + k0);
                int q4 = k0 >> 2;
                scv0 = ((const float4*)bnsc)[q4];
                scv1 = ((const float4*)bnsc)[q4 + 1];
                shv0 = ((const float4*)bnsh)[q4];
                shv1 = ((const float4*)bnsh)[q4 + 1];
            }
        } else {
            int k0 = (kb - 8) * 32 + quad * 8;
            a0h = *(const short8*)(agg_hi + (size_t)rowA0 * HID + k0);
            a0l = *(const short8*)(agg_lo + (size_t)rowA0 * HID + k0);
            a1h = *(const short8*)(agg_hi + (size_t)rowA1 * HID + k0);
            a1l = *(const short8*)(agg_lo + (size_t)rowA1 * HID + k0);
        }

        __syncthreads();   // drains vmcnt(0): staged B + A frags + sc/sh ready

        // BN deferral: reconstruct h = relu(sc*(hi+lo)+sh), re-split -> A fragments
        if (!hf32 && kb < 8) {
            float scr[8] = {scv0.x, scv0.y, scv0.z, scv0.w, scv1.x, scv1.y, scv1.z, scv1.w};
            float shr[8] = {shv0.x, shv0.y, shv0.z, shv0.w, shv1.x, shv1.y, shv1.z, shv1.w};
#pragma unroll
            for (int j = 0; j < 8; ++j) {
                float f0 = scr[j] * (bf2f((u16)a0h[j]) + bf2f((u16)a0l[j])) + shr[j];
                f0 = f0 > 0.f ? f0 : 0.f;
                float f1 = scr[j] * (bf2f((u16)a1h[j]) + bf2f((u16)a1l[j])) + shr[j];
                f1 = f1 > 0.f ? f1 : 0.f;
                u16 h, l;
                split_bf(f0, h, l);
                a0h[j] = (short)h; a0l[j] = (short)l;
                split_bf(f1, h, l);
                a1h[j] = (short)h; a1l[j] = (short)l;
            }
        }

        const short8* bbase = (const short8*)bstage;
#pragma unroll
        for (int nbg = 0; nbg < 16; ++nbg) {
            short8 bh = bbase[nbg * 64 + lane];
            short8 bl = bbase[1024 + nbg * 64 + lane];
            acc0[nbg] = __builtin_amdgcn_mfma_f32_16x16x32_bf16(a0h, bh, acc0[nbg], 0, 0, 0);
            acc1[nbg] = __builtin_amdgcn_mfma_f32_16x16x32_bf16(a1h, bh, acc1[nbg], 0, 0, 0);
            acc0[nbg] = __builtin_amdgcn_mfma_f32_16x16x32_bf16(a0l, bh, acc0[nbg], 0, 0, 0);
            acc1[nbg] = __builtin_amdgcn_mfma_f32_16x16x32_bf16(a1l, bh, acc1[nbg], 0, 0, 0);
            acc0[nbg] = __builtin_amdgcn_mfma_f32_16x16x32_bf16(a0h, bl, acc0[nbg], 0, 0, 0);
            acc1[nbg] = __builtin_amdgcn_mfma_f32_16x16x32_bf16(a1h, bl, acc1[nbg], 0, 0, 0);
        }
    }

    __syncthreads();   // all global agg reads complete -> in-place y write safe

    // epilogue: bias + ReLU + split-store + BN partial stats (pre-split fp32)
    int badY = 0;
#pragma unroll
    for (int nbg = 0; nbg < 16; ++nbg) {
        int c = nbg * 16 + nl;
        float bv = bias[c];
        float s = 0.f, q = 0.f;
#pragma unroll
        for (int r = 0; r < 4; ++r) {
            int m = mBase + quad * 4 + r;
            if (m < M) {
                float v = acc0[nbg][r] + bv;
                if (!(v == v)) { v = 777.f; badY++; }
                v = v > 0.f ? v : 0.f;
                u16 h, l;
                split_bf(v, h, l);
                y_hi[(size_t)m * HID + c] = h;
                y_lo[(size_t)m * HID + c] = l;
                s += v;
                q += v * v;
            }
        }
        atomicAdd(&lsum[c], s);
        atomicAdd(&lsq[c], q);
    }
#pragma unroll
    for (int nbg = 0; nbg < 16; ++nbg) {
        int c = nbg * 16 + nl;
        float bv = bias[c];
        float s = 0.f, q = 0.f;
#pragma unroll
        for (int r = 0; r < 4; ++r) {
            int m = mBase + 16 + quad * 4 + r;
            if (m < M) {
                float v = acc1[nbg][r] + bv;
                if (!(v == v)) { v = 777.f; badY++; }
                v = v > 0.f ? v : 0.f;
                u16 h, l;
                split_bf(v, h, l);
                y_hi[(size_t)m * HID + c] = h;
                y_lo[(size_t)m * HID + c] = l;
                s += v;
                q += v * v;
            }
        }
        atomicAdd(&lsum[c], s);
        atomicAdd(&lsq[c], q);
    }
    if (badY) atomicAdd(&diag[2], badY);
    __syncthreads();
    atomicAdd(&colsum[tid], lsum[tid]);
    atomicAdd(&colsumsq[tid], lsq[tid]);
}

__global__ __launch_bounds__(256) void k_bnscale(const float* colsum, const float* colsumsq,
                                                 const float* g, const float* b,
                                                 float* scale, float* shift, int* diag, int M) {
    int c = threadIdx.x;
    float mu = colsum[c] / (float)M;
    float var = colsumsq[c] / (float)M - mu * mu;
    if (!(mu == mu) || !(var == var) || var > 1e30f) atomicAdd(&diag[3], 1);
    if (var < 0.f) var = 0.f;
    float sc = rsqrtf(var + BN_EPS) * g[c];
    scale[c] = sc;
    shift[c] = b[c] - mu * sc;
}

// BN apply (FINAL layer only under deferral): reads y planes, writes fp32 to outf.
__global__ __launch_bounds__(256) void k_bnapply(const u16* src_hi, const u16* src_lo,
                                                 u16* dst_hi, u16* dst_lo,
                                                 const float* scale, const float* shift,
                                                 float* outf, int finalL, int relu, int total) {
    int q4 = blockIdx.x * 256 + threadIdx.x;
    int idx = q4 * 4;
    if (idx >= total) return;
    int c = idx & (HID - 1);
    ushort4 vh = *((const ushort4*)src_hi + q4);
    ushort4 vl = *((const ushort4*)src_lo + q4);
    float o0 = scale[c + 0] * (bf2f(vh.x) + bf2f(vl.x)) + shift[c + 0];
    float o1 = scale[c + 1] * (bf2f(vh.y) + bf2f(vl.y)) + shift[c + 1];
    float o2 = scale[c + 2] * (bf2f(vh.z) + bf2f(vl.z)) + shift[c + 2];
    float o3 = scale[c + 3] * (bf2f(vh.w) + bf2f(vl.w)) + shift[c + 3];
    if (relu) {
        o0 = o0 > 0.f ? o0 : 0.f;
        o1 = o1 > 0.f ? o1 : 0.f;
        o2 = o2 > 0.f ? o2 : 0.f;
        o3 = o3 > 0.f ? o3 : 0.f;
    }
    if (finalL) {
        float4 ov; ov.x = o0; ov.y = o1; ov.z = o2; ov.w = o3;
        *((float4*)outf + q4) = ov;
    } else {
        ushort4 oh, ol;
        split_bf(o0, oh.x, ol.x);
        split_bf(o1, oh.y, ol.y);
        split_bf(o2, oh.z, ol.z);
        split_bf(o3, oh.w, ol.w);
        *((ushort4*)dst_hi + q4) = oh;
        *((ushort4*)dst_lo + q4) = ol;
    }
}

// d_out[0] = (1+k+8*int64)*2^20 only if a check failed.
__global__ void k_encode(const int* diag, float* out) {
    if (threadIdx.x != 0 || blockIdx.x != 0) return;
    int k = -1;
    for (int i = 0; i < 4; ++i) if (diag[i] != 0) { k = i; break; }
    if (k < 0) return;
    out[0] = (float)(1 + k + (diag[7] != 0 ? 8 : 0)) * 1048576.0f;
}

// ---------------- launcher (zero workspace dependency) ----------------

extern "C" void kernel_launch(void* const* d_in, const int* in_sizes, int n_in,
                              void* d_out, int out_size, void* d_ws, size_t ws_size,
                              hipStream_t stream) {
    const float*  x     = (const float*)d_in[0];
    const int*    ei    = (const int*)d_in[1];
    const float4* eattr = (const float4*)d_in[2];
    const float*  mlp_w = (const float*)d_in[3];
    const float*  mlp_b = (const float*)d_in[4];
    const float*  ew1   = (const float*)d_in[5];
    const float*  ew2   = (const float*)d_in[6];
    const float*  bn_g  = (const float*)d_in[7];
    const float*  bn_b  = (const float*)d_in[8];
    (void)n_in; (void)out_size; (void)d_ws; (void)ws_size;

    const int N = in_sizes[0] / HID;   // 50000
    const int E = in_sizes[1] / 2;     // 320000
    const size_t P = (size_t)N * HID;  // plane elements

    // ---- CSR staging inside d_out (dead before layer 0 writes d_out) ----
    char* st = (char*)d_out;
    int*    S_deg    = (int*)   (st + 0);
    float*  S_dinv   = (float*) (st + 204800);
    int*    S_offs   = (int*)   (st + 409600);
    int*    S_cursor = (int*)   (st + 614400);
    int*    S_bsum   = (int*)   (st + 819200);
    int*    S_bscan  = (int*)   (st + 820224);
    int*    S_gflag  = (int*)   (st + 821248);
    int*    S_row    = (int*)   (st + 1048576);
    float4* S_ea     = (float4*)(st + 2621440);   // ends 7,741,440 < 51.2 MB

    // ---- small homes in edge_index buffer (>=2.56 MB); eattr buffer holds eaP ----
    char* eb = (char*)d_in[1];
    int*   rowArr = (int*)  (eb + 0);          // 1,280,000
    float* dinvF  = (float*)(eb + 1280000);    // 200,000
    int*   offsF  = (int*)  (eb + 1480000);    // 200,004
    float* colsum = (float*)(eb + 1680128);
    float* colsq  = (float*)(eb + 1681152);
    float* scaleF = (float*)(eb + 1682176);
    float* shiftF = (float*)(eb + 1683200);
    int*   diag   = (int*)  (eb + 1684224);    // 1 KB
    u16*   wpH    = (u16*)  (eb + 1685504);    // 256 KB -> ends 1,947,648
    u16*   wpL    = (u16*)  (eb + 1947648);    // 256 KB -> ends 2,209,792 <= 2,560,000
    float4* eaP   = (float4*)d_in[2];          // 5,120,000 exact

    // ---- h slots as bf16 hi/lo planes (each slot = 2 planes = 51.2 MB) ----
    u16* sX_hi = (u16*)d_in[0];          // x buffer (x consumed during layer 0)
    u16* sX_lo = sX_hi + P;
    u16* sD_hi = (u16*)d_out;
    u16* sD_lo = sD_hi + P;

    int NB  = (N + 255) / 256;
    int NBE = (E + 255) / 256;
    int NBG = (N + 127) / 128;    // 391 GEMM blocks (128 rows each)
    int NBA = (N + 3) / 4;        // 12500 agg blocks (one wave per node)
    int NBQ = (int)((P / 4 + 255) / 256);

    // ---- preprocessing ----
    k_detect<<<1, 256, 0, stream>>>(ei, S_gflag, E);
    k_zero32<<<NB, 256, 0, stream>>>((unsigned int*)S_deg, N);
    k_deg<<<NBE, 256, 0, stream>>>(ei, S_gflag, S_deg, E, N);
    k_dinv<<<NB, 256, 0, stream>>>(S_deg, S_dinv, N);
    k_scan1<<<NB, 256, 0, stream>>>(S_deg, S_offs, S_bsum, N);
    k_scan2<<<1, 256, 0, stream>>>(S_bsum, S_bscan, NB);
    k_scan3<<<NB, 256, 0, stream>>>(S_offs, S_bscan, S_cursor, N, E);
    k_place<<<NBE, 256, 0, stream>>>(ei, S_gflag, eattr, S_cursor, S_row, S_ea, E, N);
    k_move<<<NBE, 256, 0, stream>>>(S_row, S_ea, S_dinv, S_offs, rowArr, eaP, dinvF, offsF, E, N);
    k_zero32<<<1, 256, 0, stream>>>((unsigned int*)diag, 256);
    k_precheckN<<<NB, 256, 0, stream>>>(offsF, S_cursor, dinvF, S_gflag, diag, N, E);
    k_precheckE<<<NBE, 256, 0, stream>>>(rowArr, diag, E, N);

    // ---- layers: even l -> dst = D(d_out), odd l -> dst = X; agg planes live in dst.
    //      BN deferral: planes hold PRE-BN y; consumers apply scale/shift from the
    //      previous layer's k_bnscale. Non-final k_bnapply launches removed. ----
    for (int l = 0; l < NLAYERS; ++l) {
        int even = (l % 2 == 0);
        u16* dst_hi = even ? sD_hi : sX_hi;
        u16* dst_lo = even ? sD_lo : sX_lo;
        const void* hinA; const u16* hin_lo; int hf32;
        if (l == 0) { hinA = (const void*)x; hin_lo = 0; hf32 = 1; }
        else if (even) { hinA = (const void*)sX_hi; hin_lo = sX_lo; hf32 = 0; }
        else { hinA = (const void*)sD_hi; hin_lo = sD_lo; hf32 = 0; }

        k_wsplit<<<64, 256, 0, stream>>>(mlp_w + (size_t)l * 512 * HID, wpH, wpL, colsum);
        k_agg<<<NBA, 256, 0, stream>>>(hinA, hin_lo, hf32, offsF, rowArr, eaP, dinvF,
                                       ew1 + (size_t)l * 128, ew2 + (size_t)l * 384,
                                       scaleF, shiftF,
                                       dst_hi, dst_lo, diag, N);
        MPNN_79044578115931_kernel<<<NBG, 256, 0, stream>>>(
            hinA, hin_lo, hf32, dst_hi, dst_lo, wpH, wpL,
            mlp_b + (size_t)l * HID, scaleF, shiftF,
            dst_hi, dst_lo, colsum, colsq, diag, N);
        k_bnscale<<<1, 256, 0, stream>>>(colsum, colsq,
                                         bn_g + (size_t)l * HID, bn_b + (size_t)l * HID,
                                         scaleF, shiftF, diag, N);
        if (l == NLAYERS - 1) {
            // final: BN (no relu) -> fp32 into X buffer, then copy back to d_out
            k_bnapply<<<NBQ, 256, 0, stream>>>(dst_hi, dst_lo, dst_hi, dst_lo, scaleF, shiftF,
                                               (float*)d_in[0], 1, 0, (int)P);
        }
    }

    hipMemcpyAsync(d_out, d_in[0], P * 4, hipMemcpyDeviceToDevice, stream);
    k_encode<<<1, 64, 0, stream>>>(diag, (float*)d_out);
}

// Round 10
// 859.010 us; speedup vs baseline: 2.5324x; 1.0577x over previous
//
#include <hip/hip_runtime.h>
#include <stdint.h>

typedef short short8 __attribute__((ext_vector_type(8)));
typedef float f32x4 __attribute__((ext_vector_type(4)));
typedef unsigned short u16;

#define HID 256
#define NLAYERS 5
#define BN_EPS 1e-5f

__device__ __forceinline__ float bf2f(u16 u) {
    union { unsigned int i; float f; } v;
    v.i = ((unsigned int)u) << 16;
    return v.f;
}
__device__ __forceinline__ u16 f2bf(float f) {
    union { float f; unsigned int i; } v;
    v.f = f;
    unsigned int r = v.i + 0x7FFFu + ((v.i >> 16) & 1u);   // RNE
    return (u16)(r >> 16);
}
// split fp32 -> (hi, lo) bf16 pair: hi+lo ~ 17-bit mantissa approximation
__device__ __forceinline__ void split_bf(float f, u16& hi, u16& lo) {
    hi = f2bf(f);
    lo = f2bf(f - bf2f(hi));
}

// 16-B direct global->LDS copy (vmcnt-tracked; drained by __syncthreads).
__device__ __forceinline__ void gl_lds16(const void* gsrc, void* ldst) {
    const __attribute__((address_space(1))) unsigned int* g =
        reinterpret_cast<const __attribute__((address_space(1))) unsigned int*>(
            reinterpret_cast<uintptr_t>(gsrc));
    __attribute__((address_space(3))) unsigned int* l =
        reinterpret_cast<__attribute__((address_space(3))) unsigned int*>(
            reinterpret_cast<uintptr_t>(ldst));
    __builtin_amdgcn_global_load_lds(g, l, 16, 0, 0);
}

// ---------------- utility ----------------

__global__ __launch_bounds__(256) void k_zero32(unsigned int* p, int n) {
    int i = blockIdx.x * 256 + threadIdx.x;
    if (i < n) p[i] = 0u;
}

// ---------------- graph preprocessing (staged in d_out) ----------------

__global__ __launch_bounds__(256) void k_detect(const int* ei, int* flag, int E) {
    __shared__ int nz;
    if (threadIdx.x == 0) nz = 0;
    __syncthreads();
    int lim = (2 * E < 4096) ? 2 * E : 4096;
    int c = 0;
    for (int i = threadIdx.x; 2 * i + 1 < lim; i += 256) c += (ei[2 * i + 1] != 0);
    atomicAdd(&nz, c);
    __syncthreads();
    if (threadIdx.x == 0) flag[0] = (nz == 0) ? 1 : 0;   // 1 => int64 layout
}

__global__ __launch_bounds__(256) void k_deg(const int* ei, const int* flag, int* deg, int E, int N) {
    int e = blockIdx.x * 256 + threadIdx.x;
    if (e >= E) return;
    int w = flag[0];
    int col = w ? ei[2 * (E + e)] : ei[E + e];
    if ((unsigned)col < (unsigned)N) atomicAdd(&deg[col], 1);
}

__global__ __launch_bounds__(256) void k_dinv(const int* deg, float* dinv, int N) {
    int n = blockIdx.x * 256 + threadIdx.x;
    if (n < N) { int d = deg[n]; dinv[n] = d > 0 ? rsqrtf((float)d) : 0.0f; }
}

__global__ __launch_bounds__(256) void k_scan1(const int* deg, int* offs, int* bsum, int N) {
    __shared__ int s[256];
    int tid = threadIdx.x;
    int i = blockIdx.x * 256 + tid;
    int v = (i < N) ? deg[i] : 0;
    s[tid] = v;
    __syncthreads();
    for (int off = 1; off < 256; off <<= 1) {
        int t = (tid >= off) ? s[tid - off] : 0;
        __syncthreads();
        s[tid] += t;
        __syncthreads();
    }
    if (i < N) offs[i] = s[tid] - v;
    if (tid == 255) bsum[blockIdx.x] = s[tid];
}

__global__ __launch_bounds__(256) void k_scan2(const int* bsum, int* bscan, int NB) {
    __shared__ int s[256];
    int tid = threadIdx.x;
    int v = (tid < NB) ? bsum[tid] : 0;
    s[tid] = v;
    __syncthreads();
    for (int off = 1; off < 256; off <<= 1) {
        int t = (tid >= off) ? s[tid - off] : 0;
        __syncthreads();
        s[tid] += t;
        __syncthreads();
    }
    bscan[tid] = s[tid] - v;
}

__global__ __launch_bounds__(256) void k_scan3(int* offs, const int* bscan, int* cursor, int N, int E) {
    int i = blockIdx.x * 256 + threadIdx.x;
    if (i < N) {
        int o = offs[i] + bscan[blockIdx.x];
        offs[i] = o;
        cursor[i] = o;
    }
    if (i == 0) offs[N] = E;
}

__global__ __launch_bounds__(256) void k_place(const int* ei, const int* flag, const float4* eattr,
                                               int* cursor, int* srow, float4* sea, int E, int N) {
    int e = blockIdx.x * 256 + threadIdx.x;
    if (e >= E) return;
    int w = flag[0];
    int r = w ? ei[2 * e] : ei[e];
    int c = w ? ei[2 * (E + e)] : ei[E + e];
    if ((unsigned)c >= (unsigned)N) return;
    int p = atomicAdd(&cursor[c], 1);
    srow[p] = r;
    sea[p] = eattr[e];
}

__global__ __launch_bounds__(256) void k_move(const int* srow, const float4* sea, const float* sdinv,
                                              const int* soffs, int* rowArr, float4* eaP,
                                              float* dinvF, int* offsF, int E, int N) {
    int i = blockIdx.x * 256 + threadIdx.x;
    if (i < E) { rowArr[i] = srow[i]; eaP[i] = sea[i]; }
    if (i < N) dinvF[i] = sdinv[i];
    if (i <= N) offsF[i] = soffs[i];
}

__global__ __launch_bounds__(256) void k_precheckN(const int* offsF, const int* cursor, const float* dinvF,
                                                   const int* gflag, int* diag, int N, int E) {
    int i = blockIdx.x * 256 + threadIdx.x;
    if (i < N) {
        if (offsF[i + 1] < offsF[i]) atomicOr(&diag[0], 1);
        if (cursor[i] != offsF[i + 1]) atomicOr(&diag[0], 2);
        float d = dinvF[i];
        if (!(d == d) || fabsf(d) > 1e10f) atomicOr(&diag[0], 4);
    }
    if (i == 0) {
        if (offsF[N] != E) atomicOr(&diag[0], 8);
        diag[7] = gflag[0];
    }
}
__global__ __launch_bounds__(256) void k_precheckE(const int* rowArr, int* diag, int E, int N) {
    int p = blockIdx.x * 256 + threadIdx.x;
    if (p < E && (unsigned)rowArr[p] >= (unsigned)N) atomicOr(&diag[0], 16);
}

// Per-layer: round W (fp32 512x256 row-major) to bf16 in MFMA B-fragment order,
// kb-major: frag t = kb*1024 + nbg*64 + lane holds
// W[kb*32 + (lane>>4)*8 + j][nbg*16 + (lane&15)], j=0..7.
// v10: hi plane ONLY (Ahi·Wlo term dropped — error ~1e-3/output/layer, see GEMM note).
// Block 0 also zeroes the BN stats accumulators (512 floats at colsum).
__global__ __launch_bounds__(256) void k_wsplit(const float* W, u16* wpH, float* colsum) {
    if (blockIdx.x == 0) {
        colsum[threadIdx.x] = 0.f;
        colsum[256 + threadIdx.x] = 0.f;
    }
    int t = blockIdx.x * 256 + threadIdx.x;   // 64 blocks -> 16384 frags
    int lane = t & 63;
    int nbg = (t >> 6) & 15;
    int kb = t >> 10;
    int quad = lane >> 4, nl = lane & 15;
    const float* src = W + (size_t)(kb * 32 + quad * 8) * HID + nbg * 16 + nl;
    short8 vh;
#pragma unroll
    for (int j = 0; j < 8; ++j) vh[j] = (short)f2bf(src[(size_t)j * HID]);
    *((short8*)wpH + t) = vh;
}

// ---------------- per-layer: aggregation (one wave per node), split output ----------------
// BN deferral: for l>=1 the hin plane holds y = relu(A·W+b) PRE-BN; this kernel
// applies h = relu(scale*y + shift) on the fly per gathered element (BW-bound -> free).
// Gathers ONLY the hi plane (R8 bandwidth win).
#define FEA(ea, j) ((ea).w * w1v[j] + (ea).x * w20[j] + (ea).y * w21[j] + (ea).z * w22[j])
#define BNX(u, comp) (fmaxf(sc4.comp * bf2f(u) + sh4.comp, 0.f))

__global__ __launch_bounds__(256) void k_agg(const void* hin_, const u16* hin_lo, int hf32,
                                             const int* offs, const int* rowArr, const float4* eaP,
                                             const float* dinv, const float* ew1, const float* ew2,
                                             const float* bnsc, const float* bnsh,
                                             u16* agg_hi, u16* agg_lo, int* diag, int M) {
    (void)hin_lo;
    int lane = threadIdx.x & 63, wave = threadIdx.x >> 6;
    int n = blockIdx.x * 4 + wave;

    float w1v[4] = {0.f, 0.f, 0.f, 0.f};
    float w20[4] = {0.f, 0.f, 0.f, 0.f};
    float w21[4] = {0.f, 0.f, 0.f, 0.f};
    float w22[4] = {0.f, 0.f, 0.f, 0.f};
    if (lane < 32) {
        int c = lane * 4;
#pragma unroll
        for (int j = 0; j < 4; ++j) w1v[j] = ew1[c + j];
    } else {
        int cc = (lane - 32) * 4;
#pragma unroll
        for (int j = 0; j < 4; ++j) {
            w20[j] = ew2[cc + j];
            w21[j] = ew2[128 + cc + j];
            w22[j] = ew2[256 + cc + j];
        }
    }

    float4 sc4 = {0.f, 0.f, 0.f, 0.f}, sh4 = {0.f, 0.f, 0.f, 0.f};
    if (!hf32) {
        sc4 = ((const float4*)bnsc)[lane];
        sh4 = ((const float4*)bnsh)[lane];
    }

    if (n >= M) return;
    float dn = dinv[n];
    int s = offs[n], e = offs[n + 1];
    float a0 = 0.f, a1 = 0.f, a2 = 0.f, a3 = 0.f;
    int p = s;

    if (hf32) {
        for (; p + 4 <= e; p += 4) {
            int r0 = rowArr[p + 0], r1 = rowArr[p + 1], r2 = rowArr[p + 2], r3 = rowArr[p + 3];
            float4 ea0 = eaP[p + 0], ea1 = eaP[p + 1], ea2 = eaP[p + 2], ea3 = eaP[p + 3];
            float4 hv0 = *((const float4*)hin_ + (size_t)r0 * 64 + lane);
            float4 hv1 = *((const float4*)hin_ + (size_t)r1 * 64 + lane);
            float4 hv2 = *((const float4*)hin_ + (size_t)r2 * 64 + lane);
            float4 hv3 = *((const float4*)hin_ + (size_t)r3 * 64 + lane);
            float n0 = dn * dinv[r0], n1 = dn * dinv[r1], n2 = dn * dinv[r2], n3 = dn * dinv[r3];
            a0 += n0 * (hv0.x + FEA(ea0, 0)) + n1 * (hv1.x + FEA(ea1, 0))
                + n2 * (hv2.x + FEA(ea2, 0)) + n3 * (hv3.x + FEA(ea3, 0));
            a1 += n0 * (hv0.y + FEA(ea0, 1)) + n1 * (hv1.y + FEA(ea1, 1))
                + n2 * (hv2.y + FEA(ea2, 1)) + n3 * (hv3.y + FEA(ea3, 1));
            a2 += n0 * (hv0.z + FEA(ea0, 2)) + n1 * (hv1.z + FEA(ea1, 2))
                + n2 * (hv2.z + FEA(ea2, 2)) + n3 * (hv3.z + FEA(ea3, 2));
            a3 += n0 * (hv0.w + FEA(ea0, 3)) + n1 * (hv1.w + FEA(ea1, 3))
                + n2 * (hv2.w + FEA(ea2, 3)) + n3 * (hv3.w + FEA(ea3, 3));
        }
        for (; p < e; ++p) {
            int r = rowArr[p];
            float4 ea = eaP[p];
            float nrm = dn * dinv[r];
            float4 hv = *((const float4*)hin_ + (size_t)r * 64 + lane);
            a0 += nrm * (hv.x + FEA(ea, 0));
            a1 += nrm * (hv.y + FEA(ea, 1));
            a2 += nrm * (hv.z + FEA(ea, 2));
            a3 += nrm * (hv.w + FEA(ea, 3));
        }
    } else {
        for (; p + 4 <= e; p += 4) {
            int r0 = rowArr[p + 0], r1 = rowArr[p + 1], r2 = rowArr[p + 2], r3 = rowArr[p + 3];
            float4 ea0 = eaP[p + 0], ea1 = eaP[p + 1], ea2 = eaP[p + 2], ea3 = eaP[p + 3];
            ushort4 hh0 = *((const ushort4*)hin_ + (size_t)r0 * 64 + lane);
            ushort4 hh1 = *((const ushort4*)hin_ + (size_t)r1 * 64 + lane);
            ushort4 hh2 = *((const ushort4*)hin_ + (size_t)r2 * 64 + lane);
            ushort4 hh3 = *((const ushort4*)hin_ + (size_t)r3 * 64 + lane);
            float n0 = dn * dinv[r0], n1 = dn * dinv[r1], n2 = dn * dinv[r2], n3 = dn * dinv[r3];
            a0 += n0 * (BNX(hh0.x, x) + FEA(ea0, 0)) + n1 * (BNX(hh1.x, x) + FEA(ea1, 0))
                + n2 * (BNX(hh2.x, x) + FEA(ea2, 0)) + n3 * (BNX(hh3.x, x) + FEA(ea3, 0));
            a1 += n0 * (BNX(hh0.y, y) + FEA(ea0, 1)) + n1 * (BNX(hh1.y, y) + FEA(ea1, 1))
                + n2 * (BNX(hh2.y, y) + FEA(ea2, 1)) + n3 * (BNX(hh3.y, y) + FEA(ea3, 1));
            a2 += n0 * (BNX(hh0.z, z) + FEA(ea0, 2)) + n1 * (BNX(hh1.z, z) + FEA(ea1, 2))
                + n2 * (BNX(hh2.z, z) + FEA(ea2, 2)) + n3 * (BNX(hh3.z, z) + FEA(ea3, 2));
            a3 += n0 * (BNX(hh0.w, w) + FEA(ea0, 3)) + n1 * (BNX(hh1.w, w) + FEA(ea1, 3))
                + n2 * (BNX(hh2.w, w) + FEA(ea2, 3)) + n3 * (BNX(hh3.w, w) + FEA(ea3, 3));
        }
        for (; p < e; ++p) {
            int r = rowArr[p];
            float4 ea = eaP[p];
            float nrm = dn * dinv[r];
            ushort4 hh = *((const ushort4*)hin_ + (size_t)r * 64 + lane);
            a0 += nrm * (BNX(hh.x, x) + FEA(ea, 0));
            a1 += nrm * (BNX(hh.y, y) + FEA(ea, 1));
            a2 += nrm * (BNX(hh.z, z) + FEA(ea, 2));
            a3 += nrm * (BNX(hh.w, w) + FEA(ea, 3));
        }
    }

    int bad = 0;
    if (!(a0 == a0)) { a0 = 777.f; bad++; }
    if (!(a1 == a1)) { a1 = 777.f; bad++; }
    if (!(a2 == a2)) { a2 = 777.f; bad++; }
    if (!(a3 == a3)) { a3 = 777.f; bad++; }
    if (bad) atomicAdd(&diag[1], bad);
    ushort4 oh, ol;
    split_bf(a0, oh.x, ol.x);
    split_bf(a1, oh.y, ol.y);
    split_bf(a2, oh.z, ol.z);
    split_bf(a3, oh.w, ol.w);
    *((ushort4*)agg_hi + (size_t)n * 64 + lane) = oh;
    *((ushort4*)agg_lo + (size_t)n * 64 + lane) = ol;
}

// ---------------- per-layer: split-precision MFMA GEMM + bias/ReLU + BN stats ----------------
// y = relu(A·W + bias); A = [h | agg]; v10: acc = Ahi·Whi + Alo·Whi  (2-term).
// The dropped Ahi·Wlo term is |err| ~ sqrt(512)·rms(A)~0.8·rms(Wrnd)~5e-5 ~ 1e-3 per
// output per layer — noise vs absmax 0.277 / threshold 0.925. A keeps 17-bit (hi+lo).
// Gains: inner loop 6->4 MFMAs, B-stage 32->16 KB/K-step (4 gl_lds16/thread), wpL dead.
// Structure = R8's measured optimum: 128 rows x 256 cols, 391 blocks, 2-barrier K-loop,
// row-exclusive (in-place y-over-agg safe). BN deferral on A h-path for l>=1 (kb<8):
// h = relu(sc*(hi+lo)+sh) reconstructed post-drain; sc/sh loads covered by the drain.
__global__ __launch_bounds__(256, 2) void MPNN_79044578115931_kernel(
        const void* hinA_, const u16* hinA_lo, int hf32,
        const u16* agg_hi, const u16* agg_lo,
        const u16* wpH, const float* bias,
        const float* bnsc, const float* bnsh,
        u16* y_hi, u16* y_lo,
        float* colsum, float* colsumsq, int* diag, int M) {
    __shared__ __align__(16) u16 bstage[8192];   // 16 KB: hi frags only
    __shared__ float lsum[256];
    __shared__ float lsq[256];

    int tid = threadIdx.x;
    int lane = tid & 63, wave = tid >> 6;
    int quad = lane >> 4, nl = lane & 15;
    int mBase = blockIdx.x * 128 + wave * 32;
    int rowA0 = mBase + nl;          // row-group 0
    int rowA1 = mBase + 16 + nl;     // row-group 1
    if (rowA0 >= M) rowA0 = M - 1;
    if (rowA1 >= M) rowA1 = M - 1;

    lsum[tid] = 0.f;
    lsq[tid] = 0.f;

    f32x4 acc0[16], acc1[16];
#pragma unroll
    for (int i = 0; i < 16; ++i) {
        acc0[i] = {0.f, 0.f, 0.f, 0.f};
        acc1[i] = {0.f, 0.f, 0.f, 0.f};
    }

    for (int kb = 0; kb < 16; ++kb) {
        __syncthreads();   // previous K-step's LDS reads done before overwrite

        // stage B kb-slice: 1024 hi frags x 16 B, thread t handles frags {i*256+t}
        const u16* srcH = wpH + (size_t)kb * 8192;
#pragma unroll
        for (int i = 0; i < 4; ++i) {
            int ci = i * 256 + tid;
            gl_lds16(srcH + ci * 8, &bstage[ci * 8]);
        }

        // A fragments for this K-step (latency covered by the drain barrier below)
        short8 a0h, a0l, a1h, a1l;
        float4 scv0, scv1, shv0, shv1;
        if (kb < 8) {
            int k0 = kb * 32 + quad * 8;
            if (hf32) {
                const float* hp0 = (const float*)hinA_ + (size_t)rowA0 * HID + k0;
                const float* hp1 = (const float*)hinA_ + (size_t)rowA1 * HID + k0;
#pragma unroll
                for (int j = 0; j < 8; ++j) {
                    u16 h, l;
                    split_bf(hp0[j], h, l);
                    a0h[j] = (short)h; a0l[j] = (short)l;
                    split_bf(hp1[j], h, l);
                    a1h[j] = (short)h; a1l[j] = (short)l;
                }
            } else {
                a0h = *(const short8*)((const u16*)hinA_ + (size_t)rowA0 * HID + k0);
                a0l = *(const short8*)(hinA_lo + (size_t)rowA0 * HID + k0);
                a1h = *(const short8*)((const u16*)hinA_ + (size_t)rowA1 * HID + k0);
                a1l = *(const short8*)(hinA_lo + (size_t)rowA1 * HID + k0);
                int q4 = k0 >> 2;
                scv0 = ((const float4*)bnsc)[q4];
                scv1 = ((const float4*)bnsc)[q4 + 1];
                shv0 = ((const float4*)bnsh)[q4];
                shv1 = ((const float4*)bnsh)[q4 + 1];
            }
        } else {
            int k0 = (kb - 8) * 32 + quad * 8;
            a0h = *(const short8*)(agg_hi + (size_t)rowA0 * HID + k0);
            a0l = *(const short8*)(agg_lo + (size_t)rowA0 * HID + k0);
            a1h = *(const short8*)(agg_hi + (size_t)rowA1 * HID + k0);
            a1l = *(const short8*)(agg_lo + (size_t)rowA1 * HID + k0);
        }

        __syncthreads();   // drains vmcnt(0): staged B + A frags + sc/sh ready

        // BN deferral: reconstruct h = relu(sc*(hi+lo)+sh), re-split -> A fragments
        if (!hf32 && kb < 8) {
            float scr[8] = {scv0.x, scv0.y, scv0.z, scv0.w, scv1.x, scv1.y, scv1.z, scv1.w};
            float shr[8] = {shv0.x, shv0.y, shv0.z, shv0.w, shv1.x, shv1.y, shv1.z, shv1.w};
#pragma unroll
            for (int j = 0; j < 8; ++j) {
                float f0 = scr[j] * (bf2f((u16)a0h[j]) + bf2f((u16)a0l[j])) + shr[j];
                f0 = f0 > 0.f ? f0 : 0.f;
                float f1 = scr[j] * (bf2f((u16)a1h[j]) + bf2f((u16)a1l[j])) + shr[j];
                f1 = f1 > 0.f ? f1 : 0.f;
                u16 h, l;
                split_bf(f0, h, l);
                a0h[j] = (short)h; a0l[j] = (short)l;
                split_bf(f1, h, l);
                a1h[j] = (short)h; a1l[j] = (short)l;
            }
        }

        const short8* bbase = (const short8*)bstage;
#pragma unroll
        for (int nbg = 0; nbg < 16; ++nbg) {
            short8 bh = bbase[nbg * 64 + lane];
            acc0[nbg] = __builtin_amdgcn_mfma_f32_16x16x32_bf16(a0h, bh, acc0[nbg], 0, 0, 0);
            acc1[nbg] = __builtin_amdgcn_mfma_f32_16x16x32_bf16(a1h, bh, acc1[nbg], 0, 0, 0);
            acc0[nbg] = __builtin_amdgcn_mfma_f32_16x16x32_bf16(a0l, bh, acc0[nbg], 0, 0, 0);
            acc1[nbg] = __builtin_amdgcn_mfma_f32_16x16x32_bf16(a1l, bh, acc1[nbg], 0, 0, 0);
        }
    }

    __syncthreads();   // all global agg reads complete -> in-place y write safe

    // epilogue: bias + ReLU + split-store + BN partial stats (pre-split fp32)
    int badY = 0;
#pragma unroll
    for (int nbg = 0; nbg < 16; ++nbg) {
        int c = nbg * 16 + nl;
        float bv = bias[c];
        float s = 0.f, q = 0.f;
#pragma unroll
        for (int r = 0; r < 4; ++r) {
            int m = mBase + quad * 4 + r;
            if (m < M) {
                float v = acc0[nbg][r] + bv;
                if (!(v == v)) { v = 777.f; badY++; }
                v = v > 0.f ? v : 0.f;
                u16 h, l;
                split_bf(v, h, l);
                y_hi[(size_t)m * HID + c] = h;
                y_lo[(size_t)m * HID + c] = l;
                s += v;
                q += v * v;
            }
        }
        atomicAdd(&lsum[c], s);
        atomicAdd(&lsq[c], q);
    }
#pragma unroll
    for (int nbg = 0; nbg < 16; ++nbg) {
        int c = nbg * 16 + nl;
        float bv = bias[c];
        float s = 0.f, q = 0.f;
#pragma unroll
        for (int r = 0; r < 4; ++r) {
            int m = mBase + 16 + quad * 4 + r;
            if (m < M) {
                float v = acc1[nbg][r] + bv;
                if (!(v == v)) { v = 777.f; badY++; }
                v = v > 0.f ? v : 0.f;
                u16 h, l;
                split_bf(v, h, l);
                y_hi[(size_t)m * HID + c] = h;
                y_lo[(size_t)m * HID + c] = l;
                s += v;
                q += v * v;
            }
        }
        atomicAdd(&lsum[c], s);
        atomicAdd(&lsq[c], q);
    }
    if (badY) atomicAdd(&diag[2], badY);
    __syncthreads();
    atomicAdd(&colsum[tid], lsum[tid]);
    atomicAdd(&colsumsq[tid], lsq[tid]);
}

__global__ __launch_bounds__(256) void k_bnscale(const float* colsum, const float* colsumsq,
                                                 const float* g, const float* b,
                                                 float* scale, float* shift, int* diag, int M) {
    int c = threadIdx.x;
    float mu = colsum[c] / (float)M;
    float var = colsumsq[c] / (float)M - mu * mu;
    if (!(mu == mu) || !(var == var) || var > 1e30f) atomicAdd(&diag[3], 1);
    if (var < 0.f) var = 0.f;
    float sc = rsqrtf(var + BN_EPS) * g[c];
    scale[c] = sc;
    shift[c] = b[c] - mu * sc;
}

// BN apply (FINAL layer only under deferral): reads y planes, writes fp32 to outf.
__global__ __launch_bounds__(256) void k_bnapply(const u16* src_hi, const u16* src_lo,
                                                 u16* dst_hi, u16* dst_lo,
                                                 const float* scale, const float* shift,
                                                 float* outf, int finalL, int relu, int total) {
    int q4 = blockIdx.x * 256 + threadIdx.x;
    int idx = q4 * 4;
    if (idx >= total) return;
    int c = idx & (HID - 1);
    ushort4 vh = *((const ushort4*)src_hi + q4);
    ushort4 vl = *((const ushort4*)src_lo + q4);
    float o0 = scale[c + 0] * (bf2f(vh.x) + bf2f(vl.x)) + shift[c + 0];
    float o1 = scale[c + 1] * (bf2f(vh.y) + bf2f(vl.y)) + shift[c + 1];
    float o2 = scale[c + 2] * (bf2f(vh.z) + bf2f(vl.z)) + shift[c + 2];
    float o3 = scale[c + 3] * (bf2f(vh.w) + bf2f(vl.w)) + shift[c + 3];
    if (relu) {
        o0 = o0 > 0.f ? o0 : 0.f;
        o1 = o1 > 0.f ? o1 : 0.f;
        o2 = o2 > 0.f ? o2 : 0.f;
        o3 = o3 > 0.f ? o3 : 0.f;
    }
    if (finalL) {
        float4 ov; ov.x = o0; ov.y = o1; ov.z = o2; ov.w = o3;
        *((float4*)outf + q4) = ov;
    } else {
        ushort4 oh, ol;
        split_bf(o0, oh.x, ol.x);
        split_bf(o1, oh.y, ol.y);
        split_bf(o2, oh.z, ol.z);
        split_bf(o3, oh.w, ol.w);
        *((ushort4*)dst_hi + q4) = oh;
        *((ushort4*)dst_lo + q4) = ol;
    }
}

// d_out[0] = (1+k+8*int64)*2^20 only if a check failed.
__global__ void k_encode(const int* diag, float* out) {
    if (threadIdx.x != 0 || blockIdx.x != 0) return;
    int k = -1;
    for (int i = 0; i < 4; ++i) if (diag[i] != 0) { k = i; break; }
    if (k < 0) return;
    out[0] = (float)(1 + k + (diag[7] != 0 ? 8 : 0)) * 1048576.0f;
}

// ---------------- launcher (zero workspace dependency) ----------------

extern "C" void kernel_launch(void* const* d_in, const int* in_sizes, int n_in,
                              void* d_out, int out_size, void* d_ws, size_t ws_size,
                              hipStream_t stream) {
    const float*  x     = (const float*)d_in[0];
    const int*    ei    = (const int*)d_in[1];
    const float4* eattr = (const float4*)d_in[2];
    const float*  mlp_w = (const float*)d_in[3];
    const float*  mlp_b = (const float*)d_in[4];
    const float*  ew1   = (const float*)d_in[5];
    const float*  ew2   = (const float*)d_in[6];
    const float*  bn_g  = (const float*)d_in[7];
    const float*  bn_b  = (const float*)d_in[8];
    (void)n_in; (void)out_size; (void)d_ws; (void)ws_size;

    const int N = in_sizes[0] / HID;   // 50000
    const int E = in_sizes[1] / 2;     // 320000
    const size_t P = (size_t)N * HID;  // plane elements

    // ---- CSR staging inside d_out (dead before layer 0 writes d_out) ----
    char* st = (char*)d_out;
    int*    S_deg    = (int*)   (st + 0);
    float*  S_dinv   = (float*) (st + 204800);
    int*    S_offs   = (int*)   (st + 409600);
    int*    S_cursor = (int*)   (st + 614400);
    int*    S_bsum   = (int*)   (st + 819200);
    int*    S_bscan  = (int*)   (st + 820224);
    int*    S_gflag  = (int*)   (st + 821248);
    int*    S_row    = (int*)   (st + 1048576);
    float4* S_ea     = (float4*)(st + 2621440);   // ends 7,741,440 < 51.2 MB

    // ---- small homes in edge_index buffer (>=2.56 MB); eattr buffer holds eaP ----
    char* eb = (char*)d_in[1];
    int*   rowArr = (int*)  (eb + 0);          // 1,280,000
    float* dinvF  = (float*)(eb + 1280000);    // 200,000
    int*   offsF  = (int*)  (eb + 1480000);    // 200,004
    float* colsum = (float*)(eb + 1680128);
    float* colsq  = (float*)(eb + 1681152);
    float* scaleF = (float*)(eb + 1682176);
    float* shiftF = (float*)(eb + 1683200);
    int*   diag   = (int*)  (eb + 1684224);    // 1 KB
    u16*   wpH    = (u16*)  (eb + 1685504);    // 256 KB -> ends 1,947,648 <= 2,560,000
    float4* eaP   = (float4*)d_in[2];          // 5,120,000 exact

    // ---- h slots as bf16 hi/lo planes (each slot = 2 planes = 51.2 MB) ----
    u16* sX_hi = (u16*)d_in[0];          // x buffer (x consumed during layer 0)
    u16* sX_lo = sX_hi + P;
    u16* sD_hi = (u16*)d_out;
    u16* sD_lo = sD_hi + P;

    int NB  = (N + 255) / 256;
    int NBE = (E + 255) / 256;
    int NBG = (N + 127) / 128;    // 391 GEMM blocks (128 rows each)
    int NBA = (N + 3) / 4;        // 12500 agg blocks (one wave per node)
    int NBQ = (int)((P / 4 + 255) / 256);

    // ---- preprocessing ----
    k_detect<<<1, 256, 0, stream>>>(ei, S_gflag, E);
    k_zero32<<<NB, 256, 0, stream>>>((unsigned int*)S_deg, N);
    k_deg<<<NBE, 256, 0, stream>>>(ei, S_gflag, S_deg, E, N);
    k_dinv<<<NB, 256, 0, stream>>>(S_deg, S_dinv, N);
    k_scan1<<<NB, 256, 0, stream>>>(S_deg, S_offs, S_bsum, N);
    k_scan2<<<1, 256, 0, stream>>>(S_bsum, S_bscan, NB);
    k_scan3<<<NB, 256, 0, stream>>>(S_offs, S_bscan, S_cursor, N, E);
    k_place<<<NBE, 256, 0, stream>>>(ei, S_gflag, eattr, S_cursor, S_row, S_ea, E, N);
    k_move<<<NBE, 256, 0, stream>>>(S_row, S_ea, S_dinv, S_offs, rowArr, eaP, dinvF, offsF, E, N);
    k_zero32<<<1, 256, 0, stream>>>((unsigned int*)diag, 256);
    k_precheckN<<<NB, 256, 0, stream>>>(offsF, S_cursor, dinvF, S_gflag, diag, N, E);
    k_precheckE<<<NBE, 256, 0, stream>>>(rowArr, diag, E, N);

    // ---- layers: even l -> dst = D(d_out), odd l -> dst = X; agg planes live in dst.
    //      BN deferral: planes hold PRE-BN y; consumers apply scale/shift from the
    //      previous layer's k_bnscale. Non-final k_bnapply launches removed. ----
    for (int l = 0; l < NLAYERS; ++l) {
        int even = (l % 2 == 0);
        u16* dst_hi = even ? sD_hi : sX_hi;
        u16* dst_lo = even ? sD_lo : sX_lo;
        const void* hinA; const u16* hin_lo; int hf32;
        if (l == 0) { hinA = (const void*)x; hin_lo = 0; hf32 = 1; }
        else if (even) { hinA = (const void*)sX_hi; hin_lo = sX_lo; hf32 = 0; }
        else { hinA = (const void*)sD_hi; hin_lo = sD_lo; hf32 = 0; }

        k_wsplit<<<64, 256, 0, stream>>>(mlp_w + (size_t)l * 512 * HID, wpH, colsum);
        k_agg<<<NBA, 256, 0, stream>>>(hinA, hin_lo, hf32, offsF, rowArr, eaP, dinvF,
                                       ew1 + (size_t)l * 128, ew2 + (size_t)l * 384,
                                       scaleF, shiftF,
                                       dst_hi, dst_lo, diag, N);
        MPNN_79044578115931_kernel<<<NBG, 256, 0, stream>>>(
            hinA, hin_lo, hf32, dst_hi, dst_lo, wpH,
            mlp_b + (size_t)l * HID, scaleF, shiftF,
            dst_hi, dst_lo, colsum, colsq, diag, N);
        k_bnscale<<<1, 256, 0, stream>>>(colsum, colsq,
                                         bn_g + (size_t)l * HID, bn_b + (size_t)l * HID,
                                         scaleF, shiftF, diag, N);
        if (l == NLAYERS - 1) {
            // final: BN (no relu) -> fp32 into X buffer, then copy back to d_out
            k_bnapply<<<NBQ, 256, 0, stream>>>(dst_hi, dst_lo, dst_hi, dst_lo, scaleF, shiftF,
                                               (float*)d_in[0], 1, 0, (int)P);
        }
    }

    hipMemcpyAsync(d_out, d_in[0], P * 4, hipMemcpyDeviceToDevice, stream);
    k_encode<<<1, 64, 0, stream>>>(diag, (float*)d_out);
}

// Round 11
// 851.732 us; speedup vs baseline: 2.5540x; 1.0085x over previous
//
#include <hip/hip_runtime.h>
#include <stdint.h>

typedef short short8 __attribute__((ext_vector_type(8)));
typedef float f32x4 __attribute__((ext_vector_type(4)));
typedef unsigned short u16;

#define HID 256
#define NLAYERS 5
#define BN_EPS 1e-5f

__device__ __forceinline__ float bf2f(u16 u) {
    union { unsigned int i; float f; } v;
    v.i = ((unsigned int)u) << 16;
    return v.f;
}
__device__ __forceinline__ u16 f2bf(float f) {
    union { float f; unsigned int i; } v;
    v.f = f;
    unsigned int r = v.i + 0x7FFFu + ((v.i >> 16) & 1u);   // RNE
    return (u16)(r >> 16);
}
// split fp32 -> (hi, lo) bf16 pair: hi+lo ~ 17-bit mantissa approximation
__device__ __forceinline__ void split_bf(float f, u16& hi, u16& lo) {
    hi = f2bf(f);
    lo = f2bf(f - bf2f(hi));
}

// 16-B direct global->LDS copy (vmcnt-tracked; drained by __syncthreads).
__device__ __forceinline__ void gl_lds16(const void* gsrc, void* ldst) {
    const __attribute__((address_space(1))) unsigned int* g =
        reinterpret_cast<const __attribute__((address_space(1))) unsigned int*>(
            reinterpret_cast<uintptr_t>(gsrc));
    __attribute__((address_space(3))) unsigned int* l =
        reinterpret_cast<__attribute__((address_space(3))) unsigned int*>(
            reinterpret_cast<uintptr_t>(ldst));
    __builtin_amdgcn_global_load_lds(g, l, 16, 0, 0);
}

// ---------------- utility ----------------

__global__ __launch_bounds__(256) void k_zero32(unsigned int* p, int n) {
    int i = blockIdx.x * 256 + threadIdx.x;
    if (i < n) p[i] = 0u;
}

// ---------------- graph preprocessing (staged in d_out) ----------------

__global__ __launch_bounds__(256) void k_detect(const int* ei, int* flag, int E) {
    __shared__ int nz;
    if (threadIdx.x == 0) nz = 0;
    __syncthreads();
    int lim = (2 * E < 4096) ? 2 * E : 4096;
    int c = 0;
    for (int i = threadIdx.x; 2 * i + 1 < lim; i += 256) c += (ei[2 * i + 1] != 0);
    atomicAdd(&nz, c);
    __syncthreads();
    if (threadIdx.x == 0) flag[0] = (nz == 0) ? 1 : 0;   // 1 => int64 layout
}

__global__ __launch_bounds__(256) void k_deg(const int* ei, const int* flag, int* deg, int E, int N) {
    int e = blockIdx.x * 256 + threadIdx.x;
    if (e >= E) return;
    int w = flag[0];
    int col = w ? ei[2 * (E + e)] : ei[E + e];
    if ((unsigned)col < (unsigned)N) atomicAdd(&deg[col], 1);
}

__global__ __launch_bounds__(256) void k_dinv(const int* deg, float* dinv, int N) {
    int n = blockIdx.x * 256 + threadIdx.x;
    if (n < N) { int d = deg[n]; dinv[n] = d > 0 ? rsqrtf((float)d) : 0.0f; }
}

__global__ __launch_bounds__(256) void k_scan1(const int* deg, int* offs, int* bsum, int N) {
    __shared__ int s[256];
    int tid = threadIdx.x;
    int i = blockIdx.x * 256 + tid;
    int v = (i < N) ? deg[i] : 0;
    s[tid] = v;
    __syncthreads();
    for (int off = 1; off < 256; off <<= 1) {
        int t = (tid >= off) ? s[tid - off] : 0;
        __syncthreads();
        s[tid] += t;
        __syncthreads();
    }
    if (i < N) offs[i] = s[tid] - v;
    if (tid == 255) bsum[blockIdx.x] = s[tid];
}

__global__ __launch_bounds__(256) void k_scan2(const int* bsum, int* bscan, int NB) {
    __shared__ int s[256];
    int tid = threadIdx.x;
    int v = (tid < NB) ? bsum[tid] : 0;
    s[tid] = v;
    __syncthreads();
    for (int off = 1; off < 256; off <<= 1) {
        int t = (tid >= off) ? s[tid - off] : 0;
        __syncthreads();
        s[tid] += t;
        __syncthreads();
    }
    bscan[tid] = s[tid] - v;
}

__global__ __launch_bounds__(256) void k_scan3(int* offs, const int* bscan, int* cursor, int N, int E) {
    int i = blockIdx.x * 256 + threadIdx.x;
    if (i < N) {
        int o = offs[i] + bscan[blockIdx.x];
        offs[i] = o;
        cursor[i] = o;
    }
    if (i == 0) offs[N] = E;
}

__global__ __launch_bounds__(256) void k_place(const int* ei, const int* flag, const float4* eattr,
                                               int* cursor, int* srow, float4* sea, int E, int N) {
    int e = blockIdx.x * 256 + threadIdx.x;
    if (e >= E) return;
    int w = flag[0];
    int r = w ? ei[2 * e] : ei[e];
    int c = w ? ei[2 * (E + e)] : ei[E + e];
    if ((unsigned)c >= (unsigned)N) return;
    int p = atomicAdd(&cursor[c], 1);
    srow[p] = r;
    sea[p] = eattr[e];
}

__global__ __launch_bounds__(256) void k_move(const int* srow, const float4* sea, const float* sdinv,
                                              const int* soffs, int* rowArr, float4* eaP,
                                              float* dinvF, int* offsF, int E, int N) {
    int i = blockIdx.x * 256 + threadIdx.x;
    if (i < E) { rowArr[i] = srow[i]; eaP[i] = sea[i]; }
    if (i < N) dinvF[i] = sdinv[i];
    if (i <= N) offsF[i] = soffs[i];
}

__global__ __launch_bounds__(256) void k_precheckN(const int* offsF, const int* cursor, const float* dinvF,
                                                   const int* gflag, int* diag, int N, int E) {
    int i = blockIdx.x * 256 + threadIdx.x;
    if (i < N) {
        if (offsF[i + 1] < offsF[i]) atomicOr(&diag[0], 1);
        if (cursor[i] != offsF[i + 1]) atomicOr(&diag[0], 2);
        float d = dinvF[i];
        if (!(d == d) || fabsf(d) > 1e10f) atomicOr(&diag[0], 4);
    }
    if (i == 0) {
        if (offsF[N] != E) atomicOr(&diag[0], 8);
        diag[7] = gflag[0];
    }
}
__global__ __launch_bounds__(256) void k_precheckE(const int* rowArr, int* diag, int E, int N) {
    int p = blockIdx.x * 256 + threadIdx.x;
    if (p < E && (unsigned)rowArr[p] >= (unsigned)N) atomicOr(&diag[0], 16);
}

// Per-layer: round W (fp32 512x256 row-major) to bf16 in MFMA B-fragment order,
// kb-major: frag t = kb*1024 + nbg*64 + lane holds
// W[kb*32 + (lane>>4)*8 + j][nbg*16 + (lane&15)], j=0..7.  (hi plane only — R10.)
// v11: block 0 ALSO performs the previous layer's bnscale (scale/shift from colsum)
// before zeroing the stats accumulators — removes 4 standalone bnscale dispatches.
__global__ __launch_bounds__(256) void k_wsplit(const float* W, u16* wpH, float* colsum,
                                                const float* g, const float* b,
                                                float* scale, float* shift, int* diag,
                                                int M, int doBN) {
    if (blockIdx.x == 0) {
        int c = threadIdx.x;
        if (doBN) {
            float mu = colsum[c] / (float)M;
            float var = colsum[256 + c] / (float)M - mu * mu;
            if (!(mu == mu) || !(var == var) || var > 1e30f) atomicAdd(&diag[3], 1);
            if (var < 0.f) var = 0.f;
            float sc = rsqrtf(var + BN_EPS) * g[c];
            scale[c] = sc;
            shift[c] = b[c] - mu * sc;
        }
        colsum[c] = 0.f;
        colsum[256 + c] = 0.f;
    }
    int t = blockIdx.x * 256 + threadIdx.x;   // 64 blocks -> 16384 frags
    int lane = t & 63;
    int nbg = (t >> 6) & 15;
    int kb = t >> 10;
    int quad = lane >> 4, nl = lane & 15;
    const float* src = W + (size_t)(kb * 32 + quad * 8) * HID + nbg * 16 + nl;
    short8 vh;
#pragma unroll
    for (int j = 0; j < 8; ++j) vh[j] = (short)f2bf(src[(size_t)j * HID]);
    *((short8*)wpH + t) = vh;
}

// ---------------- per-layer: aggregation (one wave per node), split output ----------------
// BN deferral: for l>=1 the hin plane holds y = relu(A·W+b) PRE-BN; this kernel
// applies h = relu(scale*y + shift) on the fly per gathered element (BW-bound -> free).
// Gathers ONLY the hi plane (R8 bandwidth win).
#define FEA(ea, j) ((ea).w * w1v[j] + (ea).x * w20[j] + (ea).y * w21[j] + (ea).z * w22[j])
#define BNX(u, comp) (fmaxf(sc4.comp * bf2f(u) + sh4.comp, 0.f))

__global__ __launch_bounds__(256) void k_agg(const void* hin_, const u16* hin_lo, int hf32,
                                             const int* offs, const int* rowArr, const float4* eaP,
                                             const float* dinv, const float* ew1, const float* ew2,
                                             const float* bnsc, const float* bnsh,
                                             u16* agg_hi, u16* agg_lo, int* diag, int M) {
    (void)hin_lo;
    int lane = threadIdx.x & 63, wave = threadIdx.x >> 6;
    int n = blockIdx.x * 4 + wave;

    float w1v[4] = {0.f, 0.f, 0.f, 0.f};
    float w20[4] = {0.f, 0.f, 0.f, 0.f};
    float w21[4] = {0.f, 0.f, 0.f, 0.f};
    float w22[4] = {0.f, 0.f, 0.f, 0.f};
    if (lane < 32) {
        int c = lane * 4;
#pragma unroll
        for (int j = 0; j < 4; ++j) w1v[j] = ew1[c + j];
    } else {
        int cc = (lane - 32) * 4;
#pragma unroll
        for (int j = 0; j < 4; ++j) {
            w20[j] = ew2[cc + j];
            w21[j] = ew2[128 + cc + j];
            w22[j] = ew2[256 + cc + j];
        }
    }

    float4 sc4 = {0.f, 0.f, 0.f, 0.f}, sh4 = {0.f, 0.f, 0.f, 0.f};
    if (!hf32) {
        sc4 = ((const float4*)bnsc)[lane];
        sh4 = ((const float4*)bnsh)[lane];
    }

    if (n >= M) return;
    float dn = dinv[n];
    int s = offs[n], e = offs[n + 1];
    float a0 = 0.f, a1 = 0.f, a2 = 0.f, a3 = 0.f;
    int p = s;

    if (hf32) {
        for (; p + 4 <= e; p += 4) {
            int r0 = rowArr[p + 0], r1 = rowArr[p + 1], r2 = rowArr[p + 2], r3 = rowArr[p + 3];
            float4 ea0 = eaP[p + 0], ea1 = eaP[p + 1], ea2 = eaP[p + 2], ea3 = eaP[p + 3];
            float4 hv0 = *((const float4*)hin_ + (size_t)r0 * 64 + lane);
            float4 hv1 = *((const float4*)hin_ + (size_t)r1 * 64 + lane);
            float4 hv2 = *((const float4*)hin_ + (size_t)r2 * 64 + lane);
            float4 hv3 = *((const float4*)hin_ + (size_t)r3 * 64 + lane);
            float n0 = dn * dinv[r0], n1 = dn * dinv[r1], n2 = dn * dinv[r2], n3 = dn * dinv[r3];
            a0 += n0 * (hv0.x + FEA(ea0, 0)) + n1 * (hv1.x + FEA(ea1, 0))
                + n2 * (hv2.x + FEA(ea2, 0)) + n3 * (hv3.x + FEA(ea3, 0));
            a1 += n0 * (hv0.y + FEA(ea0, 1)) + n1 * (hv1.y + FEA(ea1, 1))
                + n2 * (hv2.y + FEA(ea2, 1)) + n3 * (hv3.y + FEA(ea3, 1));
            a2 += n0 * (hv0.z + FEA(ea0, 2)) + n1 * (hv1.z + FEA(ea1, 2))
                + n2 * (hv2.z + FEA(ea2, 2)) + n3 * (hv3.z + FEA(ea3, 2));
            a3 += n0 * (hv0.w + FEA(ea0, 3)) + n1 * (hv1.w + FEA(ea1, 3))
                + n2 * (hv2.w + FEA(ea2, 3)) + n3 * (hv3.w + FEA(ea3, 3));
        }
        for (; p < e; ++p) {
            int r = rowArr[p];
            float4 ea = eaP[p];
            float nrm = dn * dinv[r];
            float4 hv = *((const float4*)hin_ + (size_t)r * 64 + lane);
            a0 += nrm * (hv.x + FEA(ea, 0));
            a1 += nrm * (hv.y + FEA(ea, 1));
            a2 += nrm * (hv.z + FEA(ea, 2));
            a3 += nrm * (hv.w + FEA(ea, 3));
        }
    } else {
        for (; p + 4 <= e; p += 4) {
            int r0 = rowArr[p + 0], r1 = rowArr[p + 1], r2 = rowArr[p + 2], r3 = rowArr[p + 3];
            float4 ea0 = eaP[p + 0], ea1 = eaP[p + 1], ea2 = eaP[p + 2], ea3 = eaP[p + 3];
            ushort4 hh0 = *((const ushort4*)hin_ + (size_t)r0 * 64 + lane);
            ushort4 hh1 = *((const ushort4*)hin_ + (size_t)r1 * 64 + lane);
            ushort4 hh2 = *((const ushort4*)hin_ + (size_t)r2 * 64 + lane);
            ushort4 hh3 = *((const ushort4*)hin_ + (size_t)r3 * 64 + lane);
            float n0 = dn * dinv[r0], n1 = dn * dinv[r1], n2 = dn * dinv[r2], n3 = dn * dinv[r3];
            a0 += n0 * (BNX(hh0.x, x) + FEA(ea0, 0)) + n1 * (BNX(hh1.x, x) + FEA(ea1, 0))
                + n2 * (BNX(hh2.x, x) + FEA(ea2, 0)) + n3 * (BNX(hh3.x, x) + FEA(ea3, 0));
            a1 += n0 * (BNX(hh0.y, y) + FEA(ea0, 1)) + n1 * (BNX(hh1.y, y) + FEA(ea1, 1))
                + n2 * (BNX(hh2.y, y) + FEA(ea2, 1)) + n3 * (BNX(hh3.y, y) + FEA(ea3, 1));
            a2 += n0 * (BNX(hh0.z, z) + FEA(ea0, 2)) + n1 * (BNX(hh1.z, z) + FEA(ea1, 2))
                + n2 * (BNX(hh2.z, z) + FEA(ea2, 2)) + n3 * (BNX(hh3.z, z) + FEA(ea3, 2));
            a3 += n0 * (BNX(hh0.w, w) + FEA(ea0, 3)) + n1 * (BNX(hh1.w, w) + FEA(ea1, 3))
                + n2 * (BNX(hh2.w, w) + FEA(ea2, 3)) + n3 * (BNX(hh3.w, w) + FEA(ea3, 3));
        }
        for (; p < e; ++p) {
            int r = rowArr[p];
            float4 ea = eaP[p];
            float nrm = dn * dinv[r];
            ushort4 hh = *((const ushort4*)hin_ + (size_t)r * 64 + lane);
            a0 += nrm * (BNX(hh.x, x) + FEA(ea, 0));
            a1 += nrm * (BNX(hh.y, y) + FEA(ea, 1));
            a2 += nrm * (BNX(hh.z, z) + FEA(ea, 2));
            a3 += nrm * (BNX(hh.w, w) + FEA(ea, 3));
        }
    }

    int bad = 0;
    if (!(a0 == a0)) { a0 = 777.f; bad++; }
    if (!(a1 == a1)) { a1 = 777.f; bad++; }
    if (!(a2 == a2)) { a2 = 777.f; bad++; }
    if (!(a3 == a3)) { a3 = 777.f; bad++; }
    if (bad) atomicAdd(&diag[1], bad);
    ushort4 oh, ol;
    split_bf(a0, oh.x, ol.x);
    split_bf(a1, oh.y, ol.y);
    split_bf(a2, oh.z, ol.z);
    split_bf(a3, oh.w, ol.w);
    *((ushort4*)agg_hi + (size_t)n * 64 + lane) = oh;
    *((ushort4*)agg_lo + (size_t)n * 64 + lane) = ol;
}

// ---------------- per-layer: split-precision MFMA GEMM + bias/ReLU + BN stats ----------------
// y = relu(A·W + bias); A = [h | agg]; acc = Ahi·Whi + Alo·Whi (2-term, R10).
// v11: BK=64 — 8 K-steps instead of 16. Per step: stage 32 KB (two contiguous kb-slices
// of wpH), load 8 A-fragments, 128 MFMA/wave. Halves the per-step fixed cost count
// (barrier pair + vmcnt(0) drain + stage-issue serialization) that the tile sweep
// (128-row=90 / 64-row=113 / 32-row=126) showed dominates. Accumulation order per acc
// element is IDENTICAL to BK=32 -> bit-identical numerics (absmax stays 0.75).
// Structure otherwise = R8 optimum: 128 rows x 256 cols, 391 blocks, row-exclusive
// (in-place y-over-agg safe). BN deferral on h path (kb<4): h = relu(sc*(hi+lo)+sh).
__global__ __launch_bounds__(256, 2) void MPNN_79044578115931_kernel(
        const void* hinA_, const u16* hinA_lo, int hf32,
        const u16* agg_hi, const u16* agg_lo,
        const u16* wpH, const float* bias,
        const float* bnsc, const float* bnsh,
        u16* y_hi, u16* y_lo,
        float* colsum, float* colsumsq, int* diag, int M) {
    __shared__ __align__(16) u16 bstage[16384];   // 32 KB: kfrag0 [0,8192), kfrag1 [8192,16384)
    __shared__ float lsum[256];
    __shared__ float lsq[256];

    int tid = threadIdx.x;
    int lane = tid & 63, wave = tid >> 6;
    int quad = lane >> 4, nl = lane & 15;
    int mBase = blockIdx.x * 128 + wave * 32;
    int rowA0 = mBase + nl;          // row-group 0
    int rowA1 = mBase + 16 + nl;     // row-group 1
    if (rowA0 >= M) rowA0 = M - 1;
    if (rowA1 >= M) rowA1 = M - 1;

    lsum[tid] = 0.f;
    lsq[tid] = 0.f;

    f32x4 acc0[16], acc1[16];
#pragma unroll
    for (int i = 0; i < 16; ++i) {
        acc0[i] = {0.f, 0.f, 0.f, 0.f};
        acc1[i] = {0.f, 0.f, 0.f, 0.f};
    }

    for (int kb = 0; kb < 8; ++kb) {   // BK=64
        __syncthreads();   // previous K-step's LDS reads done before overwrite

        // stage B kb-slice: 2048 frags x 16 B (contiguous 32 KB of wpH)
        const u16* srcH = wpH + (size_t)kb * 16384;
#pragma unroll
        for (int i = 0; i < 8; ++i) {
            int ci = i * 256 + tid;
            gl_lds16(srcH + ci * 8, &bstage[ci * 8]);
        }

        // A fragments for both 32-wide k-slices of this step
        short8 a0h0, a0l0, a1h0, a1l0, a0h1, a0l1, a1h1, a1l1;
        float4 sc0a, sc0b, sh0a, sh0b, sc1a, sc1b, sh1a, sh1b;
        if (kb < 4) {
            int k0 = kb * 64 + quad * 8;
            int k1 = k0 + 32;
            if (hf32) {
                const float* hp0 = (const float*)hinA_ + (size_t)rowA0 * HID;
                const float* hp1 = (const float*)hinA_ + (size_t)rowA1 * HID;
#pragma unroll
                for (int j = 0; j < 8; ++j) {
                    u16 h, l;
                    split_bf(hp0[k0 + j], h, l); a0h0[j] = (short)h; a0l0[j] = (short)l;
                    split_bf(hp1[k0 + j], h, l); a1h0[j] = (short)h; a1l0[j] = (short)l;
                    split_bf(hp0[k1 + j], h, l); a0h1[j] = (short)h; a0l1[j] = (short)l;
                    split_bf(hp1[k1 + j], h, l); a1h1[j] = (short)h; a1l1[j] = (short)l;
                }
            } else {
                a0h0 = *(const short8*)((const u16*)hinA_ + (size_t)rowA0 * HID + k0);
                a0l0 = *(const short8*)(hinA_lo + (size_t)rowA0 * HID + k0);
                a1h0 = *(const short8*)((const u16*)hinA_ + (size_t)rowA1 * HID + k0);
                a1l0 = *(const short8*)(hinA_lo + (size_t)rowA1 * HID + k0);
                a0h1 = *(const short8*)((const u16*)hinA_ + (size_t)rowA0 * HID + k1);
                a0l1 = *(const short8*)(hinA_lo + (size_t)rowA0 * HID + k1);
                a1h1 = *(const short8*)((const u16*)hinA_ + (size_t)rowA1 * HID + k1);
                a1l1 = *(const short8*)(hinA_lo + (size_t)rowA1 * HID + k1);
                int q0 = k0 >> 2, q1 = k1 >> 2;
                sc0a = ((const float4*)bnsc)[q0];
                sc0b = ((const float4*)bnsc)[q0 + 1];
                sh0a = ((const float4*)bnsh)[q0];
                sh0b = ((const float4*)bnsh)[q0 + 1];
                sc1a = ((const float4*)bnsc)[q1];
                sc1b = ((const float4*)bnsc)[q1 + 1];
                sh1a = ((const float4*)bnsh)[q1];
                sh1b = ((const float4*)bnsh)[q1 + 1];
            }
        } else {
            int k0 = (kb - 4) * 64 + quad * 8;
            int k1 = k0 + 32;
            a0h0 = *(const short8*)(agg_hi + (size_t)rowA0 * HID + k0);
            a0l0 = *(const short8*)(agg_lo + (size_t)rowA0 * HID + k0);
            a1h0 = *(const short8*)(agg_hi + (size_t)rowA1 * HID + k0);
            a1l0 = *(const short8*)(agg_lo + (size_t)rowA1 * HID + k0);
            a0h1 = *(const short8*)(agg_hi + (size_t)rowA0 * HID + k1);
            a0l1 = *(const short8*)(agg_lo + (size_t)rowA0 * HID + k1);
            a1h1 = *(const short8*)(agg_hi + (size_t)rowA1 * HID + k1);
            a1l1 = *(const short8*)(agg_lo + (size_t)rowA1 * HID + k1);
        }

        __syncthreads();   // drains vmcnt(0): staged B + A frags + sc/sh ready

        // BN deferral: reconstruct h = relu(sc*(hi+lo)+sh), re-split -> A fragments
        if (!hf32 && kb < 4) {
            {
                float scr[8] = {sc0a.x, sc0a.y, sc0a.z, sc0a.w, sc0b.x, sc0b.y, sc0b.z, sc0b.w};
                float shr[8] = {sh0a.x, sh0a.y, sh0a.z, sh0a.w, sh0b.x, sh0b.y, sh0b.z, sh0b.w};
#pragma unroll
                for (int j = 0; j < 8; ++j) {
                    float f0 = scr[j] * (bf2f((u16)a0h0[j]) + bf2f((u16)a0l0[j])) + shr[j];
                    f0 = f0 > 0.f ? f0 : 0.f;
                    float f1 = scr[j] * (bf2f((u16)a1h0[j]) + bf2f((u16)a1l0[j])) + shr[j];
                    f1 = f1 > 0.f ? f1 : 0.f;
                    u16 h, l;
                    split_bf(f0, h, l);
                    a0h0[j] = (short)h; a0l0[j] = (short)l;
                    split_bf(f1, h, l);
                    a1h0[j] = (short)h; a1l0[j] = (short)l;
                }
            }
            {
                float scr[8] = {sc1a.x, sc1a.y, sc1a.z, sc1a.w, sc1b.x, sc1b.y, sc1b.z, sc1b.w};
                float shr[8] = {sh1a.x, sh1a.y, sh1a.z, sh1a.w, sh1b.x, sh1b.y, sh1b.z, sh1b.w};
#pragma unroll
                for (int j = 0; j < 8; ++j) {
                    float f0 = scr[j] * (bf2f((u16)a0h1[j]) + bf2f((u16)a0l1[j])) + shr[j];
                    f0 = f0 > 0.f ? f0 : 0.f;
                    float f1 = scr[j] * (bf2f((u16)a1h1[j]) + bf2f((u16)a1l1[j])) + shr[j];
                    f1 = f1 > 0.f ? f1 : 0.f;
                    u16 h, l;
                    split_bf(f0, h, l);
                    a0h1[j] = (short)h; a0l1[j] = (short)l;
                    split_bf(f1, h, l);
                    a1h1[j] = (short)h; a1l1[j] = (short)l;
                }
            }
        }

        const short8* bbase = (const short8*)bstage;
#pragma unroll
        for (int nbg = 0; nbg < 16; ++nbg) {
            short8 bh = bbase[nbg * 64 + lane];
            acc0[nbg] = __builtin_amdgcn_mfma_f32_16x16x32_bf16(a0h0, bh, acc0[nbg], 0, 0, 0);
            acc1[nbg] = __builtin_amdgcn_mfma_f32_16x16x32_bf16(a1h0, bh, acc1[nbg], 0, 0, 0);
            acc0[nbg] = __builtin_amdgcn_mfma_f32_16x16x32_bf16(a0l0, bh, acc0[nbg], 0, 0, 0);
            acc1[nbg] = __builtin_amdgcn_mfma_f32_16x16x32_bf16(a1l0, bh, acc1[nbg], 0, 0, 0);
        }
#pragma unroll
        for (int nbg = 0; nbg < 16; ++nbg) {
            short8 bh = bbase[1024 + nbg * 64 + lane];
            acc0[nbg] = __builtin_amdgcn_mfma_f32_16x16x32_bf16(a0h1, bh, acc0[nbg], 0, 0, 0);
            acc1[nbg] = __builtin_amdgcn_mfma_f32_16x16x32_bf16(a1h1, bh, acc1[nbg], 0, 0, 0);
            acc0[nbg] = __builtin_amdgcn_mfma_f32_16x16x32_bf16(a0l1, bh, acc0[nbg], 0, 0, 0);
            acc1[nbg] = __builtin_amdgcn_mfma_f32_16x16x32_bf16(a1l1, bh, acc1[nbg], 0, 0, 0);
        }
    }

    __syncthreads();   // all global agg reads complete -> in-place y write safe

    // epilogue: bias + ReLU + split-store + BN partial stats (pre-split fp32)
    int badY = 0;
#pragma unroll
    for (int nbg = 0; nbg < 16; ++nbg) {
        int c = nbg * 16 + nl;
        float bv = bias[c];
        float s = 0.f, q = 0.f;
#pragma unroll
        for (int r = 0; r < 4; ++r) {
            int m = mBase + quad * 4 + r;
            if (m < M) {
                float v = acc0[nbg][r] + bv;
                if (!(v == v)) { v = 777.f; badY++; }
                v = v > 0.f ? v : 0.f;
                u16 h, l;
                split_bf(v, h, l);
                y_hi[(size_t)m * HID + c] = h;
                y_lo[(size_t)m * HID + c] = l;
                s += v;
                q += v * v;
            }
        }
        atomicAdd(&lsum[c], s);
        atomicAdd(&lsq[c], q);
    }
#pragma unroll
    for (int nbg = 0; nbg < 16; ++nbg) {
        int c = nbg * 16 + nl;
        float bv = bias[c];
        float s = 0.f, q = 0.f;
#pragma unroll
        for (int r = 0; r < 4; ++r) {
            int m = mBase + 16 + quad * 4 + r;
            if (m < M) {
                float v = acc1[nbg][r] + bv;
                if (!(v == v)) { v = 777.f; badY++; }
                v = v > 0.f ? v : 0.f;
                u16 h, l;
                split_bf(v, h, l);
                y_hi[(size_t)m * HID + c] = h;
                y_lo[(size_t)m * HID + c] = l;
                s += v;
                q += v * v;
            }
        }
        atomicAdd(&lsum[c], s);
        atomicAdd(&lsq[c], q);
    }
    if (badY) atomicAdd(&diag[2], badY);
    __syncthreads();
    atomicAdd(&colsum[tid], lsum[tid]);
    atomicAdd(&colsumsq[tid], lsq[tid]);
}

__global__ __launch_bounds__(256) void k_bnscale(const float* colsum, const float* colsumsq,
                                                 const float* g, const float* b,
                                                 float* scale, float* shift, int* diag, int M) {
    int c = threadIdx.x;
    float mu = colsum[c] / (float)M;
    float var = colsumsq[c] / (float)M - mu * mu;
    if (!(mu == mu) || !(var == var) || var > 1e30f) atomicAdd(&diag[3], 1);
    if (var < 0.f) var = 0.f;
    float sc = rsqrtf(var + BN_EPS) * g[c];
    scale[c] = sc;
    shift[c] = b[c] - mu * sc;
}

// BN apply (FINAL layer only under deferral): reads y planes, writes fp32 to outf.
__global__ __launch_bounds__(256) void k_bnapply(const u16* src_hi, const u16* src_lo,
                                                 u16* dst_hi, u16* dst_lo,
                                                 const float* scale, const float* shift,
                                                 float* outf, int finalL, int relu, int total) {
    int q4 = blockIdx.x * 256 + threadIdx.x;
    int idx = q4 * 4;
    if (idx >= total) return;
    int c = idx & (HID - 1);
    ushort4 vh = *((const ushort4*)src_hi + q4);
    ushort4 vl = *((const ushort4*)src_lo + q4);
    float o0 = scale[c + 0] * (bf2f(vh.x) + bf2f(vl.x)) + shift[c + 0];
    float o1 = scale[c + 1] * (bf2f(vh.y) + bf2f(vl.y)) + shift[c + 1];
    float o2 = scale[c + 2] * (bf2f(vh.z) + bf2f(vl.z)) + shift[c + 2];
    float o3 = scale[c + 3] * (bf2f(vh.w) + bf2f(vl.w)) + shift[c + 3];
    if (relu) {
        o0 = o0 > 0.f ? o0 : 0.f;
        o1 = o1 > 0.f ? o1 : 0.f;
        o2 = o2 > 0.f ? o2 : 0.f;
        o3 = o3 > 0.f ? o3 : 0.f;
    }
    if (finalL) {
        float4 ov; ov.x = o0; ov.y = o1; ov.z = o2; ov.w = o3;
        *((float4*)outf + q4) = ov;
    } else {
        ushort4 oh, ol;
        split_bf(o0, oh.x, ol.x);
        split_bf(o1, oh.y, ol.y);
        split_bf(o2, oh.z, ol.z);
        split_bf(o3, oh.w, ol.w);
        *((ushort4*)dst_hi + q4) = oh;
        *((ushort4*)dst_lo + q4) = ol;
    }
}

// d_out[0] = (1+k+8*int64)*2^20 only if a check failed.
__global__ void k_encode(const int* diag, float* out) {
    if (threadIdx.x != 0 || blockIdx.x != 0) return;
    int k = -1;
    for (int i = 0; i < 4; ++i) if (diag[i] != 0) { k = i; break; }
    if (k < 0) return;
    out[0] = (float)(1 + k + (diag[7] != 0 ? 8 : 0)) * 1048576.0f;
}

// ---------------- launcher (zero workspace dependency) ----------------

extern "C" void kernel_launch(void* const* d_in, const int* in_sizes, int n_in,
                              void* d_out, int out_size, void* d_ws, size_t ws_size,
                              hipStream_t stream) {
    const float*  x     = (const float*)d_in[0];
    const int*    ei    = (const int*)d_in[1];
    const float4* eattr = (const float4*)d_in[2];
    const float*  mlp_w = (const float*)d_in[3];
    const float*  mlp_b = (const float*)d_in[4];
    const float*  ew1   = (const float*)d_in[5];
    const float*  ew2   = (const float*)d_in[6];
    const float*  bn_g  = (const float*)d_in[7];
    const float*  bn_b  = (const float*)d_in[8];
    (void)n_in; (void)out_size; (void)d_ws; (void)ws_size;

    const int N = in_sizes[0] / HID;   // 50000
    const int E = in_sizes[1] / 2;     // 320000
    const size_t P = (size_t)N * HID;  // plane elements

    // ---- CSR staging inside d_out (dead before layer 0 writes d_out) ----
    char* st = (char*)d_out;
    int*    S_deg    = (int*)   (st + 0);
    float*  S_dinv   = (float*) (st + 204800);
    int*    S_offs   = (int*)   (st + 409600);
    int*    S_cursor = (int*)   (st + 614400);
    int*    S_bsum   = (int*)   (st + 819200);
    int*    S_bscan  = (int*)   (st + 820224);
    int*    S_gflag  = (int*)   (st + 821248);
    int*    S_row    = (int*)   (st + 1048576);
    float4* S_ea     = (float4*)(st + 2621440);   // ends 7,741,440 < 51.2 MB

    // ---- small homes in edge_index buffer (>=2.56 MB); eattr buffer holds eaP ----
    char* eb = (char*)d_in[1];
    int*   rowArr = (int*)  (eb + 0);          // 1,280,000
    float* dinvF  = (float*)(eb + 1280000);    // 200,000
    int*   offsF  = (int*)  (eb + 1480000);    // 200,004
    float* colsum = (float*)(eb + 1680128);
    float* colsq  = (float*)(eb + 1681152);
    float* scaleF = (float*)(eb + 1682176);
    float* shiftF = (float*)(eb + 1683200);
    int*   diag   = (int*)  (eb + 1684224);    // 1 KB
    u16*   wpH    = (u16*)  (eb + 1685504);    // 256 KB -> ends 1,947,648 <= 2,560,000
    float4* eaP   = (float4*)d_in[2];          // 5,120,000 exact

    // ---- h slots as bf16 hi/lo planes (each slot = 2 planes = 51.2 MB) ----
    u16* sX_hi = (u16*)d_in[0];          // x buffer (x consumed during layer 0)
    u16* sX_lo = sX_hi + P;
    u16* sD_hi = (u16*)d_out;
    u16* sD_lo = sD_hi + P;

    int NB  = (N + 255) / 256;
    int NBE = (E + 255) / 256;
    int NBG = (N + 127) / 128;    // 391 GEMM blocks (128 rows each)
    int NBA = (N + 3) / 4;        // 12500 agg blocks (one wave per node)
    int NBQ = (int)((P / 4 + 255) / 256);

    // ---- preprocessing ----
    k_detect<<<1, 256, 0, stream>>>(ei, S_gflag, E);
    k_zero32<<<NB, 256, 0, stream>>>((unsigned int*)S_deg, N);
    k_deg<<<NBE, 256, 0, stream>>>(ei, S_gflag, S_deg, E, N);
    k_dinv<<<NB, 256, 0, stream>>>(S_deg, S_dinv, N);
    k_scan1<<<NB, 256, 0, stream>>>(S_deg, S_offs, S_bsum, N);
    k_scan2<<<1, 256, 0, stream>>>(S_bsum, S_bscan, NB);
    k_scan3<<<NB, 256, 0, stream>>>(S_offs, S_bscan, S_cursor, N, E);
    k_place<<<NBE, 256, 0, stream>>>(ei, S_gflag, eattr, S_cursor, S_row, S_ea, E, N);
    k_move<<<NBE, 256, 0, stream>>>(S_row, S_ea, S_dinv, S_offs, rowArr, eaP, dinvF, offsF, E, N);
    k_zero32<<<1, 256, 0, stream>>>((unsigned int*)diag, 256);
    k_precheckN<<<NB, 256, 0, stream>>>(offsF, S_cursor, dinvF, S_gflag, diag, N, E);
    k_precheckE<<<NBE, 256, 0, stream>>>(rowArr, diag, E, N);

    // ---- layers: even l -> dst = D(d_out), odd l -> dst = X; agg planes live in dst.
    //      BN deferral: planes hold PRE-BN y; consumers apply scale/shift. v11: the
    //      previous layer's bnscale is folded into this layer's k_wsplit (block 0). ----
    for (int l = 0; l < NLAYERS; ++l) {
        int even = (l % 2 == 0);
        u16* dst_hi = even ? sD_hi : sX_hi;
        u16* dst_lo = even ? sD_lo : sX_lo;
        const void* hinA; const u16* hin_lo; int hf32;
        if (l == 0) { hinA = (const void*)x; hin_lo = 0; hf32 = 1; }
        else if (even) { hinA = (const void*)sX_hi; hin_lo = sX_lo; hf32 = 0; }
        else { hinA = (const void*)sD_hi; hin_lo = sD_lo; hf32 = 0; }

        const float* gPrev = bn_g + (size_t)(l > 0 ? l - 1 : 0) * HID;
        const float* bPrev = bn_b + (size_t)(l > 0 ? l - 1 : 0) * HID;
        k_wsplit<<<64, 256, 0, stream>>>(mlp_w + (size_t)l * 512 * HID, wpH, colsum,
                                         gPrev, bPrev, scaleF, shiftF, diag, N, l > 0 ? 1 : 0);
        k_agg<<<NBA, 256, 0, stream>>>(hinA, hin_lo, hf32, offsF, rowArr, eaP, dinvF,
                                       ew1 + (size_t)l * 128, ew2 + (size_t)l * 384,
                                       scaleF, shiftF,
                                       dst_hi, dst_lo, diag, N);
        MPNN_79044578115931_kernel<<<NBG, 256, 0, stream>>>(
            hinA, hin_lo, hf32, dst_hi, dst_lo, wpH,
            mlp_b + (size_t)l * HID, scaleF, shiftF,
            dst_hi, dst_lo, colsum, colsq, diag, N);
        if (l == NLAYERS - 1) {
            k_bnscale<<<1, 256, 0, stream>>>(colsum, colsq,
                                             bn_g + (size_t)l * HID, bn_b + (size_t)l * HID,
                                             scaleF, shiftF, diag, N);
            // final: BN (no relu) -> fp32 into X buffer, then copy back to d_out
            k_bnapply<<<NBQ, 256, 0, stream>>>(dst_hi, dst_lo, dst_hi, dst_lo, scaleF, shiftF,
                                               (float*)d_in[0], 1, 0, (int)P);
        }
    }

    hipMemcpyAsync(d_out, d_in[0], P * 4, hipMemcpyDeviceToDevice, stream);
    k_encode<<<1, 64, 0, stream>>>(diag, (float*)d_out);
}

// Round 13
// 832.302 us; speedup vs baseline: 2.6136x; 1.0233x over previous
//
#include <hip/hip_runtime.h>
#include <stdint.h>

typedef short short8 __attribute__((ext_vector_type(8)));
typedef float f32x4 __attribute__((ext_vector_type(4)));
typedef unsigned short u16;

#define HID 256
#define NLAYERS 5
#define BN_EPS 1e-5f

__device__ __forceinline__ float bf2f(u16 u) {
    union { unsigned int i; float f; } v;
    v.i = ((unsigned int)u) << 16;
    return v.f;
}
__device__ __forceinline__ u16 f2bf(float f) {
    union { float f; unsigned int i; } v;
    v.f = f;
    unsigned int r = v.i + 0x7FFFu + ((v.i >> 16) & 1u);   // RNE
    return (u16)(r >> 16);
}
// split fp32 -> (hi, lo) bf16 pair: hi+lo ~ 17-bit mantissa approximation
__device__ __forceinline__ void split_bf(float f, u16& hi, u16& lo) {
    hi = f2bf(f);
    lo = f2bf(f - bf2f(hi));
}

// 16-B direct global->LDS copy (vmcnt-tracked; drained by __syncthreads).
__device__ __forceinline__ void gl_lds16(const void* gsrc, void* ldst) {
    const __attribute__((address_space(1))) unsigned int* g =
        reinterpret_cast<const __attribute__((address_space(1))) unsigned int*>(
            reinterpret_cast<uintptr_t>(gsrc));
    __attribute__((address_space(3))) unsigned int* l =
        reinterpret_cast<__attribute__((address_space(3))) unsigned int*>(
            reinterpret_cast<uintptr_t>(ldst));
    __builtin_amdgcn_global_load_lds(g, l, 16, 0, 0);
}

// ---------------- graph preprocessing (staged in d_out; fused v13) ----------------

// zero deg (all blocks) + int64-layout detect (block 0)
__global__ __launch_bounds__(256) void k_zdet(const int* ei, int* flag, unsigned int* deg,
                                              int E, int N) {
    int i = blockIdx.x * 256 + threadIdx.x;
    if (i < N) deg[i] = 0u;
    if (blockIdx.x == 0) {
        __shared__ int nz;
        if (threadIdx.x == 0) nz = 0;
        __syncthreads();
        int lim = (2 * E < 4096) ? 2 * E : 4096;
        int c = 0;
        for (int k = threadIdx.x; 2 * k + 1 < lim; k += 256) c += (ei[2 * k + 1] != 0);
        atomicAdd(&nz, c);
        __syncthreads();
        if (threadIdx.x == 0) flag[0] = (nz == 0) ? 1 : 0;   // 1 => int64 layout
    }
}

__global__ __launch_bounds__(256) void k_deg(const int* ei, const int* flag, int* deg, int E, int N) {
    int e = blockIdx.x * 256 + threadIdx.x;
    if (e >= E) return;
    int w = flag[0];
    int col = w ? ei[2 * (E + e)] : ei[E + e];
    if ((unsigned)col < (unsigned)N) atomicAdd(&deg[col], 1);
}

// block-local inclusive scan of deg + dinv compute (fused)
__global__ __launch_bounds__(256) void k_scan1d(const int* deg, int* offs, int* bsum,
                                                float* dinv, int N) {
    __shared__ int s[256];
    int tid = threadIdx.x;
    int i = blockIdx.x * 256 + tid;
    int v = (i < N) ? deg[i] : 0;
    if (i < N) dinv[i] = v > 0 ? rsqrtf((float)v) : 0.0f;
    s[tid] = v;
    __syncthreads();
    for (int off = 1; off < 256; off <<= 1) {
        int t = (tid >= off) ? s[tid - off] : 0;
        __syncthreads();
        s[tid] += t;
        __syncthreads();
    }
    if (i < N) offs[i] = s[tid] - v;
    if (tid == 255) bsum[blockIdx.x] = s[tid];
}

// scan of block sums (diag zeroing moved to k_move — R12 bug: zeroing diag here
// corrupted live int32 edge targets, since diag aliases the ei buffer region that
// k_place still reads; eb small-homes are only safe to touch AFTER k_place).
__global__ __launch_bounds__(256) void k_scan2(const int* bsum, int* bscan, int NB) {
    __shared__ int s[256];
    int tid = threadIdx.x;
    int v = (tid < NB) ? bsum[tid] : 0;
    s[tid] = v;
    __syncthreads();
    for (int off = 1; off < 256; off <<= 1) {
        int t = (tid >= off) ? s[tid - off] : 0;
        __syncthreads();
        s[tid] += t;
        __syncthreads();
    }
    bscan[tid] = s[tid] - v;
}

__global__ __launch_bounds__(256) void k_scan3(int* offs, const int* bscan, int* cursor, int N, int E) {
    int i = blockIdx.x * 256 + threadIdx.x;
    if (i < N) {
        int o = offs[i] + bscan[blockIdx.x];
        offs[i] = o;
        cursor[i] = o;
    }
    if (i == 0) offs[N] = E;
}

__global__ __launch_bounds__(256) void k_place(const int* ei, const int* flag, const float4* eattr,
                                               int* cursor, int* srow, float4* sea, int E, int N) {
    int e = blockIdx.x * 256 + threadIdx.x;
    if (e >= E) return;
    int w = flag[0];
    int r = w ? ei[2 * e] : ei[e];
    int c = w ? ei[2 * (E + e)] : ei[E + e];
    if ((unsigned)c >= (unsigned)N) return;
    int p = atomicAdd(&cursor[c], 1);
    srow[p] = r;
    sea[p] = eattr[e];
}

// k_move: ei fully consumed by k_place -> safe to overwrite eb small-homes.
// Also zeroes diag (i<256) — must precede k_precheck, done here to save a dispatch.
__global__ __launch_bounds__(256) void k_move(const int* srow, const float4* sea, const float* sdinv,
                                              const int* soffs, int* rowArr, float4* eaP,
                                              float* dinvF, int* offsF, int* diag, int E, int N) {
    int i = blockIdx.x * 256 + threadIdx.x;
    if (i < E) { rowArr[i] = srow[i]; eaP[i] = sea[i]; }
    if (i < N) dinvF[i] = sdinv[i];
    if (i <= N) offsF[i] = soffs[i];
    if (i < 256) diag[i] = 0;
}

// precheckN + precheckE fused (grid covers E >= N)
__global__ __launch_bounds__(256) void k_precheck(const int* offsF, const int* cursor,
                                                  const float* dinvF, const int* gflag,
                                                  const int* rowArr, int* diag, int N, int E) {
    int i = blockIdx.x * 256 + threadIdx.x;
    if (i < N) {
        if (offsF[i + 1] < offsF[i]) atomicOr(&diag[0], 1);
        if (cursor[i] != offsF[i + 1]) atomicOr(&diag[0], 2);
        float d = dinvF[i];
        if (!(d == d) || fabsf(d) > 1e10f) atomicOr(&diag[0], 4);
    }
    if (i == 0) {
        if (offsF[N] != E) atomicOr(&diag[0], 8);
        diag[7] = gflag[0];
    }
    if (i < E && (unsigned)rowArr[i] >= (unsigned)N) atomicOr(&diag[0], 16);
}

// Per-layer: round W (fp32 512x256 row-major) to bf16 in MFMA B-fragment order,
// kb-major: frag t = kb*1024 + nbg*64 + lane holds
// W[kb*32 + (lane>>4)*8 + j][nbg*16 + (lane&15)], j=0..7.  (hi plane only — R10.)
// Block 0 ALSO performs the previous layer's bnscale before zeroing the stats (R11).
__global__ __launch_bounds__(256) void k_wsplit(const float* W, u16* wpH, float* colsum,
                                                const float* g, const float* b,
                                                float* scale, float* shift, int* diag,
                                                int M, int doBN) {
    if (blockIdx.x == 0) {
        int c = threadIdx.x;
        if (doBN) {
            float mu = colsum[c] / (float)M;
            float var = colsum[256 + c] / (float)M - mu * mu;
            if (!(mu == mu) || !(var == var) || var > 1e30f) atomicAdd(&diag[3], 1);
            if (var < 0.f) var = 0.f;
            float sc = rsqrtf(var + BN_EPS) * g[c];
            scale[c] = sc;
            shift[c] = b[c] - mu * sc;
        }
        colsum[c] = 0.f;
        colsum[256 + c] = 0.f;
    }
    int t = blockIdx.x * 256 + threadIdx.x;   // 64 blocks -> 16384 frags
    int lane = t & 63;
    int nbg = (t >> 6) & 15;
    int kb = t >> 10;
    int quad = lane >> 4, nl = lane & 15;
    const float* src = W + (size_t)(kb * 32 + quad * 8) * HID + nbg * 16 + nl;
    short8 vh;
#pragma unroll
    for (int j = 0; j < 8; ++j) vh[j] = (short)f2bf(src[(size_t)j * HID]);
    *((short8*)wpH + t) = vh;
}

// ---------------- per-layer: aggregation (one wave per node), split output ----------------
// BN deferral: for l>=1 the hin plane holds y = relu(A·W+b) PRE-BN; this kernel
// applies h = relu(scale*y + shift) on the fly per gathered element (BW-bound -> free).
// Gathers ONLY the hi plane (R8 bandwidth win).
#define FEA(ea, j) ((ea).w * w1v[j] + (ea).x * w20[j] + (ea).y * w21[j] + (ea).z * w22[j])
#define BNX(u, comp) (fmaxf(sc4.comp * bf2f(u) + sh4.comp, 0.f))

__global__ __launch_bounds__(256) void k_agg(const void* hin_, const u16* hin_lo, int hf32,
                                             const int* offs, const int* rowArr, const float4* eaP,
                                             const float* dinv, const float* ew1, const float* ew2,
                                             const float* bnsc, const float* bnsh,
                                             u16* agg_hi, u16* agg_lo, int* diag, int M) {
    (void)hin_lo;
    int lane = threadIdx.x & 63, wave = threadIdx.x >> 6;
    int n = blockIdx.x * 4 + wave;

    float w1v[4] = {0.f, 0.f, 0.f, 0.f};
    float w20[4] = {0.f, 0.f, 0.f, 0.f};
    float w21[4] = {0.f, 0.f, 0.f, 0.f};
    float w22[4] = {0.f, 0.f, 0.f, 0.f};
    if (lane < 32) {
        int c = lane * 4;
#pragma unroll
        for (int j = 0; j < 4; ++j) w1v[j] = ew1[c + j];
    } else {
        int cc = (lane - 32) * 4;
#pragma unroll
        for (int j = 0; j < 4; ++j) {
            w20[j] = ew2[cc + j];
            w21[j] = ew2[128 + cc + j];
            w22[j] = ew2[256 + cc + j];
        }
    }

    float4 sc4 = {0.f, 0.f, 0.f, 0.f}, sh4 = {0.f, 0.f, 0.f, 0.f};
    if (!hf32) {
        sc4 = ((const float4*)bnsc)[lane];
        sh4 = ((const float4*)bnsh)[lane];
    }

    if (n >= M) return;
    float dn = dinv[n];
    int s = offs[n], e = offs[n + 1];
    float a0 = 0.f, a1 = 0.f, a2 = 0.f, a3 = 0.f;
    int p = s;

    if (hf32) {
        for (; p + 4 <= e; p += 4) {
            int r0 = rowArr[p + 0], r1 = rowArr[p + 1], r2 = rowArr[p + 2], r3 = rowArr[p + 3];
            float4 ea0 = eaP[p + 0], ea1 = eaP[p + 1], ea2 = eaP[p + 2], ea3 = eaP[p + 3];
            float4 hv0 = *((const float4*)hin_ + (size_t)r0 * 64 + lane);
            float4 hv1 = *((const float4*)hin_ + (size_t)r1 * 64 + lane);
            float4 hv2 = *((const float4*)hin_ + (size_t)r2 * 64 + lane);
            float4 hv3 = *((const float4*)hin_ + (size_t)r3 * 64 + lane);
            float n0 = dn * dinv[r0], n1 = dn * dinv[r1], n2 = dn * dinv[r2], n3 = dn * dinv[r3];
            a0 += n0 * (hv0.x + FEA(ea0, 0)) + n1 * (hv1.x + FEA(ea1, 0))
                + n2 * (hv2.x + FEA(ea2, 0)) + n3 * (hv3.x + FEA(ea3, 0));
            a1 += n0 * (hv0.y + FEA(ea0, 1)) + n1 * (hv1.y + FEA(ea1, 1))
                + n2 * (hv2.y + FEA(ea2, 1)) + n3 * (hv3.y + FEA(ea3, 1));
            a2 += n0 * (hv0.z + FEA(ea0, 2)) + n1 * (hv1.z + FEA(ea1, 2))
                + n2 * (hv2.z + FEA(ea2, 2)) + n3 * (hv3.z + FEA(ea3, 2));
            a3 += n0 * (hv0.w + FEA(ea0, 3)) + n1 * (hv1.w + FEA(ea1, 3))
                + n2 * (hv2.w + FEA(ea2, 3)) + n3 * (hv3.w + FEA(ea3, 3));
        }
        for (; p < e; ++p) {
            int r = rowArr[p];
            float4 ea = eaP[p];
            float nrm = dn * dinv[r];
            float4 hv = *((const float4*)hin_ + (size_t)r * 64 + lane);
            a0 += nrm * (hv.x + FEA(ea, 0));
            a1 += nrm * (hv.y + FEA(ea, 1));
            a2 += nrm * (hv.z + FEA(ea, 2));
            a3 += nrm * (hv.w + FEA(ea, 3));
        }
    } else {
        for (; p + 4 <= e; p += 4) {
            int r0 = rowArr[p + 0], r1 = rowArr[p + 1], r2 = rowArr[p + 2], r3 = rowArr[p + 3];
            float4 ea0 = eaP[p + 0], ea1 = eaP[p + 1], ea2 = eaP[p + 2], ea3 = eaP[p + 3];
            ushort4 hh0 = *((const ushort4*)hin_ + (size_t)r0 * 64 + lane);
            ushort4 hh1 = *((const ushort4*)hin_ + (size_t)r1 * 64 + lane);
            ushort4 hh2 = *((const ushort4*)hin_ + (size_t)r2 * 64 + lane);
            ushort4 hh3 = *((const ushort4*)hin_ + (size_t)r3 * 64 + lane);
            float n0 = dn * dinv[r0], n1 = dn * dinv[r1], n2 = dn * dinv[r2], n3 = dn * dinv[r3];
            a0 += n0 * (BNX(hh0.x, x) + FEA(ea0, 0)) + n1 * (BNX(hh1.x, x) + FEA(ea1, 0))
                + n2 * (BNX(hh2.x, x) + FEA(ea2, 0)) + n3 * (BNX(hh3.x, x) + FEA(ea3, 0));
            a1 += n0 * (BNX(hh0.y, y) + FEA(ea0, 1)) + n1 * (BNX(hh1.y, y) + FEA(ea1, 1))
                + n2 * (BNX(hh2.y, y) + FEA(ea2, 1)) + n3 * (BNX(hh3.y, y) + FEA(ea3, 1));
            a2 += n0 * (BNX(hh0.z, z) + FEA(ea0, 2)) + n1 * (BNX(hh1.z, z) + FEA(ea1, 2))
                + n2 * (BNX(hh2.z, z) + FEA(ea2, 2)) + n3 * (BNX(hh3.z, z) + FEA(ea3, 2));
            a3 += n0 * (BNX(hh0.w, w) + FEA(ea0, 3)) + n1 * (BNX(hh1.w, w) + FEA(ea1, 3))
                + n2 * (BNX(hh2.w, w) + FEA(ea2, 3)) + n3 * (BNX(hh3.w, w) + FEA(ea3, 3));
        }
        for (; p < e; ++p) {
            int r = rowArr[p];
            float4 ea = eaP[p];
            float nrm = dn * dinv[r];
            ushort4 hh = *((const ushort4*)hin_ + (size_t)r * 64 + lane);
            a0 += nrm * (BNX(hh.x, x) + FEA(ea, 0));
            a1 += nrm * (BNX(hh.y, y) + FEA(ea, 1));
            a2 += nrm * (BNX(hh.z, z) + FEA(ea, 2));
            a3 += nrm * (BNX(hh.w, w) + FEA(ea, 3));
        }
    }

    int bad = 0;
    if (!(a0 == a0)) { a0 = 777.f; bad++; }
    if (!(a1 == a1)) { a1 = 777.f; bad++; }
    if (!(a2 == a2)) { a2 = 777.f; bad++; }
    if (!(a3 == a3)) { a3 = 777.f; bad++; }
    if (bad) atomicAdd(&diag[1], bad);
    ushort4 oh, ol;
    split_bf(a0, oh.x, ol.x);
    split_bf(a1, oh.y, ol.y);
    split_bf(a2, oh.z, ol.z);
    split_bf(a3, oh.w, ol.w);
    *((ushort4*)agg_hi + (size_t)n * 64 + lane) = oh;
    *((ushort4*)agg_lo + (size_t)n * 64 + lane) = ol;
}

// ---------------- per-layer: split-precision MFMA GEMM + bias/ReLU + BN stats ----------------
// y = relu(A·W + bias); A = [h | agg]; acc = Ahi·Whi + Alo·Whi (2-term, R10).
// BK=64 (R11), 128 rows x 256 cols, 391 blocks, row-exclusive: a block reads only its
// own rows of hinA/agg during the K-loop and writes y to the same rows only after the
// final drain barrier -> y may alias hinA (final layer, in-place over X) or agg planes.
// BN deferral on h path (kb<4): h = relu(sc*(hi+lo)+sh) reconstructed post-drain.
__global__ __launch_bounds__(256, 2) void MPNN_79044578115931_kernel(
        const void* hinA_, const u16* hinA_lo, int hf32,
        const u16* agg_hi, const u16* agg_lo,
        const u16* wpH, const float* bias,
        const float* bnsc, const float* bnsh,
        u16* y_hi, u16* y_lo,
        float* colsum, float* colsumsq, int* diag, int M) {
    __shared__ __align__(16) u16 bstage[16384];   // 32 KB: kfrag0 [0,8192), kfrag1 [8192,16384)
    __shared__ float lsum[256];
    __shared__ float lsq[256];

    int tid = threadIdx.x;
    int lane = tid & 63, wave = tid >> 6;
    int quad = lane >> 4, nl = lane & 15;
    int mBase = blockIdx.x * 128 + wave * 32;
    int rowA0 = mBase + nl;          // row-group 0
    int rowA1 = mBase + 16 + nl;     // row-group 1
    if (rowA0 >= M) rowA0 = M - 1;
    if (rowA1 >= M) rowA1 = M - 1;

    lsum[tid] = 0.f;
    lsq[tid] = 0.f;

    f32x4 acc0[16], acc1[16];
#pragma unroll
    for (int i = 0; i < 16; ++i) {
        acc0[i] = {0.f, 0.f, 0.f, 0.f};
        acc1[i] = {0.f, 0.f, 0.f, 0.f};
    }

    for (int kb = 0; kb < 8; ++kb) {   // BK=64
        __syncthreads();   // previous K-step's LDS reads done before overwrite

        // stage B kb-slice: 2048 frags x 16 B (contiguous 32 KB of wpH)
        const u16* srcH = wpH + (size_t)kb * 16384;
#pragma unroll
        for (int i = 0; i < 8; ++i) {
            int ci = i * 256 + tid;
            gl_lds16(srcH + ci * 8, &bstage[ci * 8]);
        }

        // A fragments for both 32-wide k-slices of this step
        short8 a0h0, a0l0, a1h0, a1l0, a0h1, a0l1, a1h1, a1l1;
        float4 sc0a, sc0b, sh0a, sh0b, sc1a, sc1b, sh1a, sh1b;
        if (kb < 4) {
            int k0 = kb * 64 + quad * 8;
            int k1 = k0 + 32;
            if (hf32) {
                const float* hp0 = (const float*)hinA_ + (size_t)rowA0 * HID;
                const float* hp1 = (const float*)hinA_ + (size_t)rowA1 * HID;
#pragma unroll
                for (int j = 0; j < 8; ++j) {
                    u16 h, l;
                    split_bf(hp0[k0 + j], h, l); a0h0[j] = (short)h; a0l0[j] = (short)l;
                    split_bf(hp1[k0 + j], h, l); a1h0[j] = (short)h; a1l0[j] = (short)l;
                    split_bf(hp0[k1 + j], h, l); a0h1[j] = (short)h; a0l1[j] = (short)l;
                    split_bf(hp1[k1 + j], h, l); a1h1[j] = (short)h; a1l1[j] = (short)l;
                }
            } else {
                a0h0 = *(const short8*)((const u16*)hinA_ + (size_t)rowA0 * HID + k0);
                a0l0 = *(const short8*)(hinA_lo + (size_t)rowA0 * HID + k0);
                a1h0 = *(const short8*)((const u16*)hinA_ + (size_t)rowA1 * HID + k0);
                a1l0 = *(const short8*)(hinA_lo + (size_t)rowA1 * HID + k0);
                a0h1 = *(const short8*)((const u16*)hinA_ + (size_t)rowA0 * HID + k1);
                a0l1 = *(const short8*)(hinA_lo + (size_t)rowA0 * HID + k1);
                a1h1 = *(const short8*)((const u16*)hinA_ + (size_t)rowA1 * HID + k1);
                a1l1 = *(const short8*)(hinA_lo + (size_t)rowA1 * HID + k1);
                int q0 = k0 >> 2, q1 = k1 >> 2;
                sc0a = ((const float4*)bnsc)[q0];
                sc0b = ((const float4*)bnsc)[q0 + 1];
                sh0a = ((const float4*)bnsh)[q0];
                sh0b = ((const float4*)bnsh)[q0 + 1];
                sc1a = ((const float4*)bnsc)[q1];
                sc1b = ((const float4*)bnsc)[q1 + 1];
                sh1a = ((const float4*)bnsh)[q1];
                sh1b = ((const float4*)bnsh)[q1 + 1];
            }
        } else {
            int k0 = (kb - 4) * 64 + quad * 8;
            int k1 = k0 + 32;
            a0h0 = *(const short8*)(agg_hi + (size_t)rowA0 * HID + k0);
            a0l0 = *(const short8*)(agg_lo + (size_t)rowA0 * HID + k0);
            a1h0 = *(const short8*)(agg_hi + (size_t)rowA1 * HID + k0);
            a1l0 = *(const short8*)(agg_lo + (size_t)rowA1 * HID + k0);
            a0h1 = *(const short8*)(agg_hi + (size_t)rowA0 * HID + k1);
            a0l1 = *(const short8*)(agg_lo + (size_t)rowA0 * HID + k1);
            a1h1 = *(const short8*)(agg_hi + (size_t)rowA1 * HID + k1);
            a1l1 = *(const short8*)(agg_lo + (size_t)rowA1 * HID + k1);
        }

        __syncthreads();   // drains vmcnt(0): staged B + A frags + sc/sh ready

        // BN deferral: reconstruct h = relu(sc*(hi+lo)+sh), re-split -> A fragments
        if (!hf32 && kb < 4) {
            {
                float scr[8] = {sc0a.x, sc0a.y, sc0a.z, sc0a.w, sc0b.x, sc0b.y, sc0b.z, sc0b.w};
                float shr[8] = {sh0a.x, sh0a.y, sh0a.z, sh0a.w, sh0b.x, sh0b.y, sh0b.z, sh0b.w};
#pragma unroll
                for (int j = 0; j < 8; ++j) {
                    float f0 = scr[j] * (bf2f((u16)a0h0[j]) + bf2f((u16)a0l0[j])) + shr[j];
                    f0 = f0 > 0.f ? f0 : 0.f;
                    float f1 = scr[j] * (bf2f((u16)a1h0[j]) + bf2f((u16)a1l0[j])) + shr[j];
                    f1 = f1 > 0.f ? f1 : 0.f;
                    u16 h, l;
                    split_bf(f0, h, l);
                    a0h0[j] = (short)h; a0l0[j] = (short)l;
                    split_bf(f1, h, l);
                    a1h0[j] = (short)h; a1l0[j] = (short)l;
                }
            }
            {
                float scr[8] = {sc1a.x, sc1a.y, sc1a.z, sc1a.w, sc1b.x, sc1b.y, sc1b.z, sc1b.w};
                float shr[8] = {sh1a.x, sh1a.y, sh1a.z, sh1a.w, sh1b.x, sh1b.y, sh1b.z, sh1b.w};
#pragma unroll
                for (int j = 0; j < 8; ++j) {
                    float f0 = scr[j] * (bf2f((u16)a0h1[j]) + bf2f((u16)a0l1[j])) + shr[j];
                    f0 = f0 > 0.f ? f0 : 0.f;
                    float f1 = scr[j] * (bf2f((u16)a1h1[j]) + bf2f((u16)a1l1[j])) + shr[j];
                    f1 = f1 > 0.f ? f1 : 0.f;
                    u16 h, l;
                    split_bf(f0, h, l);
                    a0h1[j] = (short)h; a0l1[j] = (short)l;
                    split_bf(f1, h, l);
                    a1h1[j] = (short)h; a1l1[j] = (short)l;
                }
            }
        }

        const short8* bbase = (const short8*)bstage;
#pragma unroll
        for (int nbg = 0; nbg < 16; ++nbg) {
            short8 bh = bbase[nbg * 64 + lane];
            acc0[nbg] = __builtin_amdgcn_mfma_f32_16x16x32_bf16(a0h0, bh, acc0[nbg], 0, 0, 0);
            acc1[nbg] = __builtin_amdgcn_mfma_f32_16x16x32_bf16(a1h0, bh, acc1[nbg], 0, 0, 0);
            acc0[nbg] = __builtin_amdgcn_mfma_f32_16x16x32_bf16(a0l0, bh, acc0[nbg], 0, 0, 0);
            acc1[nbg] = __builtin_amdgcn_mfma_f32_16x16x32_bf16(a1l0, bh, acc1[nbg], 0, 0, 0);
        }
#pragma unroll
        for (int nbg = 0; nbg < 16; ++nbg) {
            short8 bh = bbase[1024 + nbg * 64 + lane];
            acc0[nbg] = __builtin_amdgcn_mfma_f32_16x16x32_bf16(a0h1, bh, acc0[nbg], 0, 0, 0);
            acc1[nbg] = __builtin_amdgcn_mfma_f32_16x16x32_bf16(a1h1, bh, acc1[nbg], 0, 0, 0);
            acc0[nbg] = __builtin_amdgcn_mfma_f32_16x16x32_bf16(a0l1, bh, acc0[nbg], 0, 0, 0);
            acc1[nbg] = __builtin_amdgcn_mfma_f32_16x16x32_bf16(a1l1, bh, acc1[nbg], 0, 0, 0);
        }
    }

    __syncthreads();   // all global A reads complete -> in-place y write safe

    // epilogue: bias + ReLU + split-store + BN partial stats (pre-split fp32)
    int badY = 0;
#pragma unroll
    for (int nbg = 0; nbg < 16; ++nbg) {
        int c = nbg * 16 + nl;
        float bv = bias[c];
        float s = 0.f, q = 0.f;
#pragma unroll
        for (int r = 0; r < 4; ++r) {
            int m = mBase + quad * 4 + r;
            if (m < M) {
                float v = acc0[nbg][r] + bv;
                if (!(v == v)) { v = 777.f; badY++; }
                v = v > 0.f ? v : 0.f;
                u16 h, l;
                split_bf(v, h, l);
                y_hi[(size_t)m * HID + c] = h;
                y_lo[(size_t)m * HID + c] = l;
                s += v;
                q += v * v;
            }
        }
        atomicAdd(&lsum[c], s);
        atomicAdd(&lsq[c], q);
    }
#pragma unroll
    for (int nbg = 0; nbg < 16; ++nbg) {
        int c = nbg * 16 + nl;
        float bv = bias[c];
        float s = 0.f, q = 0.f;
#pragma unroll
        for (int r = 0; r < 4; ++r) {
            int m = mBase + 16 + quad * 4 + r;
            if (m < M) {
                float v = acc1[nbg][r] + bv;
                if (!(v == v)) { v = 777.f; badY++; }
                v = v > 0.f ? v : 0.f;
                u16 h, l;
                split_bf(v, h, l);
                y_hi[(size_t)m * HID + c] = h;
                y_lo[(size_t)m * HID + c] = l;
                s += v;
                q += v * v;
            }
        }
        atomicAdd(&lsum[c], s);
        atomicAdd(&lsq[c], q);
    }
    if (badY) atomicAdd(&diag[2], badY);
    __syncthreads();
    atomicAdd(&colsum[tid], lsum[tid]);
    atomicAdd(&colsumsq[tid], lsq[tid]);
}

__global__ __launch_bounds__(256) void k_bnscale(const float* colsum, const float* colsumsq,
                                                 const float* g, const float* b,
                                                 float* scale, float* shift, int* diag, int M) {
    int c = threadIdx.x;
    float mu = colsum[c] / (float)M;
    float var = colsumsq[c] / (float)M - mu * mu;
    if (!(mu == mu) || !(var == var) || var > 1e30f) atomicAdd(&diag[3], 1);
    if (var < 0.f) var = 0.f;
    float sc = rsqrtf(var + BN_EPS) * g[c];
    scale[c] = sc;
    shift[c] = b[c] - mu * sc;
}

// BN apply (FINAL layer only): reads y planes (X), writes fp32 DIRECTLY to d_out.
__global__ __launch_bounds__(256) void k_bnapply(const u16* src_hi, const u16* src_lo,
                                                 const float* scale, const float* shift,
                                                 float* outf, int total) {
    int q4 = blockIdx.x * 256 + threadIdx.x;
    int idx = q4 * 4;
    if (idx >= total) return;
    int c = idx & (HID - 1);
    ushort4 vh = *((const ushort4*)src_hi + q4);
    ushort4 vl = *((const ushort4*)src_lo + q4);
    float4 ov;
    ov.x = scale[c + 0] * (bf2f(vh.x) + bf2f(vl.x)) + shift[c + 0];
    ov.y = scale[c + 1] * (bf2f(vh.y) + bf2f(vl.y)) + shift[c + 1];
    ov.z = scale[c + 2] * (bf2f(vh.z) + bf2f(vl.z)) + shift[c + 2];
    ov.w = scale[c + 3] * (bf2f(vh.w) + bf2f(vl.w)) + shift[c + 3];
    *((float4*)outf + q4) = ov;
}

// d_out[0] = (1+k+8*int64)*2^20 only if a check failed.
__global__ void k_encode(const int* diag, float* out) {
    if (threadIdx.x != 0 || blockIdx.x != 0) return;
    int k = -1;
    for (int i = 0; i < 4; ++i) if (diag[i] != 0) { k = i; break; }
    if (k < 0) return;
    out[0] = (float)(1 + k + (diag[7] != 0 ? 8 : 0)) * 1048576.0f;
}

// ---------------- launcher (zero workspace dependency) ----------------

extern "C" void kernel_launch(void* const* d_in, const int* in_sizes, int n_in,
                              void* d_out, int out_size, void* d_ws, size_t ws_size,
                              hipStream_t stream) {
    const float*  x     = (const float*)d_in[0];
    const int*    ei    = (const int*)d_in[1];
    const float4* eattr = (const float4*)d_in[2];
    const float*  mlp_w = (const float*)d_in[3];
    const float*  mlp_b = (const float*)d_in[4];
    const float*  ew1   = (const float*)d_in[5];
    const float*  ew2   = (const float*)d_in[6];
    const float*  bn_g  = (const float*)d_in[7];
    const float*  bn_b  = (const float*)d_in[8];
    (void)n_in; (void)out_size; (void)d_ws; (void)ws_size;

    const int N = in_sizes[0] / HID;   // 50000
    const int E = in_sizes[1] / 2;     // 320000
    const size_t P = (size_t)N * HID;  // plane elements

    // ---- CSR staging inside d_out (dead before layer 0 writes d_out) ----
    char* st = (char*)d_out;
    int*    S_deg    = (int*)   (st + 0);
    float*  S_dinv   = (float*) (st + 204800);
    int*    S_offs   = (int*)   (st + 409600);
    int*    S_cursor = (int*)   (st + 614400);
    int*    S_bsum   = (int*)   (st + 819200);
    int*    S_bscan  = (int*)   (st + 820224);
    int*    S_gflag  = (int*)   (st + 821248);
    int*    S_row    = (int*)   (st + 1048576);
    float4* S_ea     = (float4*)(st + 2621440);   // ends 7,741,440 < 51.2 MB

    // ---- small homes in edge_index buffer (>=2.56 MB); eattr buffer holds eaP.
    //      NOTE: these alias live ei data — only writable AFTER k_place consumed ei. ----
    char* eb = (char*)d_in[1];
    int*   rowArr = (int*)  (eb + 0);          // 1,280,000
    float* dinvF  = (float*)(eb + 1280000);    // 200,000
    int*   offsF  = (int*)  (eb + 1480000);    // 200,004
    float* colsum = (float*)(eb + 1680128);
    float* colsq  = (float*)(eb + 1681152);
    float* scaleF = (float*)(eb + 1682176);
    float* shiftF = (float*)(eb + 1683200);
    int*   diag   = (int*)  (eb + 1684224);    // 1 KB
    u16*   wpH    = (u16*)  (eb + 1685504);    // 256 KB -> ends 1,947,648 <= 2,560,000
    float4* eaP   = (float4*)d_in[2];          // 5,120,000 exact

    // ---- h slots as bf16 hi/lo planes (each slot = 2 planes = 51.2 MB) ----
    u16* sX_hi = (u16*)d_in[0];          // x buffer (x consumed during layer 0)
    u16* sX_lo = sX_hi + P;
    u16* sD_hi = (u16*)d_out;
    u16* sD_lo = sD_hi + P;

    int NB  = (N + 255) / 256;
    int NBE = (E + 255) / 256;
    int NBG = (N + 127) / 128;    // 391 GEMM blocks (128 rows each)
    int NBA = (N + 3) / 4;        // 12500 agg blocks (one wave per node)
    int NBQ = (int)((P / 4 + 255) / 256);

    // ---- preprocessing (fused, 8 dispatches) ----
    k_zdet<<<NB, 256, 0, stream>>>(ei, S_gflag, (unsigned int*)S_deg, E, N);
    k_deg<<<NBE, 256, 0, stream>>>(ei, S_gflag, S_deg, E, N);
    k_scan1d<<<NB, 256, 0, stream>>>(S_deg, S_offs, S_bsum, S_dinv, N);
    k_scan2<<<1, 256, 0, stream>>>(S_bsum, S_bscan, NB);
    k_scan3<<<NB, 256, 0, stream>>>(S_offs, S_bscan, S_cursor, N, E);
    k_place<<<NBE, 256, 0, stream>>>(ei, S_gflag, eattr, S_cursor, S_row, S_ea, E, N);
    k_move<<<NBE, 256, 0, stream>>>(S_row, S_ea, S_dinv, S_offs, rowArr, eaP, dinvF, offsF,
                                    diag, E, N);
    k_precheck<<<NBE, 256, 0, stream>>>(offsF, S_cursor, dinvF, S_gflag, rowArr, diag, N, E);

    // ---- layers: even l -> dst = D(d_out), odd l -> dst = X; agg planes live in dst.
    //      BN deferral: planes hold PRE-BN y; consumers apply scale/shift; the previous
    //      layer's bnscale is folded into this layer's k_wsplit (block 0).
    //      FINAL layer's y goes to the X planes IN PLACE (row-exclusive GEMM reads its
    //      rows' h before the epilogue write), so k_bnapply writes fp32 directly to
    //      d_out — no D2D memcpy bounce. ----
    for (int l = 0; l < NLAYERS; ++l) {
        int even = (l % 2 == 0);
        u16* dst_hi = even ? sD_hi : sX_hi;
        u16* dst_lo = even ? sD_lo : sX_lo;
        const void* hinA; const u16* hin_lo; int hf32;
        if (l == 0) { hinA = (const void*)x; hin_lo = 0; hf32 = 1; }
        else if (even) { hinA = (const void*)sX_hi; hin_lo = sX_lo; hf32 = 0; }
        else { hinA = (const void*)sD_hi; hin_lo = sD_lo; hf32 = 0; }

        int finalL = (l == NLAYERS - 1);
        u16* y_hi = finalL ? sX_hi : dst_hi;   // final layer: in-place over its own h (X)
        u16* y_lo = finalL ? sX_lo : dst_lo;

        const float* gPrev = bn_g + (size_t)(l > 0 ? l - 1 : 0) * HID;
        const float* bPrev = bn_b + (size_t)(l > 0 ? l - 1 : 0) * HID;
        k_wsplit<<<64, 256, 0, stream>>>(mlp_w + (size_t)l * 512 * HID, wpH, colsum,
                                         gPrev, bPrev, scaleF, shiftF, diag, N, l > 0 ? 1 : 0);
        k_agg<<<NBA, 256, 0, stream>>>(hinA, hin_lo, hf32, offsF, rowArr, eaP, dinvF,
                                       ew1 + (size_t)l * 128, ew2 + (size_t)l * 384,
                                       scaleF, shiftF,
                                       dst_hi, dst_lo, diag, N);
        MPNN_79044578115931_kernel<<<NBG, 256, 0, stream>>>(
            hinA, hin_lo, hf32, dst_hi, dst_lo, wpH,
            mlp_b + (size_t)l * HID, scaleF, shiftF,
            y_hi, y_lo, colsum, colsq, diag, N);
        if (finalL) {
            k_bnscale<<<1, 256, 0, stream>>>(colsum, colsq,
                                             bn_g + (size_t)l * HID, bn_b + (size_t)l * HID,
                                             scaleF, shiftF, diag, N);
            // final: BN (no relu) -> fp32 directly into d_out (D planes are dead)
            k_bnapply<<<NBQ, 256, 0, stream>>>(y_hi, y_lo, scaleF, shiftF,
                                               (float*)d_out, (int)P);
        }
    }

    k_encode<<<1, 64, 0, stream>>>(diag, (float*)d_out);
}